// Round 3
// baseline (1020.544 us; speedup 1.0000x reference)
//
#include <hip/hip_runtime.h>

typedef __attribute__((ext_vector_type(8))) short bf16x8;
typedef __attribute__((ext_vector_type(4))) short s16x4;
typedef __attribute__((ext_vector_type(4))) float f32x4;

__device__ __forceinline__ float bf2f(unsigned short u) {
    union { unsigned int u; float f; } x; x.u = ((unsigned int)u) << 16; return x.f;
}
__device__ __forceinline__ unsigned short f2bf(float f) {
    union { float f; unsigned int u; } x; x.f = f;
    unsigned int u = x.u;
    unsigned int r = (u + 0x7fffu + ((u >> 16) & 1u)) >> 16;
    return (unsigned short)r;
}

#define GLDS16(gp, lp)                                                        \
    __builtin_amdgcn_global_load_lds(                                         \
        (const __attribute__((address_space(1))) void*)(gp),                  \
        (__attribute__((address_space(3))) void*)(lp), 16, 0, 0)

// ---------------------------------------------------------------------------
// GEMM: C[M=32768, N=1024] = A[M,K=1024] @ W^T + bias, W=[N,K] bf16 row-major.
// m97 structure: 128x128 tile, BK=64, 4 waves (2x2, 64x64 each), 2 barriers
// per K-step, staging via global_load_lds width=16 (linear LDS).
// A_F32: A staged as fp32 into LDS, converted to bf16 via v_cvt_pk_bf16_f32
// after ds_read (T12 recipe). Else A is bf16.
// OUT_MODE: 0 = bf16 [row][col], 1 = f32 [row][col], 2 = bf16 transposed
//           [b][col][t] (row = b*2048+t).
// grid = 2048 blocks (XCD-chunked swizzle inside), block = 256.
// ---------------------------------------------------------------------------
template<bool A_F32, int OUT_MODE>
__global__ __launch_bounds__(256)
void gemm_glds(const void* __restrict__ A_, const unsigned short* __restrict__ Bw,
               const float* __restrict__ bias, void* __restrict__ out_) {
    constexpr int AB = A_F32 ? 4 : 2;                 // bytes per A element
    __shared__ __align__(16) unsigned char lA[128 * 64 * AB];
    __shared__ __align__(16) unsigned short lB[128 * 64];

    const int tid  = threadIdx.x;
    const int lane = tid & 63;
    const int w    = tid >> 6;
    const int wr   = w >> 1, wc = w & 1;

    // XCD-chunked bijective swizzle (nwg=2048, 8 XCDs, q=256, r=0):
    // blocks resident on one XCD get consecutive tiles -> the 8 col-tiles of
    // one A row-panel share that XCD's L2 (fixes the 4x A over-fetch).
    const int bid = blockIdx.x;
    const int swz = (bid & 7) * 256 + (bid >> 3);
    const int  col0 = (swz & 7) * 128;
    const long row0 = (long)(swz >> 3) * 128;

    // ---- staging descriptors (lane-linear LDS, per-lane global addr) ----
    const int off = w * 1024 + lane * 16;             // byte offset in 4KB chunk
    const int arow = off / (64 * AB);
    const int acol = (off % (64 * AB)) / AB;
    const char* gA = (const char*)A_ + ((row0 + arow) * 1024 + acol) * AB;
    const int brow = off >> 7;
    const int bcol = (off & 127) >> 1;
    const unsigned short* gB = Bw + (size_t)(col0 + brow) * 1024 + bcol;
    constexpr int A_ISS = (128 * 64 * AB) / 4096;     // 8 (f32) or 4 (bf16)
    // each issue advances 4096 tile-bytes = 65536 global bytes (both dtypes)

    auto lA3 = (__attribute__((address_space(3))) char*)lA;
    auto lB3 = (__attribute__((address_space(3))) char*)lB;
    const int lbase = w * 1024;

    f32x4 acc[4][4];
#pragma unroll
    for (int m = 0; m < 4; ++m)
#pragma unroll
        for (int n = 0; n < 4; ++n) acc[m][n] = (f32x4){0.f, 0.f, 0.f, 0.f};

    const int fr = lane & 15, kb = (lane >> 4) * 8;

    for (int k0 = 0; k0 < 1024; k0 += 64) {
#pragma unroll
        for (int r = 0; r < A_ISS; ++r)
            GLDS16(gA + (long)r * 65536, lA3 + lbase + r * 4096);
#pragma unroll
        for (int r = 0; r < 4; ++r)
            GLDS16(gB + (size_t)r * 32768, lB3 + lbase + r * 4096);
        gA += 64 * AB;
        gB += 64;
        __syncthreads();   // drains vmcnt -> tiles resident

        bf16x8 aF[2][4], bF[2][4];
        if constexpr (A_F32) {
            const float* lAf = (const float*)lA;
#pragma unroll
            for (int c = 0; c < 2; ++c)
#pragma unroll
                for (int m = 0; m < 4; ++m) {
                    const float* p = lAf + (wr * 64 + m * 16 + fr) * 64 + c * 32 + kb;
                    f32x4 lo = *(const f32x4*)p;
                    f32x4 hi = *(const f32x4*)(p + 4);
                    unsigned q0, q1, q2, q3;
                    asm("v_cvt_pk_bf16_f32 %0, %1, %2" : "=v"(q0) : "v"(lo[0]), "v"(lo[1]));
                    asm("v_cvt_pk_bf16_f32 %0, %1, %2" : "=v"(q1) : "v"(lo[2]), "v"(lo[3]));
                    asm("v_cvt_pk_bf16_f32 %0, %1, %2" : "=v"(q2) : "v"(hi[0]), "v"(hi[1]));
                    asm("v_cvt_pk_bf16_f32 %0, %1, %2" : "=v"(q3) : "v"(hi[2]), "v"(hi[3]));
                    union { bf16x8 v; unsigned u[4]; } pk;
                    pk.u[0] = q0; pk.u[1] = q1; pk.u[2] = q2; pk.u[3] = q3;
                    aF[c][m] = pk.v;
                }
        } else {
            const unsigned short* lAh = (const unsigned short*)lA;
#pragma unroll
            for (int c = 0; c < 2; ++c)
#pragma unroll
                for (int m = 0; m < 4; ++m)
                    aF[c][m] = *(const bf16x8*)(lAh + (wr * 64 + m * 16 + fr) * 64 + c * 32 + kb);
        }
#pragma unroll
        for (int c = 0; c < 2; ++c)
#pragma unroll
            for (int n = 0; n < 4; ++n)
                bF[c][n] = *(const bf16x8*)&lB[(wc * 64 + n * 16 + fr) * 64 + c * 32 + kb];

#pragma unroll
        for (int c = 0; c < 2; ++c)
#pragma unroll
            for (int m = 0; m < 4; ++m)
#pragma unroll
                for (int n = 0; n < 4; ++n)
                    acc[m][n] = __builtin_amdgcn_mfma_f32_16x16x32_bf16(aF[c][m], bF[c][n], acc[m][n], 0, 0, 0);
        __syncthreads();   // tile consumed before next stage overwrites
    }

    // C/D layout (m89-verified): col = lane&15, row = (lane>>4)*4 + j
    const int cr = (lane >> 4) * 4;
    const int cc = lane & 15;
    if constexpr (OUT_MODE == 2) {
        const int b  = (int)(row0 >> 11);
        const int tb = ((int)row0 & 2047) + wr * 64 + cr;
#pragma unroll
        for (int m = 0; m < 4; ++m) {
#pragma unroll
            for (int n = 0; n < 4; ++n) {
                int col = col0 + wc * 64 + n * 16 + cc;
                float bv = bias[col];
                s16x4 o;
#pragma unroll
                for (int j = 0; j < 4; ++j) o[j] = (short)f2bf(acc[m][n][j] + bv);
                *(s16x4*)&((unsigned short*)out_)[((size_t)b * 1024 + col) * 2048 + tb + m * 16] = o;
            }
        }
    } else {
#pragma unroll
        for (int m = 0; m < 4; ++m) {
            long row = row0 + wr * 64 + m * 16 + cr;
#pragma unroll
            for (int n = 0; n < 4; ++n) {
                int col = col0 + wc * 64 + n * 16 + cc;
                float bv = bias[col];
#pragma unroll
                for (int j = 0; j < 4; ++j) {
                    float v = acc[m][n][j] + bv;
                    if constexpr (OUT_MODE == 1) ((float*)out_)[(row + j) * 1024 + col] = v;
                    else ((unsigned short*)out_)[(row + j) * 1024 + col] = f2bf(v);
                }
            }
        }
    }
}

// ---------------------------------------------------------------------------
// 8-point DFT (negative exponent), in place on xr/xi[8].
// ---------------------------------------------------------------------------
__device__ __forceinline__ void dft8(float* xr, float* xi) {
    const float c8 = 0.70710678118654752440f;
    float es0r = xr[0] + xr[4], es0i = xi[0] + xi[4];
    float es1r = xr[0] - xr[4], es1i = xi[0] - xi[4];
    float es2r = xr[2] + xr[6], es2i = xi[2] + xi[6];
    float es3r = xr[2] - xr[6], es3i = xi[2] - xi[6];
    float E0r = es0r + es2r, E0i = es0i + es2i;
    float E2r = es0r - es2r, E2i = es0i - es2i;
    float E1r = es1r + es3i, E1i = es1i - es3r;
    float E3r = es1r - es3i, E3i = es1i + es3r;
    float os0r = xr[1] + xr[5], os0i = xi[1] + xi[5];
    float os1r = xr[1] - xr[5], os1i = xi[1] - xi[5];
    float os2r = xr[3] + xr[7], os2i = xi[3] + xi[7];
    float os3r = xr[3] - xr[7], os3i = xi[3] - xi[7];
    float O0r = os0r + os2r, O0i = os0i + os2i;
    float O2r = os0r - os2r, O2i = os0i - os2i;
    float O1r = os1r + os3i, O1i = os1i - os3r;
    float O3r = os1r - os3i, O3i = os1i + os3r;
    float p1 = c8 * (O1r + O1i), q1 = c8 * (O1i - O1r);
    float p3 = c8 * (O3r + O3i), q3 = c8 * (O3i - O3r);
    xr[0] = E0r + O0r; xi[0] = E0i + O0i;
    xr[4] = E0r - O0r; xi[4] = E0i - O0i;
    xr[1] = E1r + p1;  xi[1] = E1i + q1;
    xr[5] = E1r - p1;  xi[5] = E1i - q1;
    xr[2] = E2r + O2i; xi[2] = E2i - O2r;
    xr[6] = E2r - O2i; xi[6] = E2i + O2r;
    xr[3] = E3r + q3;  xi[3] = E3i - p3;
    xr[7] = E3r - q3;  xi[7] = E3i + p3;
}

__device__ __forceinline__ int padc(int p) { return p + (p >> 5); }

// ---------------------------------------------------------------------------
// fft_corr: per (b, 8 d-columns): z = q + i*k read coalesced from transposed
// layout qt/kt[b][d][t]; register-blocked mixed-radix FFT (8*8*8*4);
// Hermitian split -> accumulate P = Q*conj(K) into G[b][1025][2].
// grid = 2048 (16 b x 128 chunks), block = 256.
// ---------------------------------------------------------------------------
__global__ __launch_bounds__(256)
void fft_corr(const unsigned short* __restrict__ qt, const unsigned short* __restrict__ kt,
              float* __restrict__ G) {
    __shared__ float2 zc[2112];
    __shared__ float accR[1025], accI[1025];
    float* zfr = (float*)zc;
    float* zfi = zfr + 2112;
    const int tid = threadIdx.x;
    const int b = blockIdx.x >> 7;
    const int chunk = blockIdx.x & 127;

    const float N2PI = -6.28318530717958647692f;
    float w1r, w1i, w2r, w2i, w3r, w3i;
    {
        float s, c;
        __sincosf(N2PI * (float)tid * (1.0f / 2048.0f), &s, &c); w1r = c; w1i = s;
        __sincosf(N2PI * (float)(tid & 31) * (1.0f / 256.0f), &s, &c); w2r = c; w2i = s;
        __sincosf(N2PI * (float)(tid & 3) * (1.0f / 32.0f),  &s, &c); w3r = c; w3i = s;
    }

    for (int f = tid; f < 1025; f += 256) { accR[f] = 0.f; accI[f] = 0.f; }

    const int beta = tid >> 5, s2 = tid & 31;
    const int gam  = tid >> 2, u3 = tid & 3;

    for (int r = 0; r < 8; ++r) {
        const int d = chunk * 8 + r;
        const unsigned short* qrow = qt + ((size_t)b * 1024 + d) * 2048;
        const unsigned short* krow = kt + ((size_t)b * 1024 + d) * 2048;

        float xr[8], xi[8];
#pragma unroll
        for (int k = 0; k < 8; ++k) {
            xr[k] = bf2f(qrow[tid + 256 * k]);
            xi[k] = bf2f(krow[tid + 256 * k]);
        }
        dft8(xr, xi);
        {
            float cr_ = w1r, ci_ = w1i;
#pragma unroll
            for (int k = 1; k < 8; ++k) {
                float tr = xr[k] * cr_ - xi[k] * ci_;
                float ti = xr[k] * ci_ + xi[k] * cr_;
                xr[k] = tr; xi[k] = ti;
                if (k < 7) {
                    float nr = cr_ * w1r - ci_ * w1i;
                    float ni = cr_ * w1i + ci_ * w1r;
                    cr_ = nr; ci_ = ni;
                }
            }
        }
#pragma unroll
        for (int k = 0; k < 8; ++k) zc[padc(256 * k + tid)] = make_float2(xr[k], xi[k]);
        __syncthreads();

#pragma unroll
        for (int k = 0; k < 8; ++k) {
            float2 v = zc[padc(256 * beta + 32 * k + s2)];
            xr[k] = v.x; xi[k] = v.y;
        }
        __syncthreads();
        dft8(xr, xi);
        {
            float cr_ = w2r, ci_ = w2i;
#pragma unroll
            for (int k = 1; k < 8; ++k) {
                float tr = xr[k] * cr_ - xi[k] * ci_;
                float ti = xr[k] * ci_ + xi[k] * cr_;
                xr[k] = tr; xi[k] = ti;
                if (k < 7) {
                    float nr = cr_ * w2r - ci_ * w2i;
                    float ni = cr_ * w2i + ci_ * w2r;
                    cr_ = nr; ci_ = ni;
                }
            }
        }
#pragma unroll
        for (int k = 0; k < 8; ++k) zc[padc(256 * beta + 32 * k + s2)] = make_float2(xr[k], xi[k]);
        __syncthreads();

#pragma unroll
        for (int k = 0; k < 8; ++k) {
            float2 v = zc[padc(32 * gam + 4 * k + u3)];
            xr[k] = v.x; xi[k] = v.y;
        }
        __syncthreads();
        dft8(xr, xi);
        {
            float cr_ = w3r, ci_ = w3i;
#pragma unroll
            for (int k = 1; k < 8; ++k) {
                float tr = xr[k] * cr_ - xi[k] * ci_;
                float ti = xr[k] * ci_ + xi[k] * cr_;
                xr[k] = tr; xi[k] = ti;
                if (k < 7) {
                    float nr = cr_ * w3r - ci_ * w3i;
                    float ni = cr_ * w3i + ci_ * w3r;
                    cr_ = nr; ci_ = ni;
                }
            }
        }
#pragma unroll
        for (int k = 0; k < 8; ++k) zc[padc(32 * gam + 4 * k + u3)] = make_float2(xr[k], xi[k]);
        __syncthreads();

#pragma unroll
        for (int k = 0; k < 8; ++k) {
            float2 v = zc[padc(8 * tid + k)];
            xr[k] = v.x; xi[k] = v.y;
        }
        __syncthreads();

        float Xr[8], Xi[8];
#pragma unroll
        for (int blk = 0; blk < 2; ++blk) {
            const int o = 4 * blk;
            float s0r = xr[o] + xr[o + 2], s0i = xi[o] + xi[o + 2];
            float s1r = xr[o] - xr[o + 2], s1i = xi[o] - xi[o + 2];
            float s2r = xr[o + 1] + xr[o + 3], s2i = xi[o + 1] + xi[o + 3];
            float s3r = xr[o + 1] - xr[o + 3], s3i = xi[o + 1] - xi[o + 3];
            Xr[o + 0] = s0r + s2r; Xi[o + 0] = s0i + s2i;
            Xr[o + 2] = s0r - s2r; Xi[o + 2] = s0i - s2i;
            Xr[o + 1] = s1r + s3i; Xi[o + 1] = s1i - s3r;
            Xr[o + 3] = s1r - s3i; Xi[o + 3] = s1i + s3r;
        }
        {
            const int k1 = tid >> 5;
            const int k2 = (tid >> 2) & 7;
            const int fb = k1 + 8 * k2;
#pragma unroll
            for (int blk = 0; blk < 2; ++blk) {
                const int k3 = (2 * (tid & 3) + blk) & 7;
#pragma unroll
                for (int k4 = 0; k4 < 4; ++k4) {
                    const int f = fb + 64 * k3 + 512 * k4;
                    const int pf = padc(f);
                    zfr[pf] = Xr[4 * blk + k4];
                    zfi[pf] = Xi[4 * blk + k4];
                }
            }
        }
        __syncthreads();

        for (int f = tid; f < 1025; f += 256) {
            const int f2 = (2048 - f) & 2047;
            const int pf = padc(f), pf2 = padc(f2);
            float Zr = zfr[pf],  Zi = zfi[pf];
            float Yr = zfr[pf2], Yi = -zfi[pf2];
            float Qr = 0.5f * (Zr + Yr), Qi = 0.5f * (Zi + Yi);
            float Kr = 0.5f * (Zi - Yi), Ki = -0.5f * (Zr - Yr);
            accR[f] += Qr * Kr + Qi * Ki;
            accI[f] += Qi * Kr - Qr * Ki;
        }
        __syncthreads();
    }

    for (int f = tid; f < 1025; f += 256) {
        atomicAdd(&G[((size_t)b * 1025 + f) * 2 + 0], accR[f]);
        atomicAdd(&G[((size_t)b * 1025 + f) * 2 + 1], accI[f]);
    }
}

// ---------------------------------------------------------------------------
// In-LDS radix-2 DIT FFT, N=2048 (only used by irfft_mean: 16 blocks, cheap).
// ---------------------------------------------------------------------------
__device__ __forceinline__ void fft2048(float* zr, float* zi,
                                        const float* twr, const float* twi, int tid) {
    for (int t = tid; t < 2048; t += 256) {
        int j = __brev((unsigned)t) >> 21;
        if (j > t) {
            float a = zr[t]; zr[t] = zr[j]; zr[j] = a;
            float c = zi[t]; zi[t] = zi[j]; zi[j] = c;
        }
    }
    __syncthreads();
    for (int s = 0; s < 11; ++s) {
        const int m = 1 << s;
        for (int i = tid; i < 1024; i += 256) {
            const int pos = i & (m - 1);
            const int i1  = ((i >> s) << (s + 1)) + pos;
            const int i2  = i1 + m;
            const int tw  = pos << (10 - s);
            float wr = twr[tw], wi = twi[tw];
            float xr = zr[i2], xi = zi[i2];
            float tr = wr * xr - wi * xi;
            float ti = wr * xi + wi * xr;
            float ur = zr[i1], ui = zi[i1];
            zr[i2] = ur - tr; zi[i2] = ui - ti;
            zr[i1] = ur + tr; zi[i1] = ui + ti;
        }
        __syncthreads();
    }
}

__device__ __forceinline__ void init_twiddle(float* twr, float* twi, int tid) {
    for (int j = tid; j < 1024; j += 256) {
        float ang = -6.28318530717958647692f * (float)j * (1.0f / 2048.0f);
        twr[j] = cosf(ang);
        twi[j] = sinf(ang);
    }
}

// ---------------------------------------------------------------------------
// Per-batch irfft of G -> mean_value[b][t], scale 1/(2048*1024). grid = 16.
// ---------------------------------------------------------------------------
__global__ __launch_bounds__(256)
void irfft_mean(const float* __restrict__ G, float* __restrict__ mv) {
    __shared__ float zr[2048], zi[2048];
    __shared__ float twr[1024], twi[1024];
    const int tid = threadIdx.x;
    const int b = blockIdx.x;
    init_twiddle(twr, twi, tid);
    for (int f = tid; f < 2048; f += 256) {
        int g = (f <= 1024) ? f : 2048 - f;
        float gr = G[((size_t)b * 1025 + g) * 2 + 0];
        float gi = G[((size_t)b * 1025 + g) * 2 + 1];
        zr[f] = gr;
        zi[f] = (f <= 1024) ? -gi : gi;
    }
    __syncthreads();
    fft2048(zr, zi, twr, twi, tid);
    const float sc = 1.0f / (2048.0f * 1024.0f);
    for (int t = tid; t < 2048; t += 256) mv[b * 2048 + t] = zr[t] * sc;
}

// ---------------------------------------------------------------------------
// Top-7 over batch-mean of mean_value + per-batch softmax of gathered weights.
// ---------------------------------------------------------------------------
__global__ __launch_bounds__(256)
void topk_softmax(const float* __restrict__ mv, int* __restrict__ idx_out,
                  float* __restrict__ w_out) {
    __shared__ float cm[2048];
    __shared__ float bval[256];
    __shared__ int   bidx[256];
    __shared__ int   sel[7];
    const int tid = threadIdx.x;
    for (int t = tid; t < 2048; t += 256) {
        float s = 0.f;
        for (int b = 0; b < 16; ++b) s += mv[b * 2048 + t];
        cm[t] = s * (1.0f / 16.0f);
    }
    __syncthreads();
    for (int it = 0; it < 7; ++it) {
        float best = -3.4e38f; int bi = 1 << 30;
        for (int t = tid; t < 2048; t += 256) {
            float v = cm[t];
            if (v > best || (v == best && t < bi)) { best = v; bi = t; }
        }
        bval[tid] = best; bidx[tid] = bi;
        __syncthreads();
        if (tid == 0) {
            float bb = bval[0]; int bj = bidx[0];
            for (int u = 1; u < 256; ++u)
                if (bval[u] > bb || (bval[u] == bb && bidx[u] < bj)) { bb = bval[u]; bj = bidx[u]; }
            sel[it] = bj;
            idx_out[it] = bj;
            cm[bj] = -3.4e38f;
        }
        __syncthreads();
    }
    if (tid < 16) {
        const int b = tid;
        float wv[7]; float mx = -3.4e38f;
#pragma unroll
        for (int i = 0; i < 7; ++i) { wv[i] = mv[b * 2048 + sel[i]]; mx = fmaxf(mx, wv[i]); }
        float s = 0.f;
#pragma unroll
        for (int i = 0; i < 7; ++i) { wv[i] = expf(wv[i] - mx); s += wv[i]; }
        float inv = 1.0f / s;
#pragma unroll
        for (int i = 0; i < 7; ++i) w_out[b * 7 + i] = wv[i] * inv;
    }
}

// ---------------------------------------------------------------------------
// agg[b,t,d] = sum_i w[b,i] * vp[b,(t+idx[i])%2048,d]  (bf16 in/out)
// ---------------------------------------------------------------------------
__global__ __launch_bounds__(256)
void agg_kernel(const unsigned short* __restrict__ vp, const int* __restrict__ idx,
                const float* __restrict__ w, unsigned short* __restrict__ agg) {
    const int b  = blockIdx.y;
    const int t  = blockIdx.x * 2 + (threadIdx.x >> 7);
    const int d8 = (threadIdx.x & 127) * 8;
    float av[8] = {0.f, 0.f, 0.f, 0.f, 0.f, 0.f, 0.f, 0.f};
#pragma unroll
    for (int i = 0; i < 7; ++i) {
        const int srow = (t + idx[i]) & 2047;
        const float wi = w[b * 7 + i];
        bf16x8 v = *(const bf16x8*)&vp[((size_t)b * 2048 + srow) * 1024 + d8];
#pragma unroll
        for (int j = 0; j < 8; ++j) av[j] += wi * bf2f((unsigned short)v[j]);
    }
    bf16x8 o;
#pragma unroll
    for (int j = 0; j < 8; ++j) o[j] = (short)f2bf(av[j]);
    *(bf16x8*)&agg[((size_t)b * 2048 + t) * 1024 + d8] = o;
}

// ---------------------------------------------------------------------------
__global__ __launch_bounds__(256)
void cast_w(const float* __restrict__ src, unsigned short* __restrict__ dst) {
    const int i = (blockIdx.x * 256 + threadIdx.x) * 4;   // n = 1048576 exact
    f32x4 v = *(const f32x4*)(src + i);
    s16x4 o;
#pragma unroll
    for (int j = 0; j < 4; ++j) o[j] = (short)f2bf(v[j]);
    *(s16x4*)(dst + i) = o;
}

__global__ __launch_bounds__(256)
void zero_f32(float* __restrict__ p, int n) {
    const int i = blockIdx.x * 256 + threadIdx.x;
    if (i < n) p[i] = 0.0f;
}

// ---------------------------------------------------------------------------
extern "C" void kernel_launch(void* const* d_in, const int* in_sizes, int n_in,
                              void* d_out, int out_size, void* d_ws, size_t ws_size,
                              hipStream_t stream) {
    const float* queries = (const float*)d_in[0];
    const float* keys    = (const float*)d_in[1];
    const float* values  = (const float*)d_in[2];
    const float* Wq = (const float*)d_in[3];  const float* bq = (const float*)d_in[4];
    const float* Wk = (const float*)d_in[5];  const float* bk = (const float*)d_in[6];
    const float* Wv = (const float*)d_in[7];  const float* bv = (const float*)d_in[8];
    const float* Wo = (const float*)d_in[9];  const float* bo = (const float*)d_in[10];
    float* out = (float*)d_out;

    char* ws = (char*)d_ws;
    constexpr size_t SZP = (size_t)32768 * 1024 * 2;           // 64 MB (bf16 B*L*D)
    unsigned short* qt  = (unsigned short*)(ws);               // [b][d][t]; reused as agg
    unsigned short* kt  = (unsigned short*)(ws + SZP);         // [b][d][t]
    unsigned short* vp  = (unsigned short*)(ws + 2 * SZP);     // [b][t][d]
    unsigned short* w16 = (unsigned short*)(ws + 3 * SZP);     // 4 x 1M bf16
    float* G   = (float*)(ws + 3 * SZP + 8388608);             // 16*1025*2 f32
    float* mv  = (float*)(ws + 3 * SZP + 8388608 + 131328);    // 16*2048 f32
    int*   idx = (int*)  (ws + 3 * SZP + 8388608 + 131328 + 131072);
    float* wsm = (float*)(ws + 3 * SZP + 8388608 + 131328 + 131072 + 64);
    unsigned short* agg = qt;

    cast_w<<<1024, 256, 0, stream>>>(Wq, w16 + 0 * 1048576);
    cast_w<<<1024, 256, 0, stream>>>(Wk, w16 + 1 * 1048576);
    cast_w<<<1024, 256, 0, stream>>>(Wv, w16 + 2 * 1048576);
    cast_w<<<1024, 256, 0, stream>>>(Wo, w16 + 3 * 1048576);
    zero_f32<<<(32800 + 255) / 256, 256, 0, stream>>>(G, 32800);

    gemm_glds<true, 2><<<2048, 256, 0, stream>>>(queries, w16 + 0 * 1048576, bq, qt);
    gemm_glds<true, 2><<<2048, 256, 0, stream>>>(keys,    w16 + 1 * 1048576, bk, kt);
    gemm_glds<true, 0><<<2048, 256, 0, stream>>>(values,  w16 + 2 * 1048576, bv, vp);

    fft_corr<<<2048, 256, 0, stream>>>(qt, kt, G);
    irfft_mean<<<16, 256, 0, stream>>>(G, mv);
    topk_softmax<<<1, 256, 0, stream>>>(mv, idx, wsm);
    agg_kernel<<<dim3(1024, 16), 256, 0, stream>>>(vp, idx, wsm, agg);

    gemm_glds<false, 1><<<2048, 256, 0, stream>>>(agg, w16 + 3 * 1048576, bo, out);
}

// Round 4
// 792.482 us; speedup vs baseline: 1.2878x; 1.2878x over previous
//
#include <hip/hip_runtime.h>

typedef __attribute__((ext_vector_type(8))) short bf16x8;
typedef __attribute__((ext_vector_type(4))) short s16x4;
typedef __attribute__((ext_vector_type(4))) float f32x4;

__device__ __forceinline__ float bf2f(unsigned short u) {
    union { unsigned int u; float f; } x; x.u = ((unsigned int)u) << 16; return x.f;
}
__device__ __forceinline__ unsigned short f2bf(float f) {
    union { float f; unsigned int u; } x; x.f = f;
    unsigned int u = x.u;
    unsigned int r = (u + 0x7fffu + ((u >> 16) & 1u)) >> 16;
    return (unsigned short)r;
}

#define GLDS16(gp, lp)                                                        \
    __builtin_amdgcn_global_load_lds(                                         \
        (const __attribute__((address_space(1))) void*)(gp),                  \
        (__attribute__((address_space(3))) void*)(lp), 16, 0, 0)

// ---------------------------------------------------------------------------
// GEMM: C[M=32768, N=1024] = A[M,K=1024] @ W^T + bias, W=[N,K] bf16 row-major.
// m97 structure: 128x128 tile, BK=64, 4 waves (2x2, 64x64 each),
// global_load_lds width=16 with LINEAR LDS dest + XOR-swizzled global source
// (rule #21: source permutation == read permutation).
//  - fp32 rows (256B, 16 units of 16B): unit ^= row&15
//  - bf16 rows (128B, 8 units of 16B):  unit ^= row&7
// -> fragment ds_reads land 2-way per bank (free) instead of 16-way.
// A_F32: A staged as fp32, converted via v_cvt_pk_bf16_f32 after ds_read.
// OUT_MODE: 0 = bf16 [row][col], 1 = f32 [row][col], 2 = bf16 transposed
//           [b][col][t] (row = b*2048+t).
// grid = 2048 blocks (XCD-chunked bijective swizzle), block = 256.
// ---------------------------------------------------------------------------
template<bool A_F32, int OUT_MODE>
__global__ __launch_bounds__(256)
void gemm_glds(const void* __restrict__ A_, const unsigned short* __restrict__ Bw,
               const float* __restrict__ bias, void* __restrict__ out_) {
    constexpr int AB = A_F32 ? 4 : 2;                 // bytes per A element
    __shared__ __align__(16) unsigned char lA[128 * 64 * AB];
    __shared__ __align__(16) unsigned short lB[128 * 64];

    const int tid  = threadIdx.x;
    const int lane = tid & 63;
    const int w    = tid >> 6;
    const int wr   = w >> 1, wc = w & 1;

    // XCD-chunked bijective swizzle (nwg=2048, 8 XCDs, q=256):
    const int bid = blockIdx.x;
    const int swz = (bid & 7) * 256 + (bid >> 3);
    const int  col0 = (swz & 7) * 128;
    const long row0 = (long)(swz >> 3) * 128;

    // ---- staging: linear LDS dest, XOR-swizzled per-lane global source ----
    const int loff = w * 1024 + lane * 16;            // byte offset in 4KB chunk
    const char* gA;
    if constexpr (A_F32) {
        const int rr = loff >> 8;                     // row in chunk (16/chunk), == row&15
        const int X  = (loff & 255) ^ (rr << 4);
        gA = (const char*)A_ + (size_t)(row0 + rr) * 4096 + X;
    } else {
        const int rr = loff >> 7;                     // row in chunk (32/chunk)
        const int X  = (loff & 127) ^ ((rr & 7) << 4);
        gA = (const char*)A_ + (size_t)(row0 + rr) * 2048 + X;
    }
    const int rb = loff >> 7;
    const int Xb = (loff & 127) ^ ((rb & 7) << 4);
    const char* gB = (const char*)Bw + (size_t)(col0 + rb) * 2048 + Xb;
    constexpr int A_ISS = (128 * 64 * AB) / 4096;     // 8 (f32) or 4 (bf16)
    // each issue r: +4096 LDS bytes, +65536 global bytes (both dtypes)

    auto lA3 = (__attribute__((address_space(3))) char*)lA;
    auto lB3 = (__attribute__((address_space(3))) char*)lB;
    const int lbase = w * 1024;                       // wave-uniform dest base

    f32x4 acc[4][4];
#pragma unroll
    for (int m = 0; m < 4; ++m)
#pragma unroll
        for (int n = 0; n < 4; ++n) acc[m][n] = (f32x4){0.f, 0.f, 0.f, 0.f};

    const int fr = lane & 15, g4 = lane >> 4;         // kb = g4*8 elements

    for (int k0 = 0; k0 < 1024; k0 += 64) {
#pragma unroll
        for (int r = 0; r < A_ISS; ++r)
            GLDS16(gA + (size_t)r * 65536, lA3 + lbase + r * 4096);
#pragma unroll
        for (int r = 0; r < 4; ++r)
            GLDS16(gB + (size_t)r * 65536, lB3 + lbase + r * 4096);
        gA += 64 * AB;
        gB += 128;
        __syncthreads();   // drains vmcnt -> tiles resident

        bf16x8 aF[2][4], bF[2][4];
        if constexpr (A_F32) {
            const char* lAc = (const char*)lA;
            const int msk = fr << 4;
#pragma unroll
            for (int c = 0; c < 2; ++c)
#pragma unroll
                for (int m = 0; m < 4; ++m) {
                    const int row = wr * 64 + m * 16 + fr;     // row&15 == fr
                    const int Xr  = c * 128 + g4 * 32;
                    f32x4 lo = *(const f32x4*)(lAc + row * 256 + (Xr ^ msk));
                    f32x4 hi = *(const f32x4*)(lAc + row * 256 + ((Xr + 16) ^ msk));
                    unsigned q0, q1, q2, q3;
                    asm("v_cvt_pk_bf16_f32 %0, %1, %2" : "=v"(q0) : "v"(lo[0]), "v"(lo[1]));
                    asm("v_cvt_pk_bf16_f32 %0, %1, %2" : "=v"(q1) : "v"(lo[2]), "v"(lo[3]));
                    asm("v_cvt_pk_bf16_f32 %0, %1, %2" : "=v"(q2) : "v"(hi[0]), "v"(hi[1]));
                    asm("v_cvt_pk_bf16_f32 %0, %1, %2" : "=v"(q3) : "v"(hi[2]), "v"(hi[3]));
                    union { bf16x8 v; unsigned u[4]; } pk;
                    pk.u[0] = q0; pk.u[1] = q1; pk.u[2] = q2; pk.u[3] = q3;
                    aF[c][m] = pk.v;
                }
        } else {
            const char* lAc = (const char*)lA;
            const int msk = (fr & 7) << 4;
#pragma unroll
            for (int c = 0; c < 2; ++c)
#pragma unroll
                for (int m = 0; m < 4; ++m) {
                    const int row = wr * 64 + m * 16 + fr;     // row&7 == fr&7
                    const int Xr  = c * 64 + g4 * 16;
                    aF[c][m] = *(const bf16x8*)(lAc + row * 128 + (Xr ^ msk));
                }
        }
        {
            const char* lBc = (const char*)lB;
            const int msk = (fr & 7) << 4;
#pragma unroll
            for (int c = 0; c < 2; ++c)
#pragma unroll
                for (int n = 0; n < 4; ++n) {
                    const int row = wc * 64 + n * 16 + fr;
                    const int Xr  = c * 64 + g4 * 16;
                    bF[c][n] = *(const bf16x8*)(lBc + row * 128 + (Xr ^ msk));
                }
        }

#pragma unroll
        for (int c = 0; c < 2; ++c)
#pragma unroll
            for (int m = 0; m < 4; ++m)
#pragma unroll
                for (int n = 0; n < 4; ++n)
                    acc[m][n] = __builtin_amdgcn_mfma_f32_16x16x32_bf16(aF[c][m], bF[c][n], acc[m][n], 0, 0, 0);
        __syncthreads();   // tile consumed before next stage overwrites
    }

    // C/D layout (m89-verified): col = lane&15, row = (lane>>4)*4 + j
    const int cr = g4 * 4;
    const int cc = fr;
    if constexpr (OUT_MODE == 2) {
        const int b  = (int)(row0 >> 11);
        const int tb = ((int)row0 & 2047) + wr * 64 + cr;
#pragma unroll
        for (int m = 0; m < 4; ++m) {
#pragma unroll
            for (int n = 0; n < 4; ++n) {
                int col = col0 + wc * 64 + n * 16 + cc;
                float bv = bias[col];
                s16x4 o;
#pragma unroll
                for (int j = 0; j < 4; ++j) o[j] = (short)f2bf(acc[m][n][j] + bv);
                *(s16x4*)&((unsigned short*)out_)[((size_t)b * 1024 + col) * 2048 + tb + m * 16] = o;
            }
        }
    } else {
#pragma unroll
        for (int m = 0; m < 4; ++m) {
            long row = row0 + wr * 64 + m * 16 + cr;
#pragma unroll
            for (int n = 0; n < 4; ++n) {
                int col = col0 + wc * 64 + n * 16 + cc;
                float bv = bias[col];
#pragma unroll
                for (int j = 0; j < 4; ++j) {
                    float v = acc[m][n][j] + bv;
                    if constexpr (OUT_MODE == 1) ((float*)out_)[(row + j) * 1024 + col] = v;
                    else ((unsigned short*)out_)[(row + j) * 1024 + col] = f2bf(v);
                }
            }
        }
    }
}

// ---------------------------------------------------------------------------
// 8-point DFT (negative exponent), in place on xr/xi[8].
// ---------------------------------------------------------------------------
__device__ __forceinline__ void dft8(float* xr, float* xi) {
    const float c8 = 0.70710678118654752440f;
    float es0r = xr[0] + xr[4], es0i = xi[0] + xi[4];
    float es1r = xr[0] - xr[4], es1i = xi[0] - xi[4];
    float es2r = xr[2] + xr[6], es2i = xi[2] + xi[6];
    float es3r = xr[2] - xr[6], es3i = xi[2] - xi[6];
    float E0r = es0r + es2r, E0i = es0i + es2i;
    float E2r = es0r - es2r, E2i = es0i - es2i;
    float E1r = es1r + es3i, E1i = es1i - es3r;
    float E3r = es1r - es3i, E3i = es1i + es3r;
    float os0r = xr[1] + xr[5], os0i = xi[1] + xi[5];
    float os1r = xr[1] - xr[5], os1i = xi[1] - xi[5];
    float os2r = xr[3] + xr[7], os2i = xi[3] + xi[7];
    float os3r = xr[3] - xr[7], os3i = xi[3] - xi[7];
    float O0r = os0r + os2r, O0i = os0i + os2i;
    float O2r = os0r - os2r, O2i = os0i - os2i;
    float O1r = os1r + os3i, O1i = os1i - os3r;
    float O3r = os1r - os3i, O3i = os1i + os3r;
    float p1 = c8 * (O1r + O1i), q1 = c8 * (O1i - O1r);
    float p3 = c8 * (O3r + O3i), q3 = c8 * (O3i - O3r);
    xr[0] = E0r + O0r; xi[0] = E0i + O0i;
    xr[4] = E0r - O0r; xi[4] = E0i - O0i;
    xr[1] = E1r + p1;  xi[1] = E1i + q1;
    xr[5] = E1r - p1;  xi[5] = E1i - q1;
    xr[2] = E2r + O2i; xi[2] = E2i - O2r;
    xr[6] = E2r - O2i; xi[6] = E2i + O2r;
    xr[3] = E3r + q3;  xi[3] = E3i - p3;
    xr[7] = E3r - q3;  xi[7] = E3i + p3;
}

__device__ __forceinline__ int padc(int p) { return p + (p >> 5); }

// ---------------------------------------------------------------------------
// fft_corr: per (b, 8 d-columns): z = q + i*k read coalesced from transposed
// layout qt/kt[b][d][t]; register-blocked mixed-radix FFT (8*8*8*4);
// Hermitian split -> accumulate P = Q*conj(K) into G[b][1025][2].
// grid = 2048 (16 b x 128 chunks), block = 256.
// ---------------------------------------------------------------------------
__global__ __launch_bounds__(256)
void fft_corr(const unsigned short* __restrict__ qt, const unsigned short* __restrict__ kt,
              float* __restrict__ G) {
    __shared__ float2 zc[2112];
    __shared__ float accR[1025], accI[1025];
    float* zfr = (float*)zc;
    float* zfi = zfr + 2112;
    const int tid = threadIdx.x;
    const int b = blockIdx.x >> 7;
    const int chunk = blockIdx.x & 127;

    const float N2PI = -6.28318530717958647692f;
    float w1r, w1i, w2r, w2i, w3r, w3i;
    {
        float s, c;
        __sincosf(N2PI * (float)tid * (1.0f / 2048.0f), &s, &c); w1r = c; w1i = s;
        __sincosf(N2PI * (float)(tid & 31) * (1.0f / 256.0f), &s, &c); w2r = c; w2i = s;
        __sincosf(N2PI * (float)(tid & 3) * (1.0f / 32.0f),  &s, &c); w3r = c; w3i = s;
    }

    for (int f = tid; f < 1025; f += 256) { accR[f] = 0.f; accI[f] = 0.f; }

    const int beta = tid >> 5, s2 = tid & 31;
    const int gam  = tid >> 2, u3 = tid & 3;

    for (int r = 0; r < 8; ++r) {
        const int d = chunk * 8 + r;
        const unsigned short* qrow = qt + ((size_t)b * 1024 + d) * 2048;
        const unsigned short* krow = kt + ((size_t)b * 1024 + d) * 2048;

        float xr[8], xi[8];
#pragma unroll
        for (int k = 0; k < 8; ++k) {
            xr[k] = bf2f(qrow[tid + 256 * k]);
            xi[k] = bf2f(krow[tid + 256 * k]);
        }
        dft8(xr, xi);
        {
            float cr_ = w1r, ci_ = w1i;
#pragma unroll
            for (int k = 1; k < 8; ++k) {
                float tr = xr[k] * cr_ - xi[k] * ci_;
                float ti = xr[k] * ci_ + xi[k] * cr_;
                xr[k] = tr; xi[k] = ti;
                if (k < 7) {
                    float nr = cr_ * w1r - ci_ * w1i;
                    float ni = cr_ * w1i + ci_ * w1r;
                    cr_ = nr; ci_ = ni;
                }
            }
        }
#pragma unroll
        for (int k = 0; k < 8; ++k) zc[padc(256 * k + tid)] = make_float2(xr[k], xi[k]);
        __syncthreads();

#pragma unroll
        for (int k = 0; k < 8; ++k) {
            float2 v = zc[padc(256 * beta + 32 * k + s2)];
            xr[k] = v.x; xi[k] = v.y;
        }
        __syncthreads();
        dft8(xr, xi);
        {
            float cr_ = w2r, ci_ = w2i;
#pragma unroll
            for (int k = 1; k < 8; ++k) {
                float tr = xr[k] * cr_ - xi[k] * ci_;
                float ti = xr[k] * ci_ + xi[k] * cr_;
                xr[k] = tr; xi[k] = ti;
                if (k < 7) {
                    float nr = cr_ * w2r - ci_ * w2i;
                    float ni = cr_ * w2i + ci_ * w2r;
                    cr_ = nr; ci_ = ni;
                }
            }
        }
#pragma unroll
        for (int k = 0; k < 8; ++k) zc[padc(256 * beta + 32 * k + s2)] = make_float2(xr[k], xi[k]);
        __syncthreads();

#pragma unroll
        for (int k = 0; k < 8; ++k) {
            float2 v = zc[padc(32 * gam + 4 * k + u3)];
            xr[k] = v.x; xi[k] = v.y;
        }
        __syncthreads();
        dft8(xr, xi);
        {
            float cr_ = w3r, ci_ = w3i;
#pragma unroll
            for (int k = 1; k < 8; ++k) {
                float tr = xr[k] * cr_ - xi[k] * ci_;
                float ti = xr[k] * ci_ + xi[k] * cr_;
                xr[k] = tr; xi[k] = ti;
                if (k < 7) {
                    float nr = cr_ * w3r - ci_ * w3i;
                    float ni = cr_ * w3i + ci_ * w3r;
                    cr_ = nr; ci_ = ni;
                }
            }
        }
#pragma unroll
        for (int k = 0; k < 8; ++k) zc[padc(32 * gam + 4 * k + u3)] = make_float2(xr[k], xi[k]);
        __syncthreads();

#pragma unroll
        for (int k = 0; k < 8; ++k) {
            float2 v = zc[padc(8 * tid + k)];
            xr[k] = v.x; xi[k] = v.y;
        }
        __syncthreads();

        float Xr[8], Xi[8];
#pragma unroll
        for (int blk = 0; blk < 2; ++blk) {
            const int o = 4 * blk;
            float s0r = xr[o] + xr[o + 2], s0i = xi[o] + xi[o + 2];
            float s1r = xr[o] - xr[o + 2], s1i = xi[o] - xi[o + 2];
            float s2r = xr[o + 1] + xr[o + 3], s2i = xi[o + 1] + xi[o + 3];
            float s3r = xr[o + 1] - xr[o + 3], s3i = xi[o + 1] - xi[o + 3];
            Xr[o + 0] = s0r + s2r; Xi[o + 0] = s0i + s2i;
            Xr[o + 2] = s0r - s2r; Xi[o + 2] = s0i - s2i;
            Xr[o + 1] = s1r + s3i; Xi[o + 1] = s1i - s3r;
            Xr[o + 3] = s1r - s3i; Xi[o + 3] = s1i + s3r;
        }
        {
            const int k1 = tid >> 5;
            const int k2 = (tid >> 2) & 7;
            const int fb = k1 + 8 * k2;
#pragma unroll
            for (int blk = 0; blk < 2; ++blk) {
                const int k3 = (2 * (tid & 3) + blk) & 7;
#pragma unroll
                for (int k4 = 0; k4 < 4; ++k4) {
                    const int f = fb + 64 * k3 + 512 * k4;
                    const int pf = padc(f);
                    zfr[pf] = Xr[4 * blk + k4];
                    zfi[pf] = Xi[4 * blk + k4];
                }
            }
        }
        __syncthreads();

        for (int f = tid; f < 1025; f += 256) {
            const int f2 = (2048 - f) & 2047;
            const int pf = padc(f), pf2 = padc(f2);
            float Zr = zfr[pf],  Zi = zfi[pf];
            float Yr = zfr[pf2], Yi = -zfi[pf2];
            float Qr = 0.5f * (Zr + Yr), Qi = 0.5f * (Zi + Yi);
            float Kr = 0.5f * (Zi - Yi), Ki = -0.5f * (Zr - Yr);
            accR[f] += Qr * Kr + Qi * Ki;
            accI[f] += Qi * Kr - Qr * Ki;
        }
        __syncthreads();
    }

    for (int f = tid; f < 1025; f += 256) {
        atomicAdd(&G[((size_t)b * 1025 + f) * 2 + 0], accR[f]);
        atomicAdd(&G[((size_t)b * 1025 + f) * 2 + 1], accI[f]);
    }
}

// ---------------------------------------------------------------------------
// In-LDS radix-2 DIT FFT, N=2048 (only used by irfft_mean: 16 blocks, cheap).
// ---------------------------------------------------------------------------
__device__ __forceinline__ void fft2048(float* zr, float* zi,
                                        const float* twr, const float* twi, int tid) {
    for (int t = tid; t < 2048; t += 256) {
        int j = __brev((unsigned)t) >> 21;
        if (j > t) {
            float a = zr[t]; zr[t] = zr[j]; zr[j] = a;
            float c = zi[t]; zi[t] = zi[j]; zi[j] = c;
        }
    }
    __syncthreads();
    for (int s = 0; s < 11; ++s) {
        const int m = 1 << s;
        for (int i = tid; i < 1024; i += 256) {
            const int pos = i & (m - 1);
            const int i1  = ((i >> s) << (s + 1)) + pos;
            const int i2  = i1 + m;
            const int tw  = pos << (10 - s);
            float wr = twr[tw], wi = twi[tw];
            float xr = zr[i2], xi = zi[i2];
            float tr = wr * xr - wi * xi;
            float ti = wr * xi + wi * xr;
            float ur = zr[i1], ui = zi[i1];
            zr[i2] = ur - tr; zi[i2] = ui - ti;
            zr[i1] = ur + tr; zi[i1] = ui + ti;
        }
        __syncthreads();
    }
}

__device__ __forceinline__ void init_twiddle(float* twr, float* twi, int tid) {
    for (int j = tid; j < 1024; j += 256) {
        float ang = -6.28318530717958647692f * (float)j * (1.0f / 2048.0f);
        twr[j] = cosf(ang);
        twi[j] = sinf(ang);
    }
}

// ---------------------------------------------------------------------------
// Per-batch irfft of G -> mean_value[b][t], scale 1/(2048*1024). grid = 16.
// ---------------------------------------------------------------------------
__global__ __launch_bounds__(256)
void irfft_mean(const float* __restrict__ G, float* __restrict__ mv) {
    __shared__ float zr[2048], zi[2048];
    __shared__ float twr[1024], twi[1024];
    const int tid = threadIdx.x;
    const int b = blockIdx.x;
    init_twiddle(twr, twi, tid);
    for (int f = tid; f < 2048; f += 256) {
        int g = (f <= 1024) ? f : 2048 - f;
        float gr = G[((size_t)b * 1025 + g) * 2 + 0];
        float gi = G[((size_t)b * 1025 + g) * 2 + 1];
        zr[f] = gr;
        zi[f] = (f <= 1024) ? -gi : gi;
    }
    __syncthreads();
    fft2048(zr, zi, twr, twi, tid);
    const float sc = 1.0f / (2048.0f * 1024.0f);
    for (int t = tid; t < 2048; t += 256) mv[b * 2048 + t] = zr[t] * sc;
}

// ---------------------------------------------------------------------------
// Top-7 over batch-mean of mean_value + per-batch softmax of gathered weights.
// ---------------------------------------------------------------------------
__global__ __launch_bounds__(256)
void topk_softmax(const float* __restrict__ mv, int* __restrict__ idx_out,
                  float* __restrict__ w_out) {
    __shared__ float cm[2048];
    __shared__ float bval[256];
    __shared__ int   bidx[256];
    __shared__ int   sel[7];
    const int tid = threadIdx.x;
    for (int t = tid; t < 2048; t += 256) {
        float s = 0.f;
        for (int b = 0; b < 16; ++b) s += mv[b * 2048 + t];
        cm[t] = s * (1.0f / 16.0f);
    }
    __syncthreads();
    for (int it = 0; it < 7; ++it) {
        float best = -3.4e38f; int bi = 1 << 30;
        for (int t = tid; t < 2048; t += 256) {
            float v = cm[t];
            if (v > best || (v == best && t < bi)) { best = v; bi = t; }
        }
        bval[tid] = best; bidx[tid] = bi;
        __syncthreads();
        if (tid == 0) {
            float bb = bval[0]; int bj = bidx[0];
            for (int u = 1; u < 256; ++u)
                if (bval[u] > bb || (bval[u] == bb && bidx[u] < bj)) { bb = bval[u]; bj = bidx[u]; }
            sel[it] = bj;
            idx_out[it] = bj;
            cm[bj] = -3.4e38f;
        }
        __syncthreads();
    }
    if (tid < 16) {
        const int b = tid;
        float wv[7]; float mx = -3.4e38f;
#pragma unroll
        for (int i = 0; i < 7; ++i) { wv[i] = mv[b * 2048 + sel[i]]; mx = fmaxf(mx, wv[i]); }
        float s = 0.f;
#pragma unroll
        for (int i = 0; i < 7; ++i) { wv[i] = expf(wv[i] - mx); s += wv[i]; }
        float inv = 1.0f / s;
#pragma unroll
        for (int i = 0; i < 7; ++i) w_out[b * 7 + i] = wv[i] * inv;
    }
}

// ---------------------------------------------------------------------------
// agg[b,t,d] = sum_i w[b,i] * vp[b,(t+idx[i])%2048,d]  (bf16 in/out)
// ---------------------------------------------------------------------------
__global__ __launch_bounds__(256)
void agg_kernel(const unsigned short* __restrict__ vp, const int* __restrict__ idx,
                const float* __restrict__ w, unsigned short* __restrict__ agg) {
    const int b  = blockIdx.y;
    const int t  = blockIdx.x * 2 + (threadIdx.x >> 7);
    const int d8 = (threadIdx.x & 127) * 8;
    float av[8] = {0.f, 0.f, 0.f, 0.f, 0.f, 0.f, 0.f, 0.f};
#pragma unroll
    for (int i = 0; i < 7; ++i) {
        const int srow = (t + idx[i]) & 2047;
        const float wi = w[b * 7 + i];
        bf16x8 v = *(const bf16x8*)&vp[((size_t)b * 2048 + srow) * 1024 + d8];
#pragma unroll
        for (int j = 0; j < 8; ++j) av[j] += wi * bf2f((unsigned short)v[j]);
    }
    bf16x8 o;
#pragma unroll
    for (int j = 0; j < 8; ++j) o[j] = (short)f2bf(av[j]);
    *(bf16x8*)&agg[((size_t)b * 2048 + t) * 1024 + d8] = o;
}

// ---------------------------------------------------------------------------
__global__ __launch_bounds__(256)
void cast_w(const float* __restrict__ src, unsigned short* __restrict__ dst) {
    const int i = (blockIdx.x * 256 + threadIdx.x) * 4;   // n = 1048576 exact
    f32x4 v = *(const f32x4*)(src + i);
    s16x4 o;
#pragma unroll
    for (int j = 0; j < 4; ++j) o[j] = (short)f2bf(v[j]);
    *(s16x4*)(dst + i) = o;
}

__global__ __launch_bounds__(256)
void zero_f32(float* __restrict__ p, int n) {
    const int i = blockIdx.x * 256 + threadIdx.x;
    if (i < n) p[i] = 0.0f;
}

// ---------------------------------------------------------------------------
extern "C" void kernel_launch(void* const* d_in, const int* in_sizes, int n_in,
                              void* d_out, int out_size, void* d_ws, size_t ws_size,
                              hipStream_t stream) {
    const float* queries = (const float*)d_in[0];
    const float* keys    = (const float*)d_in[1];
    const float* values  = (const float*)d_in[2];
    const float* Wq = (const float*)d_in[3];  const float* bq = (const float*)d_in[4];
    const float* Wk = (const float*)d_in[5];  const float* bk = (const float*)d_in[6];
    const float* Wv = (const float*)d_in[7];  const float* bv = (const float*)d_in[8];
    const float* Wo = (const float*)d_in[9];  const float* bo = (const float*)d_in[10];
    float* out = (float*)d_out;

    char* ws = (char*)d_ws;
    constexpr size_t SZP = (size_t)32768 * 1024 * 2;           // 64 MB (bf16 B*L*D)
    unsigned short* qt  = (unsigned short*)(ws);               // [b][d][t]; reused as agg
    unsigned short* kt  = (unsigned short*)(ws + SZP);         // [b][d][t]
    unsigned short* vp  = (unsigned short*)(ws + 2 * SZP);     // [b][t][d]
    unsigned short* w16 = (unsigned short*)(ws + 3 * SZP);     // 4 x 1M bf16
    float* G   = (float*)(ws + 3 * SZP + 8388608);             // 16*1025*2 f32
    float* mv  = (float*)(ws + 3 * SZP + 8388608 + 131328);    // 16*2048 f32
    int*   idx = (int*)  (ws + 3 * SZP + 8388608 + 131328 + 131072);
    float* wsm = (float*)(ws + 3 * SZP + 8388608 + 131328 + 131072 + 64);
    unsigned short* agg = qt;

    cast_w<<<1024, 256, 0, stream>>>(Wq, w16 + 0 * 1048576);
    cast_w<<<1024, 256, 0, stream>>>(Wk, w16 + 1 * 1048576);
    cast_w<<<1024, 256, 0, stream>>>(Wv, w16 + 2 * 1048576);
    cast_w<<<1024, 256, 0, stream>>>(Wo, w16 + 3 * 1048576);
    zero_f32<<<(32800 + 255) / 256, 256, 0, stream>>>(G, 32800);

    gemm_glds<true, 2><<<2048, 256, 0, stream>>>(queries, w16 + 0 * 1048576, bq, qt);
    gemm_glds<true, 2><<<2048, 256, 0, stream>>>(keys,    w16 + 1 * 1048576, bk, kt);
    gemm_glds<true, 0><<<2048, 256, 0, stream>>>(values,  w16 + 2 * 1048576, bv, vp);

    fft_corr<<<2048, 256, 0, stream>>>(qt, kt, G);
    irfft_mean<<<16, 256, 0, stream>>>(G, mv);
    topk_softmax<<<1, 256, 0, stream>>>(mv, idx, wsm);
    agg_kernel<<<dim3(1024, 16), 256, 0, stream>>>(vp, idx, wsm, agg);

    gemm_glds<false, 1><<<2048, 256, 0, stream>>>(agg, w16 + 3 * 1048576, bo, out);
}

// Round 5
// 743.962 us; speedup vs baseline: 1.3718x; 1.0652x over previous
//
#include <hip/hip_runtime.h>

typedef __attribute__((ext_vector_type(8))) short bf16x8;
typedef __attribute__((ext_vector_type(4))) short s16x4;
typedef __attribute__((ext_vector_type(4))) float f32x4;

__device__ __forceinline__ float bf2f(unsigned short u) {
    union { unsigned int u; float f; } x; x.u = ((unsigned int)u) << 16; return x.f;
}
__device__ __forceinline__ unsigned short f2bf(float f) {
    union { float f; unsigned int u; } x; x.f = f;
    unsigned int u = x.u;
    unsigned int r = (u + 0x7fffu + ((u >> 16) & 1u)) >> 16;
    return (unsigned short)r;
}

#define GLDS16(gp, lp)                                                        \
    __builtin_amdgcn_global_load_lds(                                         \
        (const __attribute__((address_space(1))) void*)(gp),                  \
        (__attribute__((address_space(3))) void*)(lp), 16, 0, 0)

// ---------------------------------------------------------------------------
// GEMM: C[M=32768, N=1024] = A[M,K=1024] @ W^T + bias. A,W bf16 (W=[N,K]).
// 256x256 tile, BK=64, 8 waves (2M x 4N, each 128x64), LDS 128KB dbuf.
// Depth-2 prefetch, counted s_waitcnt vmcnt(8) (never 0 mid-loop), raw
// s_barrier (no compiler vmcnt(0) drain), setprio around MFMA clusters.
// Staging: linear LDS dest via global_load_lds w=16 + XOR-swizzled global
// source; fragment reads apply the same XOR (round-4-verified: conflicts=0).
// OUT_MODE: 0 = bf16 [row][col], 1 = f32 [row][col], 2 = bf16 transposed
//           [b][col][t] (row = b*2048+t).
// grid = 512 blocks (XCD-chunked bijective swizzle), block = 512.
// ---------------------------------------------------------------------------
template<int OUT_MODE>
__global__ __launch_bounds__(512, 2)
void gemm256(const unsigned short* __restrict__ A, const unsigned short* __restrict__ Bw,
             const float* __restrict__ bias, void* __restrict__ out_) {
    __shared__ __align__(16) unsigned short sA[2][16384];   // [buf][256*64]
    __shared__ __align__(16) unsigned short sB[2][16384];

    const int tid  = threadIdx.x;
    const int lane = tid & 63;
    const int w    = tid >> 6;          // 0..7
    const int wr   = w >> 2, wc = w & 3;
    const int fr   = lane & 15, g4 = lane >> 4;

    // XCD-chunked bijective swizzle (nwg=512, 8 XCDs, q=64)
    const int bid = blockIdx.x;
    const int swz = (bid & 7) * 64 + (bid >> 3);
    const int  col0 = (swz & 3) * 256;
    const long row0 = (long)(swz >> 2) * 256;

    // staging source: unit u = r*512+tid; row=u>>3, j=u&7, src unit j^(row&7)
    const int srow = tid >> 3;                     // 0..63 (row within issue r=0)
    const int sj   = (tid & 7) ^ (srow & 7);
    const unsigned short* gA = A  + (size_t)(row0 + srow) * 1024 + sj * 8;
    const unsigned short* gB = Bw + (size_t)(col0 + srow) * 1024 + sj * 8;
    const int ldst = w * 1024;                     // wave-uniform byte base

    auto stage = [&](int buf, int t) {
        const unsigned short* a = gA + t * 64;
        const unsigned short* b = gB + t * 64;
        char* dA = (char*)&sA[buf][0];
        char* dB = (char*)&sB[buf][0];
#pragma unroll
        for (int r = 0; r < 4; ++r)
            GLDS16(a + r * 65536, (__attribute__((address_space(3))) char*)(dA + r * 8192 + ldst));
#pragma unroll
        for (int r = 0; r < 4; ++r)
            GLDS16(b + r * 65536, (__attribute__((address_space(3))) char*)(dB + r * 8192 + ldst));
    };

    f32x4 acc[8][4];
#pragma unroll
    for (int m = 0; m < 8; ++m)
#pragma unroll
        for (int n = 0; n < 4; ++n) acc[m][n] = (f32x4){0.f, 0.f, 0.f, 0.f};

    stage(0, 0);
    stage(1, 1);

    const int mskK = (fr & 7) << 4;   // (row&7)<<4 for all fragment rows (16|row-fr)

    for (int t = 0; t < 16; ++t) {
        if (t < 15) asm volatile("s_waitcnt vmcnt(8)" ::: "memory");
        else        asm volatile("s_waitcnt vmcnt(0)" ::: "memory");
        asm volatile("s_barrier" ::: "memory");
        __builtin_amdgcn_sched_barrier(0);

        const char* la = (const char*)&sA[t & 1][0];
        const char* lb = (const char*)&sB[t & 1][0];

        bf16x8 bF[2][4];
#pragma unroll
        for (int c = 0; c < 2; ++c)
#pragma unroll
            for (int n = 0; n < 4; ++n) {
                const int row = wc * 64 + n * 16 + fr;
                bF[c][n] = *(const bf16x8*)(lb + row * 128 + ((c * 64 + g4 * 16) ^ mskK));
            }
#pragma unroll
        for (int mh = 0; mh < 2; ++mh) {
            bf16x8 aF[2][4];
#pragma unroll
            for (int c = 0; c < 2; ++c)
#pragma unroll
                for (int m = 0; m < 4; ++m) {
                    const int row = wr * 128 + mh * 64 + m * 16 + fr;
                    aF[c][m] = *(const bf16x8*)(la + row * 128 + ((c * 64 + g4 * 16) ^ mskK));
                }
            __builtin_amdgcn_s_setprio(1);
#pragma unroll
            for (int c = 0; c < 2; ++c)
#pragma unroll
                for (int n = 0; n < 4; ++n)
#pragma unroll
                    for (int m = 0; m < 4; ++m)
                        acc[mh * 4 + m][n] =
                            __builtin_amdgcn_mfma_f32_16x16x32_bf16(aF[c][m], bF[c][n], acc[mh * 4 + m][n], 0, 0, 0);
            __builtin_amdgcn_s_setprio(0);
        }

        __builtin_amdgcn_sched_barrier(0);
        asm volatile("s_barrier" ::: "memory");   // all waves done reading buf[t&1]
        if (t + 2 < 16) stage(t & 1, t + 2);      // overwrite freed buffer
    }

    // C/D layout (m89-verified): col = lane&15, row = (lane>>4)*4 + j
    const int cr = g4 * 4;
    const int cc = fr;
    if constexpr (OUT_MODE == 2) {
        const int b  = (int)(row0 >> 11);
        const int tb = ((int)row0 & 2047) + wr * 128 + cr;
#pragma unroll
        for (int m = 0; m < 8; ++m) {
#pragma unroll
            for (int n = 0; n < 4; ++n) {
                int col = col0 + wc * 64 + n * 16 + cc;
                float bv = bias[col];
                s16x4 o;
#pragma unroll
                for (int j = 0; j < 4; ++j) o[j] = (short)f2bf(acc[m][n][j] + bv);
                *(s16x4*)&((unsigned short*)out_)[((size_t)b * 1024 + col) * 2048 + tb + m * 16] = o;
            }
        }
    } else {
#pragma unroll
        for (int m = 0; m < 8; ++m) {
            long row = row0 + wr * 128 + m * 16 + cr;
#pragma unroll
            for (int n = 0; n < 4; ++n) {
                int col = col0 + wc * 64 + n * 16 + cc;
                float bv = bias[col];
#pragma unroll
                for (int j = 0; j < 4; ++j) {
                    float v = acc[m][n][j] + bv;
                    if constexpr (OUT_MODE == 1) ((float*)out_)[(row + j) * 1024 + col] = v;
                    else ((unsigned short*)out_)[(row + j) * 1024 + col] = f2bf(v);
                }
            }
        }
    }
}

// ---------------------------------------------------------------------------
// fp32 -> bf16 cast, 8 elems/thread. n = 33554432 exact (grid 16384 x 256).
// ---------------------------------------------------------------------------
__global__ __launch_bounds__(256)
void cast_f2b(const float* __restrict__ src, unsigned short* __restrict__ dst) {
    const size_t i = ((size_t)blockIdx.x * 256 + threadIdx.x) * 8;
    f32x4 v0 = *(const f32x4*)(src + i);
    f32x4 v1 = *(const f32x4*)(src + i + 4);
    bf16x8 o;
#pragma unroll
    for (int j = 0; j < 4; ++j) o[j] = (short)f2bf(v0[j]);
#pragma unroll
    for (int j = 0; j < 4; ++j) o[4 + j] = (short)f2bf(v1[j]);
    *(bf16x8*)(dst + i) = o;
}

// ---------------------------------------------------------------------------
// 8-point DFT (negative exponent), in place on xr/xi[8].
// ---------------------------------------------------------------------------
__device__ __forceinline__ void dft8(float* xr, float* xi) {
    const float c8 = 0.70710678118654752440f;
    float es0r = xr[0] + xr[4], es0i = xi[0] + xi[4];
    float es1r = xr[0] - xr[4], es1i = xi[0] - xi[4];
    float es2r = xr[2] + xr[6], es2i = xi[2] + xi[6];
    float es3r = xr[2] - xr[6], es3i = xi[2] - xi[6];
    float E0r = es0r + es2r, E0i = es0i + es2i;
    float E2r = es0r - es2r, E2i = es0i - es2i;
    float E1r = es1r + es3i, E1i = es1i - es3r;
    float E3r = es1r - es3i, E3i = es1i + es3r;
    float os0r = xr[1] + xr[5], os0i = xi[1] + xi[5];
    float os1r = xr[1] - xr[5], os1i = xi[1] - xi[5];
    float os2r = xr[3] + xr[7], os2i = xi[3] + xi[7];
    float os3r = xr[3] - xr[7], os3i = xi[3] - xi[7];
    float O0r = os0r + os2r, O0i = os0i + os2i;
    float O2r = os0r - os2r, O2i = os0i - os2i;
    float O1r = os1r + os3i, O1i = os1i - os3r;
    float O3r = os1r - os3i, O3i = os1i + os3r;
    float p1 = c8 * (O1r + O1i), q1 = c8 * (O1i - O1r);
    float p3 = c8 * (O3r + O3i), q3 = c8 * (O3i - O3r);
    xr[0] = E0r + O0r; xi[0] = E0i + O0i;
    xr[4] = E0r - O0r; xi[4] = E0i - O0i;
    xr[1] = E1r + p1;  xi[1] = E1i + q1;
    xr[5] = E1r - p1;  xi[5] = E1i - q1;
    xr[2] = E2r + O2i; xi[2] = E2i - O2r;
    xr[6] = E2r - O2i; xi[6] = E2i + O2r;
    xr[3] = E3r + q3;  xi[3] = E3i - p3;
    xr[7] = E3r - q3;  xi[7] = E3i + p3;
}

__device__ __forceinline__ int padc(int p) { return p + (p >> 5); }

// ---------------------------------------------------------------------------
// fft_corr: per (b, 8 d-columns): z = q + i*k read coalesced from transposed
// layout qt/kt[b][d][t]; register-blocked mixed-radix FFT (8*8*8*4);
// Hermitian split -> accumulate P = Q*conj(K) into G[b][1025][2].
// grid = 2048 (16 b x 128 chunks), block = 256.
// ---------------------------------------------------------------------------
__global__ __launch_bounds__(256)
void fft_corr(const unsigned short* __restrict__ qt, const unsigned short* __restrict__ kt,
              float* __restrict__ G) {
    __shared__ float2 zc[2112];
    __shared__ float accR[1025], accI[1025];
    float* zfr = (float*)zc;
    float* zfi = zfr + 2112;
    const int tid = threadIdx.x;
    const int b = blockIdx.x >> 7;
    const int chunk = blockIdx.x & 127;

    const float N2PI = -6.28318530717958647692f;
    float w1r, w1i, w2r, w2i, w3r, w3i;
    {
        float s, c;
        __sincosf(N2PI * (float)tid * (1.0f / 2048.0f), &s, &c); w1r = c; w1i = s;
        __sincosf(N2PI * (float)(tid & 31) * (1.0f / 256.0f), &s, &c); w2r = c; w2i = s;
        __sincosf(N2PI * (float)(tid & 3) * (1.0f / 32.0f),  &s, &c); w3r = c; w3i = s;
    }

    for (int f = tid; f < 1025; f += 256) { accR[f] = 0.f; accI[f] = 0.f; }

    const int beta = tid >> 5, s2 = tid & 31;
    const int gam  = tid >> 2, u3 = tid & 3;

    for (int r = 0; r < 8; ++r) {
        const int d = chunk * 8 + r;
        const unsigned short* qrow = qt + ((size_t)b * 1024 + d) * 2048;
        const unsigned short* krow = kt + ((size_t)b * 1024 + d) * 2048;

        float xr[8], xi[8];
#pragma unroll
        for (int k = 0; k < 8; ++k) {
            xr[k] = bf2f(qrow[tid + 256 * k]);
            xi[k] = bf2f(krow[tid + 256 * k]);
        }
        dft8(xr, xi);
        {
            float cr_ = w1r, ci_ = w1i;
#pragma unroll
            for (int k = 1; k < 8; ++k) {
                float tr = xr[k] * cr_ - xi[k] * ci_;
                float ti = xr[k] * ci_ + xi[k] * cr_;
                xr[k] = tr; xi[k] = ti;
                if (k < 7) {
                    float nr = cr_ * w1r - ci_ * w1i;
                    float ni = cr_ * w1i + ci_ * w1r;
                    cr_ = nr; ci_ = ni;
                }
            }
        }
#pragma unroll
        for (int k = 0; k < 8; ++k) zc[padc(256 * k + tid)] = make_float2(xr[k], xi[k]);
        __syncthreads();

#pragma unroll
        for (int k = 0; k < 8; ++k) {
            float2 v = zc[padc(256 * beta + 32 * k + s2)];
            xr[k] = v.x; xi[k] = v.y;
        }
        __syncthreads();
        dft8(xr, xi);
        {
            float cr_ = w2r, ci_ = w2i;
#pragma unroll
            for (int k = 1; k < 8; ++k) {
                float tr = xr[k] * cr_ - xi[k] * ci_;
                float ti = xr[k] * ci_ + xi[k] * cr_;
                xr[k] = tr; xi[k] = ti;
                if (k < 7) {
                    float nr = cr_ * w2r - ci_ * w2i;
                    float ni = cr_ * w2i + ci_ * w2r;
                    cr_ = nr; ci_ = ni;
                }
            }
        }
#pragma unroll
        for (int k = 0; k < 8; ++k) zc[padc(256 * beta + 32 * k + s2)] = make_float2(xr[k], xi[k]);
        __syncthreads();

#pragma unroll
        for (int k = 0; k < 8; ++k) {
            float2 v = zc[padc(32 * gam + 4 * k + u3)];
            xr[k] = v.x; xi[k] = v.y;
        }
        __syncthreads();
        dft8(xr, xi);
        {
            float cr_ = w3r, ci_ = w3i;
#pragma unroll
            for (int k = 1; k < 8; ++k) {
                float tr = xr[k] * cr_ - xi[k] * ci_;
                float ti = xr[k] * ci_ + xi[k] * cr_;
                xr[k] = tr; xi[k] = ti;
                if (k < 7) {
                    float nr = cr_ * w3r - ci_ * w3i;
                    float ni = cr_ * w3i + ci_ * w3r;
                    cr_ = nr; ci_ = ni;
                }
            }
        }
#pragma unroll
        for (int k = 0; k < 8; ++k) zc[padc(32 * gam + 4 * k + u3)] = make_float2(xr[k], xi[k]);
        __syncthreads();

#pragma unroll
        for (int k = 0; k < 8; ++k) {
            float2 v = zc[padc(8 * tid + k)];
            xr[k] = v.x; xi[k] = v.y;
        }
        __syncthreads();

        float Xr[8], Xi[8];
#pragma unroll
        for (int blk = 0; blk < 2; ++blk) {
            const int o = 4 * blk;
            float s0r = xr[o] + xr[o + 2], s0i = xi[o] + xi[o + 2];
            float s1r = xr[o] - xr[o + 2], s1i = xi[o] - xi[o + 2];
            float s2r = xr[o + 1] + xr[o + 3], s2i = xi[o + 1] + xi[o + 3];
            float s3r = xr[o + 1] - xr[o + 3], s3i = xi[o + 1] - xi[o + 3];
            Xr[o + 0] = s0r + s2r; Xi[o + 0] = s0i + s2i;
            Xr[o + 2] = s0r - s2r; Xi[o + 2] = s0i - s2i;
            Xr[o + 1] = s1r + s3i; Xi[o + 1] = s1i - s3r;
            Xr[o + 3] = s1r - s3i; Xi[o + 3] = s1i + s3r;
        }
        {
            const int k1 = tid >> 5;
            const int k2 = (tid >> 2) & 7;
            const int fb = k1 + 8 * k2;
#pragma unroll
            for (int blk = 0; blk < 2; ++blk) {
                const int k3 = (2 * (tid & 3) + blk) & 7;
#pragma unroll
                for (int k4 = 0; k4 < 4; ++k4) {
                    const int f = fb + 64 * k3 + 512 * k4;
                    const int pf = padc(f);
                    zfr[pf] = Xr[4 * blk + k4];
                    zfi[pf] = Xi[4 * blk + k4];
                }
            }
        }
        __syncthreads();

        for (int f = tid; f < 1025; f += 256) {
            const int f2 = (2048 - f) & 2047;
            const int pf = padc(f), pf2 = padc(f2);
            float Zr = zfr[pf],  Zi = zfi[pf];
            float Yr = zfr[pf2], Yi = -zfi[pf2];
            float Qr = 0.5f * (Zr + Yr), Qi = 0.5f * (Zi + Yi);
            float Kr = 0.5f * (Zi - Yi), Ki = -0.5f * (Zr - Yr);
            accR[f] += Qr * Kr + Qi * Ki;
            accI[f] += Qi * Kr - Qr * Ki;
        }
        __syncthreads();
    }

    for (int f = tid; f < 1025; f += 256) {
        atomicAdd(&G[((size_t)b * 1025 + f) * 2 + 0], accR[f]);
        atomicAdd(&G[((size_t)b * 1025 + f) * 2 + 1], accI[f]);
    }
}

// ---------------------------------------------------------------------------
// In-LDS radix-2 DIT FFT, N=2048 (only used by irfft_mean: 16 blocks, cheap).
// ---------------------------------------------------------------------------
__device__ __forceinline__ void fft2048(float* zr, float* zi,
                                        const float* twr, const float* twi, int tid) {
    for (int t = tid; t < 2048; t += 256) {
        int j = __brev((unsigned)t) >> 21;
        if (j > t) {
            float a = zr[t]; zr[t] = zr[j]; zr[j] = a;
            float c = zi[t]; zi[t] = zi[j]; zi[j] = c;
        }
    }
    __syncthreads();
    for (int s = 0; s < 11; ++s) {
        const int m = 1 << s;
        for (int i = tid; i < 1024; i += 256) {
            const int pos = i & (m - 1);
            const int i1  = ((i >> s) << (s + 1)) + pos;
            const int i2  = i1 + m;
            const int tw  = pos << (10 - s);
            float wr = twr[tw], wi = twi[tw];
            float xr = zr[i2], xi = zi[i2];
            float tr = wr * xr - wi * xi;
            float ti = wr * xi + wi * xr;
            float ur = zr[i1], ui = zi[i1];
            zr[i2] = ur - tr; zi[i2] = ui - ti;
            zr[i1] = ur + tr; zi[i1] = ui + ti;
        }
        __syncthreads();
    }
}

__device__ __forceinline__ void init_twiddle(float* twr, float* twi, int tid) {
    for (int j = tid; j < 1024; j += 256) {
        float ang = -6.28318530717958647692f * (float)j * (1.0f / 2048.0f);
        twr[j] = cosf(ang);
        twi[j] = sinf(ang);
    }
}

// ---------------------------------------------------------------------------
// Per-batch irfft of G -> mean_value[b][t], scale 1/(2048*1024). grid = 16.
// ---------------------------------------------------------------------------
__global__ __launch_bounds__(256)
void irfft_mean(const float* __restrict__ G, float* __restrict__ mv) {
    __shared__ float zr[2048], zi[2048];
    __shared__ float twr[1024], twi[1024];
    const int tid = threadIdx.x;
    const int b = blockIdx.x;
    init_twiddle(twr, twi, tid);
    for (int f = tid; f < 2048; f += 256) {
        int g = (f <= 1024) ? f : 2048 - f;
        float gr = G[((size_t)b * 1025 + g) * 2 + 0];
        float gi = G[((size_t)b * 1025 + g) * 2 + 1];
        zr[f] = gr;
        zi[f] = (f <= 1024) ? -gi : gi;
    }
    __syncthreads();
    fft2048(zr, zi, twr, twi, tid);
    const float sc = 1.0f / (2048.0f * 1024.0f);
    for (int t = tid; t < 2048; t += 256) mv[b * 2048 + t] = zr[t] * sc;
}

// ---------------------------------------------------------------------------
// Top-7 over batch-mean of mean_value + per-batch softmax of gathered weights.
// ---------------------------------------------------------------------------
__global__ __launch_bounds__(256)
void topk_softmax(const float* __restrict__ mv, int* __restrict__ idx_out,
                  float* __restrict__ w_out) {
    __shared__ float cm[2048];
    __shared__ float bval[256];
    __shared__ int   bidx[256];
    __shared__ int   sel[7];
    const int tid = threadIdx.x;
    for (int t = tid; t < 2048; t += 256) {
        float s = 0.f;
        for (int b = 0; b < 16; ++b) s += mv[b * 2048 + t];
        cm[t] = s * (1.0f / 16.0f);
    }
    __syncthreads();
    for (int it = 0; it < 7; ++it) {
        float best = -3.4e38f; int bi = 1 << 30;
        for (int t = tid; t < 2048; t += 256) {
            float v = cm[t];
            if (v > best || (v == best && t < bi)) { best = v; bi = t; }
        }
        bval[tid] = best; bidx[tid] = bi;
        __syncthreads();
        if (tid == 0) {
            float bb = bval[0]; int bj = bidx[0];
            for (int u = 1; u < 256; ++u)
                if (bval[u] > bb || (bval[u] == bb && bidx[u] < bj)) { bb = bval[u]; bj = bidx[u]; }
            sel[it] = bj;
            idx_out[it] = bj;
            cm[bj] = -3.4e38f;
        }
        __syncthreads();
    }
    if (tid < 16) {
        const int b = tid;
        float wv[7]; float mx = -3.4e38f;
#pragma unroll
        for (int i = 0; i < 7; ++i) { wv[i] = mv[b * 2048 + sel[i]]; mx = fmaxf(mx, wv[i]); }
        float s = 0.f;
#pragma unroll
        for (int i = 0; i < 7; ++i) { wv[i] = expf(wv[i] - mx); s += wv[i]; }
        float inv = 1.0f / s;
#pragma unroll
        for (int i = 0; i < 7; ++i) w_out[b * 7 + i] = wv[i] * inv;
    }
}

// ---------------------------------------------------------------------------
// agg[b,t,d] = sum_i w[b,i] * vp[b,(t+idx[i])%2048,d]  (bf16 in/out)
// ---------------------------------------------------------------------------
__global__ __launch_bounds__(256)
void agg_kernel(const unsigned short* __restrict__ vp, const int* __restrict__ idx,
                const float* __restrict__ w, unsigned short* __restrict__ agg) {
    const int b  = blockIdx.y;
    const int t  = blockIdx.x * 2 + (threadIdx.x >> 7);
    const int d8 = (threadIdx.x & 127) * 8;
    float av[8] = {0.f, 0.f, 0.f, 0.f, 0.f, 0.f, 0.f, 0.f};
#pragma unroll
    for (int i = 0; i < 7; ++i) {
        const int srow = (t + idx[i]) & 2047;
        const float wi = w[b * 7 + i];
        bf16x8 v = *(const bf16x8*)&vp[((size_t)b * 2048 + srow) * 1024 + d8];
#pragma unroll
        for (int j = 0; j < 8; ++j) av[j] += wi * bf2f((unsigned short)v[j]);
    }
    bf16x8 o;
#pragma unroll
    for (int j = 0; j < 8; ++j) o[j] = (short)f2bf(av[j]);
    *(bf16x8*)&agg[((size_t)b * 2048 + t) * 1024 + d8] = o;
}

// ---------------------------------------------------------------------------
__global__ __launch_bounds__(256)
void cast_w(const float* __restrict__ src, unsigned short* __restrict__ dst) {
    const int i = (blockIdx.x * 256 + threadIdx.x) * 4;   // n = 1048576 exact
    f32x4 v = *(const f32x4*)(src + i);
    s16x4 o;
#pragma unroll
    for (int j = 0; j < 4; ++j) o[j] = (short)f2bf(v[j]);
    *(s16x4*)(dst + i) = o;
}

__global__ __launch_bounds__(256)
void zero_f32(float* __restrict__ p, int n) {
    const int i = blockIdx.x * 256 + threadIdx.x;
    if (i < n) p[i] = 0.0f;
}

// ---------------------------------------------------------------------------
extern "C" void kernel_launch(void* const* d_in, const int* in_sizes, int n_in,
                              void* d_out, int out_size, void* d_ws, size_t ws_size,
                              hipStream_t stream) {
    const float* queries = (const float*)d_in[0];
    const float* keys    = (const float*)d_in[1];
    const float* values  = (const float*)d_in[2];
    const float* Wq = (const float*)d_in[3];  const float* bq = (const float*)d_in[4];
    const float* Wk = (const float*)d_in[5];  const float* bk = (const float*)d_in[6];
    const float* Wv = (const float*)d_in[7];  const float* bv = (const float*)d_in[8];
    const float* Wo = (const float*)d_in[9];  const float* bo = (const float*)d_in[10];
    float* out = (float*)d_out;

    char* ws = (char*)d_ws;
    constexpr size_t SZP = (size_t)32768 * 1024 * 2;           // 64 MB (bf16 B*L*D)
    unsigned short* qt  = (unsigned short*)(ws);               // [b][d][t]; reused as agg
    unsigned short* kt  = (unsigned short*)(ws + SZP);         // [b][d][t]
    unsigned short* vp  = (unsigned short*)(ws + 2 * SZP);     // [b][t][d]
    unsigned short* ab  = (unsigned short*)(ws + 3 * SZP);     // bf16 A staging (reused 3x)
    unsigned short* w16 = (unsigned short*)(ws + 4 * SZP);     // 4 x 1M bf16
    float* G   = (float*)(ws + 4 * SZP + 8388608);             // 16*1025*2 f32
    float* mv  = (float*)(ws + 4 * SZP + 8388608 + 131328);    // 16*2048 f32
    int*   idx = (int*)  (ws + 4 * SZP + 8388608 + 131328 + 131072);
    float* wsm = (float*)(ws + 4 * SZP + 8388608 + 131328 + 131072 + 64);
    unsigned short* agg = qt;

    cast_w<<<1024, 256, 0, stream>>>(Wq, w16 + 0 * 1048576);
    cast_w<<<1024, 256, 0, stream>>>(Wk, w16 + 1 * 1048576);
    cast_w<<<1024, 256, 0, stream>>>(Wv, w16 + 2 * 1048576);
    cast_w<<<1024, 256, 0, stream>>>(Wo, w16 + 3 * 1048576);
    zero_f32<<<(32800 + 255) / 256, 256, 0, stream>>>(G, 32800);

    cast_f2b<<<16384, 256, 0, stream>>>(queries, ab);
    gemm256<2><<<512, 512, 0, stream>>>(ab, w16 + 0 * 1048576, bq, qt);
    cast_f2b<<<16384, 256, 0, stream>>>(keys, ab);
    gemm256<2><<<512, 512, 0, stream>>>(ab, w16 + 1 * 1048576, bk, kt);
    cast_f2b<<<16384, 256, 0, stream>>>(values, ab);
    gemm256<0><<<512, 512, 0, stream>>>(ab, w16 + 2 * 1048576, bv, vp);

    fft_corr<<<2048, 256, 0, stream>>>(qt, kt, G);
    irfft_mean<<<16, 256, 0, stream>>>(G, mv);
    topk_softmax<<<1, 256, 0, stream>>>(mv, idx, wsm);
    agg_kernel<<<dim3(1024, 16), 256, 0, stream>>>(vp, idx, wsm, agg);

    gemm256<1><<<512, 512, 0, stream>>>(agg, w16 + 3 * 1048576, bo, out);
}

// Round 6
// 626.418 us; speedup vs baseline: 1.6292x; 1.1876x over previous
//
#include <hip/hip_runtime.h>

typedef __attribute__((ext_vector_type(8))) short bf16x8;
typedef __attribute__((ext_vector_type(4))) short s16x4;
typedef __attribute__((ext_vector_type(4))) float f32x4;

__device__ __forceinline__ float bf2f(unsigned short u) {
    union { unsigned int u; float f; } x; x.u = ((unsigned int)u) << 16; return x.f;
}
__device__ __forceinline__ unsigned short f2bf(float f) {
    union { float f; unsigned int u; } x; x.f = f;
    unsigned int u = x.u;
    unsigned int r = (u + 0x7fffu + ((u >> 16) & 1u)) >> 16;
    return (unsigned short)r;
}

#define GLDS16(gp, lp)                                                        \
    __builtin_amdgcn_global_load_lds(                                         \
        (const __attribute__((address_space(1))) void*)(gp),                  \
        (__attribute__((address_space(3))) void*)(lp), 16, 0, 0)

// ---------------------------------------------------------------------------
// GEMM: C[M=32768, N=1024] = A[M,K=1024] @ W^T + bias. A,W bf16 (W=[N,K]).
// 256x256 tile, BK=64, 8 waves (2M x 4N, each 128x64), LDS 128KB dbuf.
// Depth-2 prefetch, counted s_waitcnt vmcnt(8) (never 0 mid-loop), raw
// s_barrier, setprio around MFMA clusters, XOR-swizzled staging (conflicts=0).
// OUT_MODE: 0 = bf16 [row][col], 1 = f32 [row][col], 2 = bf16 transposed
//           [b][col][t] (row = b*2048+t).
// grid = 512 blocks (XCD-chunked bijective swizzle), block = 512.
// ---------------------------------------------------------------------------
template<int OUT_MODE>
__global__ __launch_bounds__(512, 2)
void gemm256(const unsigned short* __restrict__ A, const unsigned short* __restrict__ Bw,
             const float* __restrict__ bias, void* __restrict__ out_) {
    __shared__ __align__(16) unsigned short sA[2][16384];   // [buf][256*64]
    __shared__ __align__(16) unsigned short sB[2][16384];

    const int tid  = threadIdx.x;
    const int lane = tid & 63;
    const int w    = tid >> 6;          // 0..7
    const int wr   = w >> 2, wc = w & 3;
    const int fr   = lane & 15, g4 = lane >> 4;

    // XCD-chunked bijective swizzle (nwg=512, 8 XCDs, q=64)
    const int bid = blockIdx.x;
    const int swz = (bid & 7) * 64 + (bid >> 3);
    const int  col0 = (swz & 3) * 256;
    const long row0 = (long)(swz >> 2) * 256;

    // staging source: unit u = r*512+tid; row=u>>3, j=u&7, src unit j^(row&7)
    const int srow = tid >> 3;                     // 0..63 (row within issue r=0)
    const int sj   = (tid & 7) ^ (srow & 7);
    const unsigned short* gA = A  + (size_t)(row0 + srow) * 1024 + sj * 8;
    const unsigned short* gB = Bw + (size_t)(col0 + srow) * 1024 + sj * 8;
    const int ldst = w * 1024;                     // wave-uniform byte base

    auto stage = [&](int buf, int t) {
        const unsigned short* a = gA + t * 64;
        const unsigned short* b = gB + t * 64;
        char* dA = (char*)&sA[buf][0];
        char* dB = (char*)&sB[buf][0];
#pragma unroll
        for (int r = 0; r < 4; ++r)
            GLDS16(a + r * 65536, (__attribute__((address_space(3))) char*)(dA + r * 8192 + ldst));
#pragma unroll
        for (int r = 0; r < 4; ++r)
            GLDS16(b + r * 65536, (__attribute__((address_space(3))) char*)(dB + r * 8192 + ldst));
    };

    f32x4 acc[8][4];
#pragma unroll
    for (int m = 0; m < 8; ++m)
#pragma unroll
        for (int n = 0; n < 4; ++n) acc[m][n] = (f32x4){0.f, 0.f, 0.f, 0.f};

    stage(0, 0);
    stage(1, 1);

    const int mskK = (fr & 7) << 4;   // (row&7)<<4 for all fragment rows (16|row-fr)

    for (int t = 0; t < 16; ++t) {
        if (t < 15) asm volatile("s_waitcnt vmcnt(8)" ::: "memory");
        else        asm volatile("s_waitcnt vmcnt(0)" ::: "memory");
        asm volatile("s_barrier" ::: "memory");
        __builtin_amdgcn_sched_barrier(0);

        const char* la = (const char*)&sA[t & 1][0];
        const char* lb = (const char*)&sB[t & 1][0];

        bf16x8 bF[2][4];
#pragma unroll
        for (int c = 0; c < 2; ++c)
#pragma unroll
            for (int n = 0; n < 4; ++n) {
                const int row = wc * 64 + n * 16 + fr;
                bF[c][n] = *(const bf16x8*)(lb + row * 128 + ((c * 64 + g4 * 16) ^ mskK));
            }
#pragma unroll
        for (int mh = 0; mh < 2; ++mh) {
            bf16x8 aF[2][4];
#pragma unroll
            for (int c = 0; c < 2; ++c)
#pragma unroll
                for (int m = 0; m < 4; ++m) {
                    const int row = wr * 128 + mh * 64 + m * 16 + fr;
                    aF[c][m] = *(const bf16x8*)(la + row * 128 + ((c * 64 + g4 * 16) ^ mskK));
                }
            __builtin_amdgcn_s_setprio(1);
#pragma unroll
            for (int c = 0; c < 2; ++c)
#pragma unroll
                for (int n = 0; n < 4; ++n)
#pragma unroll
                    for (int m = 0; m < 4; ++m)
                        acc[mh * 4 + m][n] =
                            __builtin_amdgcn_mfma_f32_16x16x32_bf16(aF[c][m], bF[c][n], acc[mh * 4 + m][n], 0, 0, 0);
            __builtin_amdgcn_s_setprio(0);
        }

        __builtin_amdgcn_sched_barrier(0);
        asm volatile("s_barrier" ::: "memory");   // all waves done reading buf[t&1]
        if (t + 2 < 16) stage(t & 1, t + 2);      // overwrite freed buffer
    }

    // C/D layout (m89-verified): col = lane&15, row = (lane>>4)*4 + j
    const int cr = g4 * 4;
    const int cc = fr;
    if constexpr (OUT_MODE == 2) {
        const int b  = (int)(row0 >> 11);
        const int tb = ((int)row0 & 2047) + wr * 128 + cr;
#pragma unroll
        for (int m = 0; m < 8; ++m) {
#pragma unroll
            for (int n = 0; n < 4; ++n) {
                int col = col0 + wc * 64 + n * 16 + cc;
                float bv = bias[col];
                s16x4 o;
#pragma unroll
                for (int j = 0; j < 4; ++j) o[j] = (short)f2bf(acc[m][n][j] + bv);
                *(s16x4*)&((unsigned short*)out_)[((size_t)b * 1024 + col) * 2048 + tb + m * 16] = o;
            }
        }
    } else {
#pragma unroll
        for (int m = 0; m < 8; ++m) {
            long row = row0 + wr * 128 + m * 16 + cr;
#pragma unroll
            for (int n = 0; n < 4; ++n) {
                int col = col0 + wc * 64 + n * 16 + cc;
                float bv = bias[col];
#pragma unroll
                for (int j = 0; j < 4; ++j) {
                    float v = acc[m][n][j] + bv;
                    if constexpr (OUT_MODE == 1) ((float*)out_)[(row + j) * 1024 + col] = v;
                    else ((unsigned short*)out_)[(row + j) * 1024 + col] = f2bf(v);
                }
            }
        }
    }
}

// ---------------------------------------------------------------------------
// fp32 -> bf16 cast, 8 elems/thread. n = 33554432 exact (grid 16384 x 256).
// ---------------------------------------------------------------------------
__global__ __launch_bounds__(256)
void cast_f2b(const float* __restrict__ src, unsigned short* __restrict__ dst) {
    const size_t i = ((size_t)blockIdx.x * 256 + threadIdx.x) * 8;
    f32x4 v0 = *(const f32x4*)(src + i);
    f32x4 v1 = *(const f32x4*)(src + i + 4);
    bf16x8 o;
#pragma unroll
    for (int j = 0; j < 4; ++j) o[j] = (short)f2bf(v0[j]);
#pragma unroll
    for (int j = 0; j < 4; ++j) o[4 + j] = (short)f2bf(v1[j]);
    *(bf16x8*)(dst + i) = o;
}

// ---------------------------------------------------------------------------
// 8-point DFT (negative exponent), in place on xr/xi[8].
// ---------------------------------------------------------------------------
__device__ __forceinline__ void dft8(float* xr, float* xi) {
    const float c8 = 0.70710678118654752440f;
    float es0r = xr[0] + xr[4], es0i = xi[0] + xi[4];
    float es1r = xr[0] - xr[4], es1i = xi[0] - xi[4];
    float es2r = xr[2] + xr[6], es2i = xi[2] + xi[6];
    float es3r = xr[2] - xr[6], es3i = xi[2] - xi[6];
    float E0r = es0r + es2r, E0i = es0i + es2i;
    float E2r = es0r - es2r, E2i = es0i - es2i;
    float E1r = es1r + es3i, E1i = es1i - es3r;
    float E3r = es1r - es3i, E3i = es1i + es3r;
    float os0r = xr[1] + xr[5], os0i = xi[1] + xi[5];
    float os1r = xr[1] - xr[5], os1i = xi[1] - xi[5];
    float os2r = xr[3] + xr[7], os2i = xi[3] + xi[7];
    float os3r = xr[3] - xr[7], os3i = xi[3] - xi[7];
    float O0r = os0r + os2r, O0i = os0i + os2i;
    float O2r = os0r - os2r, O2i = os0i - os2i;
    float O1r = os1r + os3i, O1i = os1i - os3r;
    float O3r = os1r - os3i, O3i = os1i + os3r;
    float p1 = c8 * (O1r + O1i), q1 = c8 * (O1i - O1r);
    float p3 = c8 * (O3r + O3i), q3 = c8 * (O3i - O3r);
    xr[0] = E0r + O0r; xi[0] = E0i + O0i;
    xr[4] = E0r - O0r; xi[4] = E0i - O0i;
    xr[1] = E1r + p1;  xi[1] = E1i + q1;
    xr[5] = E1r - p1;  xi[5] = E1i - q1;
    xr[2] = E2r + O2i; xi[2] = E2i - O2r;
    xr[6] = E2r - O2i; xi[6] = E2i + O2r;
    xr[3] = E3r + q3;  xi[3] = E3i - p3;
    xr[7] = E3r - q3;  xi[7] = E3i + p3;
}

__device__ __forceinline__ int padc(int p) { return p + (p >> 5); }

// ---------------------------------------------------------------------------
// fft_corr: per (b, 8 d-columns): z = q + i*k read coalesced from transposed
// layout qt/kt[b][d][t]; register-blocked mixed-radix FFT (8*8*8*4);
// Hermitian split -> accumulate P = Q*conj(K) into G[b][1025][2].
// grid = 2048 (16 b x 128 chunks), block = 256.
// ---------------------------------------------------------------------------
__global__ __launch_bounds__(256)
void fft_corr(const unsigned short* __restrict__ qt, const unsigned short* __restrict__ kt,
              float* __restrict__ G) {
    __shared__ float2 zc[2112];
    __shared__ float accR[1025], accI[1025];
    float* zfr = (float*)zc;
    float* zfi = zfr + 2112;
    const int tid = threadIdx.x;
    const int b = blockIdx.x >> 7;
    const int chunk = blockIdx.x & 127;

    const float N2PI = -6.28318530717958647692f;
    float w1r, w1i, w2r, w2i, w3r, w3i;
    {
        float s, c;
        __sincosf(N2PI * (float)tid * (1.0f / 2048.0f), &s, &c); w1r = c; w1i = s;
        __sincosf(N2PI * (float)(tid & 31) * (1.0f / 256.0f), &s, &c); w2r = c; w2i = s;
        __sincosf(N2PI * (float)(tid & 3) * (1.0f / 32.0f),  &s, &c); w3r = c; w3i = s;
    }

    for (int f = tid; f < 1025; f += 256) { accR[f] = 0.f; accI[f] = 0.f; }

    const int beta = tid >> 5, s2 = tid & 31;
    const int gam  = tid >> 2, u3 = tid & 3;

    for (int r = 0; r < 8; ++r) {
        const int d = chunk * 8 + r;
        const unsigned short* qrow = qt + ((size_t)b * 1024 + d) * 2048;
        const unsigned short* krow = kt + ((size_t)b * 1024 + d) * 2048;

        float xr[8], xi[8];
#pragma unroll
        for (int k = 0; k < 8; ++k) {
            xr[k] = bf2f(qrow[tid + 256 * k]);
            xi[k] = bf2f(krow[tid + 256 * k]);
        }
        dft8(xr, xi);
        {
            float cr_ = w1r, ci_ = w1i;
#pragma unroll
            for (int k = 1; k < 8; ++k) {
                float tr = xr[k] * cr_ - xi[k] * ci_;
                float ti = xr[k] * ci_ + xi[k] * cr_;
                xr[k] = tr; xi[k] = ti;
                if (k < 7) {
                    float nr = cr_ * w1r - ci_ * w1i;
                    float ni = cr_ * w1i + ci_ * w1r;
                    cr_ = nr; ci_ = ni;
                }
            }
        }
#pragma unroll
        for (int k = 0; k < 8; ++k) zc[padc(256 * k + tid)] = make_float2(xr[k], xi[k]);
        __syncthreads();

#pragma unroll
        for (int k = 0; k < 8; ++k) {
            float2 v = zc[padc(256 * beta + 32 * k + s2)];
            xr[k] = v.x; xi[k] = v.y;
        }
        __syncthreads();
        dft8(xr, xi);
        {
            float cr_ = w2r, ci_ = w2i;
#pragma unroll
            for (int k = 1; k < 8; ++k) {
                float tr = xr[k] * cr_ - xi[k] * ci_;
                float ti = xr[k] * ci_ + xi[k] * cr_;
                xr[k] = tr; xi[k] = ti;
                if (k < 7) {
                    float nr = cr_ * w2r - ci_ * w2i;
                    float ni = cr_ * w2i + ci_ * w2r;
                    cr_ = nr; ci_ = ni;
                }
            }
        }
#pragma unroll
        for (int k = 0; k < 8; ++k) zc[padc(256 * beta + 32 * k + s2)] = make_float2(xr[k], xi[k]);
        __syncthreads();

#pragma unroll
        for (int k = 0; k < 8; ++k) {
            float2 v = zc[padc(32 * gam + 4 * k + u3)];
            xr[k] = v.x; xi[k] = v.y;
        }
        __syncthreads();
        dft8(xr, xi);
        {
            float cr_ = w3r, ci_ = w3i;
#pragma unroll
            for (int k = 1; k < 8; ++k) {
                float tr = xr[k] * cr_ - xi[k] * ci_;
                float ti = xr[k] * ci_ + xi[k] * cr_;
                xr[k] = tr; xi[k] = ti;
                if (k < 7) {
                    float nr = cr_ * w3r - ci_ * w3i;
                    float ni = cr_ * w3i + ci_ * w3r;
                    cr_ = nr; ci_ = ni;
                }
            }
        }
#pragma unroll
        for (int k = 0; k < 8; ++k) zc[padc(32 * gam + 4 * k + u3)] = make_float2(xr[k], xi[k]);
        __syncthreads();

#pragma unroll
        for (int k = 0; k < 8; ++k) {
            float2 v = zc[padc(8 * tid + k)];
            xr[k] = v.x; xi[k] = v.y;
        }
        __syncthreads();

        float Xr[8], Xi[8];
#pragma unroll
        for (int blk = 0; blk < 2; ++blk) {
            const int o = 4 * blk;
            float s0r = xr[o] + xr[o + 2], s0i = xi[o] + xi[o + 2];
            float s1r = xr[o] - xr[o + 2], s1i = xi[o] - xi[o + 2];
            float s2r = xr[o + 1] + xr[o + 3], s2i = xi[o + 1] + xi[o + 3];
            float s3r = xr[o + 1] - xr[o + 3], s3i = xi[o + 1] - xi[o + 3];
            Xr[o + 0] = s0r + s2r; Xi[o + 0] = s0i + s2i;
            Xr[o + 2] = s0r - s2r; Xi[o + 2] = s0i - s2i;
            Xr[o + 1] = s1r + s3i; Xi[o + 1] = s1i - s3r;
            Xr[o + 3] = s1r - s3i; Xi[o + 3] = s1i + s3r;
        }
        {
            const int k1 = tid >> 5;
            const int k2 = (tid >> 2) & 7;
            const int fb = k1 + 8 * k2;
#pragma unroll
            for (int blk = 0; blk < 2; ++blk) {
                const int k3 = (2 * (tid & 3) + blk) & 7;
#pragma unroll
                for (int k4 = 0; k4 < 4; ++k4) {
                    const int f = fb + 64 * k3 + 512 * k4;
                    const int pf = padc(f);
                    zfr[pf] = Xr[4 * blk + k4];
                    zfi[pf] = Xi[4 * blk + k4];
                }
            }
        }
        __syncthreads();

        for (int f = tid; f < 1025; f += 256) {
            const int f2 = (2048 - f) & 2047;
            const int pf = padc(f), pf2 = padc(f2);
            float Zr = zfr[pf],  Zi = zfi[pf];
            float Yr = zfr[pf2], Yi = -zfi[pf2];
            float Qr = 0.5f * (Zr + Yr), Qi = 0.5f * (Zi + Yi);
            float Kr = 0.5f * (Zi - Yi), Ki = -0.5f * (Zr - Yr);
            accR[f] += Qr * Kr + Qi * Ki;
            accI[f] += Qi * Kr - Qr * Ki;
        }
        __syncthreads();
    }

    for (int f = tid; f < 1025; f += 256) {
        atomicAdd(&G[((size_t)b * 1025 + f) * 2 + 0], accR[f]);
        atomicAdd(&G[((size_t)b * 1025 + f) * 2 + 1], accI[f]);
    }
}

// ---------------------------------------------------------------------------
// In-LDS radix-2 DIT FFT, N=2048 (only used by irfft_mean: 16 blocks, cheap).
// ---------------------------------------------------------------------------
__device__ __forceinline__ void fft2048(float* zr, float* zi,
                                        const float* twr, const float* twi, int tid) {
    for (int t = tid; t < 2048; t += 256) {
        int j = __brev((unsigned)t) >> 21;
        if (j > t) {
            float a = zr[t]; zr[t] = zr[j]; zr[j] = a;
            float c = zi[t]; zi[t] = zi[j]; zi[j] = c;
        }
    }
    __syncthreads();
    for (int s = 0; s < 11; ++s) {
        const int m = 1 << s;
        for (int i = tid; i < 1024; i += 256) {
            const int pos = i & (m - 1);
            const int i1  = ((i >> s) << (s + 1)) + pos;
            const int i2  = i1 + m;
            const int tw  = pos << (10 - s);
            float wr = twr[tw], wi = twi[tw];
            float xr = zr[i2], xi = zi[i2];
            float tr = wr * xr - wi * xi;
            float ti = wr * xi + wi * xr;
            float ur = zr[i1], ui = zi[i1];
            zr[i2] = ur - tr; zi[i2] = ui - ti;
            zr[i1] = ur + tr; zi[i1] = ui + ti;
        }
        __syncthreads();
    }
}

__device__ __forceinline__ void init_twiddle(float* twr, float* twi, int tid) {
    for (int j = tid; j < 1024; j += 256) {
        float ang = -6.28318530717958647692f * (float)j * (1.0f / 2048.0f);
        twr[j] = cosf(ang);
        twi[j] = sinf(ang);
    }
}

// ---------------------------------------------------------------------------
// Per-batch irfft of G -> mean_value[b][t], scale 1/(2048*1024). grid = 16.
// ---------------------------------------------------------------------------
__global__ __launch_bounds__(256)
void irfft_mean(const float* __restrict__ G, float* __restrict__ mv) {
    __shared__ float zr[2048], zi[2048];
    __shared__ float twr[1024], twi[1024];
    const int tid = threadIdx.x;
    const int b = blockIdx.x;
    init_twiddle(twr, twi, tid);
    for (int f = tid; f < 2048; f += 256) {
        int g = (f <= 1024) ? f : 2048 - f;
        float gr = G[((size_t)b * 1025 + g) * 2 + 0];
        float gi = G[((size_t)b * 1025 + g) * 2 + 1];
        zr[f] = gr;
        zi[f] = (f <= 1024) ? -gi : gi;
    }
    __syncthreads();
    fft2048(zr, zi, twr, twi, tid);
    const float sc = 1.0f / (2048.0f * 1024.0f);
    for (int t = tid; t < 2048; t += 256) mv[b * 2048 + t] = zr[t] * sc;
}

// ---------------------------------------------------------------------------
// Top-7 over batch-mean of mean_value + per-batch softmax of gathered weights.
// Parallel argmax: per-thread partial (8 slots) -> 64-lane shfl_xor butterfly
// -> 4 wave results -> tiny serial combine. Tie-break: smaller index wins
// (matches top_k first-occurrence). Single block, 256 threads.
// ---------------------------------------------------------------------------
__global__ __launch_bounds__(256)
void topk_softmax(const float* __restrict__ mv, int* __restrict__ idx_out,
                  float* __restrict__ w_out) {
    __shared__ float cm[2048];
    __shared__ float wv4[4];
    __shared__ int   wi4[4];
    __shared__ int   sel[7];
    const int tid  = threadIdx.x;
    const int lane = tid & 63;
    const int wvid = tid >> 6;

    for (int t = tid; t < 2048; t += 256) {
        float s = 0.f;
        for (int b = 0; b < 16; ++b) s += mv[b * 2048 + t];
        cm[t] = s * (1.0f / 16.0f);
    }
    __syncthreads();

    for (int it = 0; it < 7; ++it) {
        float best = -3.4e38f; int bi = 1 << 30;
#pragma unroll
        for (int q = 0; q < 8; ++q) {
            const int t = tid + q * 256;
            float v = cm[t];
            if (v > best || (v == best && t < bi)) { best = v; bi = t; }
        }
#pragma unroll
        for (int off = 32; off > 0; off >>= 1) {
            float ov = __shfl_xor(best, off, 64);
            int   oi = __shfl_xor(bi,   off, 64);
            if (ov > best || (ov == best && oi < bi)) { best = ov; bi = oi; }
        }
        if (lane == 0) { wv4[wvid] = best; wi4[wvid] = bi; }
        __syncthreads();
        if (tid == 0) {
            float bb = wv4[0]; int bj = wi4[0];
#pragma unroll
            for (int u = 1; u < 4; ++u)
                if (wv4[u] > bb || (wv4[u] == bb && wi4[u] < bj)) { bb = wv4[u]; bj = wi4[u]; }
            sel[it] = bj;
            idx_out[it] = bj;
            cm[bj] = -3.4e38f;
        }
        __syncthreads();
    }

    if (tid < 16) {
        const int b = tid;
        float wv[7]; float mx = -3.4e38f;
#pragma unroll
        for (int i = 0; i < 7; ++i) { wv[i] = mv[b * 2048 + sel[i]]; mx = fmaxf(mx, wv[i]); }
        float s = 0.f;
#pragma unroll
        for (int i = 0; i < 7; ++i) { wv[i] = expf(wv[i] - mx); s += wv[i]; }
        float inv = 1.0f / s;
#pragma unroll
        for (int i = 0; i < 7; ++i) w_out[b * 7 + i] = wv[i] * inv;
    }
}

// ---------------------------------------------------------------------------
// agg[b,t,d] = sum_i w[b,i] * vp[b,(t+idx[i])%2048,d]  (bf16 in/out)
// ---------------------------------------------------------------------------
__global__ __launch_bounds__(256)
void agg_kernel(const unsigned short* __restrict__ vp, const int* __restrict__ idx,
                const float* __restrict__ w, unsigned short* __restrict__ agg) {
    const int b  = blockIdx.y;
    const int t  = blockIdx.x * 2 + (threadIdx.x >> 7);
    const int d8 = (threadIdx.x & 127) * 8;
    float av[8] = {0.f, 0.f, 0.f, 0.f, 0.f, 0.f, 0.f, 0.f};
#pragma unroll
    for (int i = 0; i < 7; ++i) {
        const int srow = (t + idx[i]) & 2047;
        const float wi = w[b * 7 + i];
        bf16x8 v = *(const bf16x8*)&vp[((size_t)b * 2048 + srow) * 1024 + d8];
#pragma unroll
        for (int j = 0; j < 8; ++j) av[j] += wi * bf2f((unsigned short)v[j]);
    }
    bf16x8 o;
#pragma unroll
    for (int j = 0; j < 8; ++j) o[j] = (short)f2bf(av[j]);
    *(bf16x8*)&agg[((size_t)b * 2048 + t) * 1024 + d8] = o;
}

// ---------------------------------------------------------------------------
__global__ __launch_bounds__(256)
void cast_w(const float* __restrict__ src, unsigned short* __restrict__ dst) {
    const int i = (blockIdx.x * 256 + threadIdx.x) * 4;   // n = 1048576 exact
    f32x4 v = *(const f32x4*)(src + i);
    s16x4 o;
#pragma unroll
    for (int j = 0; j < 4; ++j) o[j] = (short)f2bf(v[j]);
    *(s16x4*)(dst + i) = o;
}

__global__ __launch_bounds__(256)
void zero_f32(float* __restrict__ p, int n) {
    const int i = blockIdx.x * 256 + threadIdx.x;
    if (i < n) p[i] = 0.0f;
}

// ---------------------------------------------------------------------------
extern "C" void kernel_launch(void* const* d_in, const int* in_sizes, int n_in,
                              void* d_out, int out_size, void* d_ws, size_t ws_size,
                              hipStream_t stream) {
    const float* queries = (const float*)d_in[0];
    const float* keys    = (const float*)d_in[1];
    const float* values  = (const float*)d_in[2];
    const float* Wq = (const float*)d_in[3];  const float* bq = (const float*)d_in[4];
    const float* Wk = (const float*)d_in[5];  const float* bk = (const float*)d_in[6];
    const float* Wv = (const float*)d_in[7];  const float* bv = (const float*)d_in[8];
    const float* Wo = (const float*)d_in[9];  const float* bo = (const float*)d_in[10];
    float* out = (float*)d_out;

    char* ws = (char*)d_ws;
    constexpr size_t SZP = (size_t)32768 * 1024 * 2;           // 64 MB (bf16 B*L*D)
    unsigned short* qt  = (unsigned short*)(ws);               // [b][d][t]; reused as agg
    unsigned short* kt  = (unsigned short*)(ws + SZP);         // [b][d][t]
    unsigned short* vp  = (unsigned short*)(ws + 2 * SZP);     // [b][t][d]
    unsigned short* ab  = (unsigned short*)(ws + 3 * SZP);     // bf16 A staging (reused 3x)
    unsigned short* w16 = (unsigned short*)(ws + 4 * SZP);     // 4 x 1M bf16
    float* G   = (float*)(ws + 4 * SZP + 8388608);             // 16*1025*2 f32
    float* mv  = (float*)(ws + 4 * SZP + 8388608 + 131328);    // 16*2048 f32
    int*   idx = (int*)  (ws + 4 * SZP + 8388608 + 131328 + 131072);
    float* wsm = (float*)(ws + 4 * SZP + 8388608 + 131328 + 131072 + 64);
    unsigned short* agg = qt;

    cast_w<<<1024, 256, 0, stream>>>(Wq, w16 + 0 * 1048576);
    cast_w<<<1024, 256, 0, stream>>>(Wk, w16 + 1 * 1048576);
    cast_w<<<1024, 256, 0, stream>>>(Wv, w16 + 2 * 1048576);
    cast_w<<<1024, 256, 0, stream>>>(Wo, w16 + 3 * 1048576);
    zero_f32<<<(32800 + 255) / 256, 256, 0, stream>>>(G, 32800);

    cast_f2b<<<16384, 256, 0, stream>>>(queries, ab);
    gemm256<2><<<512, 512, 0, stream>>>(ab, w16 + 0 * 1048576, bq, qt);
    cast_f2b<<<16384, 256, 0, stream>>>(keys, ab);
    gemm256<2><<<512, 512, 0, stream>>>(ab, w16 + 1 * 1048576, bk, kt);
    cast_f2b<<<16384, 256, 0, stream>>>(values, ab);
    gemm256<0><<<512, 512, 0, stream>>>(ab, w16 + 2 * 1048576, bv, vp);

    fft_corr<<<2048, 256, 0, stream>>>(qt, kt, G);
    irfft_mean<<<16, 256, 0, stream>>>(G, mv);
    topk_softmax<<<1, 256, 0, stream>>>(mv, idx, wsm);
    agg_kernel<<<dim3(1024, 16), 256, 0, stream>>>(vp, idx, wsm, agg);

    gemm256<1><<<512, 512, 0, stream>>>(agg, w16 + 3 * 1048576, bo, out);
}

// Round 7
// 597.300 us; speedup vs baseline: 1.7086x; 1.0487x over previous
//
#include <hip/hip_runtime.h>

typedef __attribute__((ext_vector_type(8))) short bf16x8;
typedef __attribute__((ext_vector_type(4))) short s16x4;
typedef __attribute__((ext_vector_type(4))) float f32x4;

__device__ __forceinline__ float bf2f(unsigned short u) {
    union { unsigned int u; float f; } x; x.u = ((unsigned int)u) << 16; return x.f;
}
__device__ __forceinline__ unsigned short f2bf(float f) {
    union { float f; unsigned int u; } x; x.f = f;
    unsigned int u = x.u;
    unsigned int r = (u + 0x7fffu + ((u >> 16) & 1u)) >> 16;
    return (unsigned short)r;
}

#define GLDS16(gp, lp)                                                        \
    __builtin_amdgcn_global_load_lds(                                         \
        (const __attribute__((address_space(1))) void*)(gp),                  \
        (__attribute__((address_space(3))) void*)(lp), 16, 0, 0)

// ---------------------------------------------------------------------------
// GEMM: C[M, N=1024] = A[M,K=1024] @ W^T + bias. A,W bf16 (W=[N,K]).
// 256x256 tile, BK=64, 8 waves, LDS 128KB dbuf, depth-2 prefetch with counted
// vmcnt(8), raw s_barrier, setprio, XOR-swizzled staging (verified conflicts=0).
// OUT_MODE: 0 = bf16 [row][col], 1 = f32 [row][col], 2 = bf16 transposed
//           [b][col][t] (row = b*2048+t).
// grid = (M/256)*(N/256) blocks (generic XCD swizzle via gridDim), block 512.
// ---------------------------------------------------------------------------
template<int OUT_MODE>
__global__ __launch_bounds__(512, 2)
void gemm256(const unsigned short* __restrict__ A, const unsigned short* __restrict__ Bw,
             const float* __restrict__ bias, void* __restrict__ out_) {
    __shared__ __align__(16) unsigned short sA[2][16384];   // [buf][256*64]
    __shared__ __align__(16) unsigned short sB[2][16384];

    const int tid  = threadIdx.x;
    const int lane = tid & 63;
    const int w    = tid >> 6;          // 0..7
    const int wr   = w >> 2, wc = w & 3;
    const int fr   = lane & 15, g4 = lane >> 4;

    // XCD-chunked bijective swizzle (generic, requires gridDim.x % 8 == 0)
    const int bid = blockIdx.x;
    const int qq  = (int)gridDim.x >> 3;
    const int swz = (bid & 7) * qq + (bid >> 3);
    const int  col0 = (swz & 3) * 256;
    const long row0 = (long)(swz >> 2) * 256;

    // staging source: unit u = r*512+tid; row=u>>3, j=u&7, src unit j^(row&7)
    const int srow = tid >> 3;
    const int sj   = (tid & 7) ^ (srow & 7);
    const unsigned short* gA = A  + (size_t)(row0 + srow) * 1024 + sj * 8;
    const unsigned short* gB = Bw + (size_t)(col0 + srow) * 1024 + sj * 8;
    const int ldst = w * 1024;

    auto stage = [&](int buf, int t) {
        const unsigned short* a = gA + t * 64;
        const unsigned short* b = gB + t * 64;
        char* dA = (char*)&sA[buf][0];
        char* dB = (char*)&sB[buf][0];
#pragma unroll
        for (int r = 0; r < 4; ++r)
            GLDS16(a + r * 65536, (__attribute__((address_space(3))) char*)(dA + r * 8192 + ldst));
#pragma unroll
        for (int r = 0; r < 4; ++r)
            GLDS16(b + r * 65536, (__attribute__((address_space(3))) char*)(dB + r * 8192 + ldst));
    };

    f32x4 acc[8][4];
#pragma unroll
    for (int m = 0; m < 8; ++m)
#pragma unroll
        for (int n = 0; n < 4; ++n) acc[m][n] = (f32x4){0.f, 0.f, 0.f, 0.f};

    stage(0, 0);
    stage(1, 1);

    const int mskK = (fr & 7) << 4;

    for (int t = 0; t < 16; ++t) {
        if (t < 15) asm volatile("s_waitcnt vmcnt(8)" ::: "memory");
        else        asm volatile("s_waitcnt vmcnt(0)" ::: "memory");
        asm volatile("s_barrier" ::: "memory");
        __builtin_amdgcn_sched_barrier(0);

        const char* la = (const char*)&sA[t & 1][0];
        const char* lb = (const char*)&sB[t & 1][0];

        bf16x8 bF[2][4];
#pragma unroll
        for (int c = 0; c < 2; ++c)
#pragma unroll
            for (int n = 0; n < 4; ++n) {
                const int row = wc * 64 + n * 16 + fr;
                bF[c][n] = *(const bf16x8*)(lb + row * 128 + ((c * 64 + g4 * 16) ^ mskK));
            }
#pragma unroll
        for (int mh = 0; mh < 2; ++mh) {
            bf16x8 aF[2][4];
#pragma unroll
            for (int c = 0; c < 2; ++c)
#pragma unroll
                for (int m = 0; m < 4; ++m) {
                    const int row = wr * 128 + mh * 64 + m * 16 + fr;
                    aF[c][m] = *(const bf16x8*)(la + row * 128 + ((c * 64 + g4 * 16) ^ mskK));
                }
            __builtin_amdgcn_s_setprio(1);
#pragma unroll
            for (int c = 0; c < 2; ++c)
#pragma unroll
                for (int n = 0; n < 4; ++n)
#pragma unroll
                    for (int m = 0; m < 4; ++m)
                        acc[mh * 4 + m][n] =
                            __builtin_amdgcn_mfma_f32_16x16x32_bf16(aF[c][m], bF[c][n], acc[mh * 4 + m][n], 0, 0, 0);
            __builtin_amdgcn_s_setprio(0);
        }

        __builtin_amdgcn_sched_barrier(0);
        asm volatile("s_barrier" ::: "memory");
        if (t + 2 < 16) stage(t & 1, t + 2);
    }

    // C/D layout (m89-verified): col = lane&15, row = (lane>>4)*4 + j
    const int cr = g4 * 4;
    const int cc = fr;
    if constexpr (OUT_MODE == 2) {
        const int b  = (int)(row0 >> 11);
        const int tb = ((int)row0 & 2047) + wr * 128 + cr;
#pragma unroll
        for (int m = 0; m < 8; ++m) {
#pragma unroll
            for (int n = 0; n < 4; ++n) {
                int col = col0 + wc * 64 + n * 16 + cc;
                float bv = bias[col];
                s16x4 o;
#pragma unroll
                for (int j = 0; j < 4; ++j) o[j] = (short)f2bf(acc[m][n][j] + bv);
                *(s16x4*)&((unsigned short*)out_)[((size_t)b * 1024 + col) * 2048 + tb + m * 16] = o;
            }
        }
    } else {
#pragma unroll
        for (int m = 0; m < 8; ++m) {
            long row = row0 + wr * 128 + m * 16 + cr;
#pragma unroll
            for (int n = 0; n < 4; ++n) {
                int col = col0 + wc * 64 + n * 16 + cc;
                float bv = bias[col];
#pragma unroll
                for (int j = 0; j < 4; ++j) {
                    float v = acc[m][n][j] + bv;
                    if constexpr (OUT_MODE == 1) ((float*)out_)[(row + j) * 1024 + col] = v;
                    else ((unsigned short*)out_)[(row + j) * 1024 + col] = f2bf(v);
                }
            }
        }
    }
}

// ---------------------------------------------------------------------------
// fp32 -> bf16 cast, 8 elems/thread (grid 16384 x 256 for 33.5M elems).
// ---------------------------------------------------------------------------
__global__ __launch_bounds__(256)
void cast_f2b(const float* __restrict__ src, unsigned short* __restrict__ dst) {
    const size_t i = ((size_t)blockIdx.x * 256 + threadIdx.x) * 8;
    f32x4 v0 = *(const f32x4*)(src + i);
    f32x4 v1 = *(const f32x4*)(src + i + 4);
    bf16x8 o;
#pragma unroll
    for (int j = 0; j < 4; ++j) o[j] = (short)f2bf(v0[j]);
#pragma unroll
    for (int j = 0; j < 4; ++j) o[4 + j] = (short)f2bf(v1[j]);
    *(bf16x8*)(dst + i) = o;
}

// ---------------------------------------------------------------------------
// transpose-cast: dst[j][i] = bf16(src[i][j]), 1024x1024. grid (16,16), 256 thr.
// ---------------------------------------------------------------------------
__global__ __launch_bounds__(256)
void cast_wT(const float* __restrict__ src, unsigned short* __restrict__ dst) {
    __shared__ float t[64][65];
    const int bx = blockIdx.x * 64, by = blockIdx.y * 64;
    const int tx = threadIdx.x & 63, ty = threadIdx.x >> 6;
    for (int r = ty; r < 64; r += 4)
        t[r][tx] = src[(size_t)(by + r) * 1024 + bx + tx];
    __syncthreads();
    for (int r = ty; r < 64; r += 4)
        dst[(size_t)(bx + r) * 1024 + by + tx] = f2bf(t[tx][r]);
}

// ---------------------------------------------------------------------------
// b2[n] = dot(Wo[n,:], bv) + bo[n].  grid 256 x 256 (one wave per n).
// ---------------------------------------------------------------------------
__global__ __launch_bounds__(256)
void bias2_kernel(const float* __restrict__ Wo, const float* __restrict__ bv,
                  const float* __restrict__ bo, float* __restrict__ b2) {
    const int n = blockIdx.x * 4 + (threadIdx.x >> 6);
    const int lane = threadIdx.x & 63;
    float s = 0.f;
    for (int k = lane; k < 1024; k += 64) s += Wo[(size_t)n * 1024 + k] * bv[k];
#pragma unroll
    for (int off = 32; off > 0; off >>= 1) s += __shfl_xor(s, off, 64);
    if (lane == 0) b2[n] = s + bo[n];
}

// ---------------------------------------------------------------------------
// 8-point DFT (negative exponent), in place on xr/xi[8].
// ---------------------------------------------------------------------------
__device__ __forceinline__ void dft8(float* xr, float* xi) {
    const float c8 = 0.70710678118654752440f;
    float es0r = xr[0] + xr[4], es0i = xi[0] + xi[4];
    float es1r = xr[0] - xr[4], es1i = xi[0] - xi[4];
    float es2r = xr[2] + xr[6], es2i = xi[2] + xi[6];
    float es3r = xr[2] - xr[6], es3i = xi[2] - xi[6];
    float E0r = es0r + es2r, E0i = es0i + es2i;
    float E2r = es0r - es2r, E2i = es0i - es2i;
    float E1r = es1r + es3i, E1i = es1i - es3r;
    float E3r = es1r - es3i, E3i = es1i + es3r;
    float os0r = xr[1] + xr[5], os0i = xi[1] + xi[5];
    float os1r = xr[1] - xr[5], os1i = xi[1] - xi[5];
    float os2r = xr[3] + xr[7], os2i = xi[3] + xi[7];
    float os3r = xr[3] - xr[7], os3i = xi[3] - xi[7];
    float O0r = os0r + os2r, O0i = os0i + os2i;
    float O2r = os0r - os2r, O2i = os0i - os2i;
    float O1r = os1r + os3i, O1i = os1i - os3r;
    float O3r = os1r - os3i, O3i = os1i + os3r;
    float p1 = c8 * (O1r + O1i), q1 = c8 * (O1i - O1r);
    float p3 = c8 * (O3r + O3i), q3 = c8 * (O3i - O3r);
    xr[0] = E0r + O0r; xi[0] = E0i + O0i;
    xr[4] = E0r - O0r; xi[4] = E0i - O0i;
    xr[1] = E1r + p1;  xi[1] = E1i + q1;
    xr[5] = E1r - p1;  xi[5] = E1i - q1;
    xr[2] = E2r + O2i; xi[2] = E2i - O2r;
    xr[6] = E2r - O2i; xi[6] = E2i + O2r;
    xr[3] = E3r + q3;  xi[3] = E3i - p3;
    xr[7] = E3r - q3;  xi[7] = E3i + p3;
}

__device__ __forceinline__ int padc(int p) { return p + (p >> 5); }

// apply W^{k} chain (base wr_,wi_) to both streams a and b
#define TWIDDLE2(wr_, wi_)                                                    \
    {                                                                         \
        float cr_ = (wr_), ci_ = (wi_);                                       \
        _Pragma("unroll")                                                     \
        for (int k = 1; k < 8; ++k) {                                         \
            float t0 = ar[k] * cr_ - ai[k] * ci_;                             \
            float t1 = ar[k] * ci_ + ai[k] * cr_;                             \
            ar[k] = t0; ai[k] = t1;                                           \
            float t2 = br[k] * cr_ - bi[k] * ci_;                             \
            float t3 = br[k] * ci_ + bi[k] * cr_;                             \
            br[k] = t2; bi[k] = t3;                                           \
            if (k < 7) {                                                      \
                float nr = cr_ * (wr_) - ci_ * (wi_);                         \
                float ni = cr_ * (wi_) + ci_ * (wr_);                         \
                cr_ = nr; ci_ = ni;                                           \
            }                                                                 \
        }                                                                     \
    }

// ---------------------------------------------------------------------------
// fft_corr v2: dual-column batching (2 d-cols per FFT round-trip, shared
// twiddle chain), accumulator in registers, minimal barriers (6 per 2 cols).
// grid = 2048 (16 b x 128 chunks), block = 256.
// ---------------------------------------------------------------------------
__global__ __launch_bounds__(256)
void fft_corr(const unsigned short* __restrict__ qt, const unsigned short* __restrict__ kt,
              float* __restrict__ G) {
    __shared__ float2 za[2112];
    __shared__ float2 zb[2112];
    float* zfr0 = (float*)za; float* zfi0 = zfr0 + 2112;
    float* zfr1 = (float*)zb; float* zfi1 = zfr1 + 2112;
    const int tid = threadIdx.x;
    const int b = blockIdx.x >> 7;
    const int chunk = blockIdx.x & 127;

    const float N2PI = -6.28318530717958647692f;
    float w1r, w1i, w2r, w2i, w3r, w3i;
    {
        float s, c;
        __sincosf(N2PI * (float)tid * (1.0f / 2048.0f), &s, &c); w1r = c; w1i = s;
        __sincosf(N2PI * (float)(tid & 31) * (1.0f / 256.0f), &s, &c); w2r = c; w2i = s;
        __sincosf(N2PI * (float)(tid & 3) * (1.0f / 32.0f),  &s, &c); w3r = c; w3i = s;
    }

    float aR0 = 0.f, aI0 = 0.f, aR1 = 0.f, aI1 = 0.f;
    float aR2 = 0.f, aI2 = 0.f, aR3 = 0.f, aI3 = 0.f, aR4 = 0.f;

    const int beta = tid >> 5, s2 = tid & 31;
    const int gam  = tid >> 2, u3 = tid & 3;

    for (int it = 0; it < 4; ++it) {
        const int d0 = chunk * 8 + it * 2;
        const unsigned short* q0 = qt + ((size_t)b * 1024 + d0) * 2048;
        const unsigned short* k0 = kt + ((size_t)b * 1024 + d0) * 2048;
        const unsigned short* q1 = q0 + 2048;
        const unsigned short* k1 = k0 + 2048;

        float ar[8], ai[8], br[8], bi[8];
        // ----- R1: z[tid + 256k], coalesced loads, dual columns -----
#pragma unroll
        for (int k = 0; k < 8; ++k) {
            ar[k] = bf2f(q0[tid + 256 * k]); ai[k] = bf2f(k0[tid + 256 * k]);
            br[k] = bf2f(q1[tid + 256 * k]); bi[k] = bf2f(k1[tid + 256 * k]);
        }
        dft8(ar, ai); dft8(br, bi);
        TWIDDLE2(w1r, w1i)
#pragma unroll
        for (int k = 0; k < 8; ++k) {
            const int p = padc(256 * k + tid);
            za[p] = make_float2(ar[k], ai[k]);
            zb[p] = make_float2(br[k], bi[k]);
        }
        __syncthreads();

        // ----- R2: read/write own set (no intra-round barrier needed) -----
#pragma unroll
        for (int k = 0; k < 8; ++k) {
            const int p = padc(256 * beta + 32 * k + s2);
            float2 va = za[p]; ar[k] = va.x; ai[k] = va.y;
            float2 vb = zb[p]; br[k] = vb.x; bi[k] = vb.y;
        }
        dft8(ar, ai); dft8(br, bi);
        TWIDDLE2(w2r, w2i)
#pragma unroll
        for (int k = 0; k < 8; ++k) {
            const int p = padc(256 * beta + 32 * k + s2);
            za[p] = make_float2(ar[k], ai[k]);
            zb[p] = make_float2(br[k], bi[k]);
        }
        __syncthreads();

        // ----- R3 -----
#pragma unroll
        for (int k = 0; k < 8; ++k) {
            const int p = padc(32 * gam + 4 * k + u3);
            float2 va = za[p]; ar[k] = va.x; ai[k] = va.y;
            float2 vb = zb[p]; br[k] = vb.x; bi[k] = vb.y;
        }
        dft8(ar, ai); dft8(br, bi);
        TWIDDLE2(w3r, w3i)
#pragma unroll
        for (int k = 0; k < 8; ++k) {
            const int p = padc(32 * gam + 4 * k + u3);
            za[p] = make_float2(ar[k], ai[k]);
            zb[p] = make_float2(br[k], bi[k]);
        }
        __syncthreads();

        // ----- R4: read 8t..8t+7, radix-4 pairs in place, scatter -----
#pragma unroll
        for (int k = 0; k < 8; ++k) {
            const int p = padc(8 * tid + k);
            float2 va = za[p]; ar[k] = va.x; ai[k] = va.y;
            float2 vb = zb[p]; br[k] = vb.x; bi[k] = vb.y;
        }
        __syncthreads();   // reads complete before scatter overwrites aliased planes

#pragma unroll
        for (int blk = 0; blk < 2; ++blk) {
            const int o = 4 * blk;
            {
                float s0r = ar[o] + ar[o + 2], s0i = ai[o] + ai[o + 2];
                float s1r = ar[o] - ar[o + 2], s1i = ai[o] - ai[o + 2];
                float s2r = ar[o + 1] + ar[o + 3], s2i = ai[o + 1] + ai[o + 3];
                float s3r = ar[o + 1] - ar[o + 3], s3i = ai[o + 1] - ai[o + 3];
                ar[o + 0] = s0r + s2r; ai[o + 0] = s0i + s2i;
                ar[o + 2] = s0r - s2r; ai[o + 2] = s0i - s2i;
                ar[o + 1] = s1r + s3i; ai[o + 1] = s1i - s3r;
                ar[o + 3] = s1r - s3i; ai[o + 3] = s1i + s3r;
            }
            {
                float s0r = br[o] + br[o + 2], s0i = bi[o] + bi[o + 2];
                float s1r = br[o] - br[o + 2], s1i = bi[o] - bi[o + 2];
                float s2r = br[o + 1] + br[o + 3], s2i = bi[o + 1] + bi[o + 3];
                float s3r = br[o + 1] - br[o + 3], s3i = bi[o + 1] - bi[o + 3];
                br[o + 0] = s0r + s2r; bi[o + 0] = s0i + s2i;
                br[o + 2] = s0r - s2r; bi[o + 2] = s0i - s2i;
                br[o + 1] = s1r + s3i; bi[o + 1] = s1i - s3r;
                br[o + 3] = s1r - s3i; bi[o + 3] = s1i + s3r;
            }
        }
        {
            const int k1 = tid >> 5;
            const int k2 = (tid >> 2) & 7;
            const int fb = k1 + 8 * k2;
#pragma unroll
            for (int blk = 0; blk < 2; ++blk) {
                const int k3 = (2 * (tid & 3) + blk) & 7;
#pragma unroll
                for (int k4 = 0; k4 < 4; ++k4) {
                    const int f = fb + 64 * k3 + 512 * k4;
                    const int pf = padc(f);
                    zfr0[pf] = ar[4 * blk + k4]; zfi0[pf] = ai[4 * blk + k4];
                    zfr1[pf] = br[4 * blk + k4]; zfi1[pf] = bi[4 * blk + k4];
                }
            }
        }
        __syncthreads();

        // ----- Hermitian split + accumulate (registers) -----
#pragma unroll
        for (int k = 0; k < 4; ++k) {
            const int f = tid + 256 * k;
            const int f2 = (2048 - f) & 2047;
            const int pf = padc(f), pf2 = padc(f2);
            float Zr = zfr0[pf],  Zi = zfi0[pf];
            float Yr = zfr0[pf2], Yi = -zfi0[pf2];
            float Qr = 0.5f * (Zr + Yr), Qi = 0.5f * (Zi + Yi);
            float Kr = 0.5f * (Zi - Yi), Ki = -0.5f * (Zr - Yr);
            float dR = Qr * Kr + Qi * Ki;
            float dI = Qi * Kr - Qr * Ki;
            Zr = zfr1[pf];  Zi = zfi1[pf];
            Yr = zfr1[pf2]; Yi = -zfi1[pf2];
            Qr = 0.5f * (Zr + Yr); Qi = 0.5f * (Zi + Yi);
            Kr = 0.5f * (Zi - Yi); Ki = -0.5f * (Zr - Yr);
            dR += Qr * Kr + Qi * Ki;
            dI += Qi * Kr - Qr * Ki;
            if      (k == 0) { aR0 += dR; aI0 += dI; }
            else if (k == 1) { aR1 += dR; aI1 += dI; }
            else if (k == 2) { aR2 += dR; aI2 += dI; }
            else             { aR3 += dR; aI3 += dI; }
        }
        if (tid == 0) {   // f = 1024: Q = Re(Z), K = Im(Z), P imag = 0
            const int pf = padc(1024);
            aR4 += zfr0[pf] * zfi0[pf] + zfr1[pf] * zfi1[pf];
        }
        __syncthreads();   // plane reads done before next iteration's R1 writes
    }

    atomicAdd(&G[((size_t)b * 1025 + tid +   0) * 2 + 0], aR0);
    atomicAdd(&G[((size_t)b * 1025 + tid +   0) * 2 + 1], aI0);
    atomicAdd(&G[((size_t)b * 1025 + tid + 256) * 2 + 0], aR1);
    atomicAdd(&G[((size_t)b * 1025 + tid + 256) * 2 + 1], aI1);
    atomicAdd(&G[((size_t)b * 1025 + tid + 512) * 2 + 0], aR2);
    atomicAdd(&G[((size_t)b * 1025 + tid + 512) * 2 + 1], aI2);
    atomicAdd(&G[((size_t)b * 1025 + tid + 768) * 2 + 0], aR3);
    atomicAdd(&G[((size_t)b * 1025 + tid + 768) * 2 + 1], aI3);
    if (tid == 0)
        atomicAdd(&G[((size_t)b * 1025 + 1024) * 2 + 0], aR4);
}

// ---------------------------------------------------------------------------
// In-LDS radix-2 DIT FFT, N=2048 (only used by irfft_mean: 16 blocks, cheap).
// ---------------------------------------------------------------------------
__device__ __forceinline__ void fft2048(float* zr, float* zi,
                                        const float* twr, const float* twi, int tid) {
    for (int t = tid; t < 2048; t += 256) {
        int j = __brev((unsigned)t) >> 21;
        if (j > t) {
            float a = zr[t]; zr[t] = zr[j]; zr[j] = a;
            float c = zi[t]; zi[t] = zi[j]; zi[j] = c;
        }
    }
    __syncthreads();
    for (int s = 0; s < 11; ++s) {
        const int m = 1 << s;
        for (int i = tid; i < 1024; i += 256) {
            const int pos = i & (m - 1);
            const int i1  = ((i >> s) << (s + 1)) + pos;
            const int i2  = i1 + m;
            const int tw  = pos << (10 - s);
            float wr = twr[tw], wi = twi[tw];
            float xr = zr[i2], xi = zi[i2];
            float tr = wr * xr - wi * xi;
            float ti = wr * xi + wi * xr;
            float ur = zr[i1], ui = zi[i1];
            zr[i2] = ur - tr; zi[i2] = ui - ti;
            zr[i1] = ur + tr; zi[i1] = ui + ti;
        }
        __syncthreads();
    }
}

__device__ __forceinline__ void init_twiddle(float* twr, float* twi, int tid) {
    for (int j = tid; j < 1024; j += 256) {
        float ang = -6.28318530717958647692f * (float)j * (1.0f / 2048.0f);
        twr[j] = cosf(ang);
        twi[j] = sinf(ang);
    }
}

// ---------------------------------------------------------------------------
// Per-batch irfft of G -> mean_value[b][t], scale 1/(2048*1024). grid = 16.
// ---------------------------------------------------------------------------
__global__ __launch_bounds__(256)
void irfft_mean(const float* __restrict__ G, float* __restrict__ mv) {
    __shared__ float zr[2048], zi[2048];
    __shared__ float twr[1024], twi[1024];
    const int tid = threadIdx.x;
    const int b = blockIdx.x;
    init_twiddle(twr, twi, tid);
    for (int f = tid; f < 2048; f += 256) {
        int g = (f <= 1024) ? f : 2048 - f;
        float gr = G[((size_t)b * 1025 + g) * 2 + 0];
        float gi = G[((size_t)b * 1025 + g) * 2 + 1];
        zr[f] = gr;
        zi[f] = (f <= 1024) ? -gi : gi;
    }
    __syncthreads();
    fft2048(zr, zi, twr, twi, tid);
    const float sc = 1.0f / (2048.0f * 1024.0f);
    for (int t = tid; t < 2048; t += 256) mv[b * 2048 + t] = zr[t] * sc;
}

// ---------------------------------------------------------------------------
// Top-7 over batch-mean + per-batch softmax (parallel argmax, round-6 version).
// ---------------------------------------------------------------------------
__global__ __launch_bounds__(256)
void topk_softmax(const float* __restrict__ mv, int* __restrict__ idx_out,
                  float* __restrict__ w_out) {
    __shared__ float cm[2048];
    __shared__ float wv4[4];
    __shared__ int   wi4[4];
    __shared__ int   sel[7];
    const int tid  = threadIdx.x;
    const int lane = tid & 63;
    const int wvid = tid >> 6;

    for (int t = tid; t < 2048; t += 256) {
        float s = 0.f;
        for (int b = 0; b < 16; ++b) s += mv[b * 2048 + t];
        cm[t] = s * (1.0f / 16.0f);
    }
    __syncthreads();

    for (int it = 0; it < 7; ++it) {
        float best = -3.4e38f; int bi = 1 << 30;
#pragma unroll
        for (int q = 0; q < 8; ++q) {
            const int t = tid + q * 256;
            float v = cm[t];
            if (v > best || (v == best && t < bi)) { best = v; bi = t; }
        }
#pragma unroll
        for (int off = 32; off > 0; off >>= 1) {
            float ov = __shfl_xor(best, off, 64);
            int   oi = __shfl_xor(bi,   off, 64);
            if (ov > best || (ov == best && oi < bi)) { best = ov; bi = oi; }
        }
        if (lane == 0) { wv4[wvid] = best; wi4[wvid] = bi; }
        __syncthreads();
        if (tid == 0) {
            float bb = wv4[0]; int bj = wi4[0];
#pragma unroll
            for (int u = 1; u < 4; ++u)
                if (wv4[u] > bb || (wv4[u] == bb && wi4[u] < bj)) { bb = wv4[u]; bj = wi4[u]; }
            sel[it] = bj;
            idx_out[it] = bj;
            cm[bj] = -3.4e38f;
        }
        __syncthreads();
    }

    if (tid < 16) {
        const int b = tid;
        float wv[7]; float mx = -3.4e38f;
#pragma unroll
        for (int i = 0; i < 7; ++i) { wv[i] = mv[b * 2048 + sel[i]]; mx = fmaxf(mx, wv[i]); }
        float s = 0.f;
#pragma unroll
        for (int i = 0; i < 7; ++i) { wv[i] = expf(wv[i] - mx); s += wv[i]; }
        float inv = 1.0f / s;
#pragma unroll
        for (int i = 0; i < 7; ++i) w_out[b * 7 + i] = wv[i] * inv;
    }
}

// ---------------------------------------------------------------------------
// agg[b,t,d] = sum_i w[b,i] * vb[b,(t+idx[i])%2048,d]  (bf16 in/out)
// ---------------------------------------------------------------------------
__global__ __launch_bounds__(256)
void agg_kernel(const unsigned short* __restrict__ vb, const int* __restrict__ idx,
                const float* __restrict__ w, unsigned short* __restrict__ agg) {
    const int b  = blockIdx.y;
    const int t  = blockIdx.x * 2 + (threadIdx.x >> 7);
    const int d8 = (threadIdx.x & 127) * 8;
    float av[8] = {0.f, 0.f, 0.f, 0.f, 0.f, 0.f, 0.f, 0.f};
#pragma unroll
    for (int i = 0; i < 7; ++i) {
        const int srow = (t + idx[i]) & 2047;
        const float wi = w[b * 7 + i];
        bf16x8 v = *(const bf16x8*)&vb[((size_t)b * 2048 + srow) * 1024 + d8];
#pragma unroll
        for (int j = 0; j < 8; ++j) av[j] += wi * bf2f((unsigned short)v[j]);
    }
    bf16x8 o;
#pragma unroll
    for (int j = 0; j < 8; ++j) o[j] = (short)f2bf(av[j]);
    *(bf16x8*)&agg[((size_t)b * 2048 + t) * 1024 + d8] = o;
}

// ---------------------------------------------------------------------------
__global__ __launch_bounds__(256)
void cast_w(const float* __restrict__ src, unsigned short* __restrict__ dst) {
    const int i = (blockIdx.x * 256 + threadIdx.x) * 4;   // n = 1048576 exact
    f32x4 v = *(const f32x4*)(src + i);
    s16x4 o;
#pragma unroll
    for (int j = 0; j < 4; ++j) o[j] = (short)f2bf(v[j]);
    *(s16x4*)(dst + i) = o;
}

__global__ __launch_bounds__(256)
void zero_f32(float* __restrict__ p, int n) {
    const int i = blockIdx.x * 256 + threadIdx.x;
    if (i < n) p[i] = 0.0f;
}

// ---------------------------------------------------------------------------
extern "C" void kernel_launch(void* const* d_in, const int* in_sizes, int n_in,
                              void* d_out, int out_size, void* d_ws, size_t ws_size,
                              hipStream_t stream) {
    const float* queries = (const float*)d_in[0];
    const float* keys    = (const float*)d_in[1];
    const float* values  = (const float*)d_in[2];
    const float* Wq = (const float*)d_in[3];  const float* bq = (const float*)d_in[4];
    const float* Wk = (const float*)d_in[5];  const float* bk = (const float*)d_in[6];
    const float* Wv = (const float*)d_in[7];  const float* bv = (const float*)d_in[8];
    const float* Wo = (const float*)d_in[9];  const float* bo = (const float*)d_in[10];
    float* out = (float*)d_out;

    char* ws = (char*)d_ws;
    constexpr size_t SZP = (size_t)32768 * 1024 * 2;           // 64 MB (bf16 B*L*D)
    unsigned short* qt  = (unsigned short*)(ws);               // [b][d][t]; reused as agg
    unsigned short* kt  = (unsigned short*)(ws + SZP);         // [b][d][t]
    unsigned short* vb  = (unsigned short*)(ws + 2 * SZP);     // cast values [b][t][d]
    unsigned short* ab  = (unsigned short*)(ws + 3 * SZP);     // A-cast staging (64MB)
    // wo/wvT live inside ab (used only before the first cast_f2b overwrites it)
    unsigned short* wo  = ab;                                  // bf16 Wo
    unsigned short* wvT = ab + 1048576;                        // bf16 Wv^T
    unsigned short* wq  = (unsigned short*)(ws + 4 * SZP);     // weights region (6MB)
    unsigned short* wk  = wq + 1048576;
    unsigned short* W2  = wq + 2097152;                        // bf16 Wo@Wv [N][K]
    char* tail = ws + 4 * SZP + 6291456;
    float* zb1024 = (float*)(tail);                            // 4KB zero bias
    float* b2     = (float*)(tail + 4096);                     // 4KB
    float* G      = (float*)(tail + 8192);                     // 16*1025*2 f32
    float* mv     = (float*)(tail + 8192 + 131328);
    int*   idx    = (int*)  (tail + 8192 + 131328 + 131072);
    float* wsm    = (float*)(tail + 8192 + 131328 + 131072 + 64);
    unsigned short* agg = qt;

    // weight preprocessing + W2 = Wo@Wv, b2 = Wo@bv + bo
    cast_w<<<1024, 256, 0, stream>>>(Wq, wq);
    cast_w<<<1024, 256, 0, stream>>>(Wk, wk);
    cast_w<<<1024, 256, 0, stream>>>(Wo, wo);
    cast_wT<<<dim3(16, 16), 256, 0, stream>>>(Wv, wvT);
    zero_f32<<<(32800 + 255) / 256, 256, 0, stream>>>(G, 32800);
    zero_f32<<<4, 256, 0, stream>>>(zb1024, 1024);
    bias2_kernel<<<256, 256, 0, stream>>>(Wo, bv, bo, b2);
    gemm256<0><<<16, 512, 0, stream>>>(wo, wvT, zb1024, W2);

    // projections (q, k) + cast of values
    cast_f2b<<<16384, 256, 0, stream>>>(queries, ab);
    gemm256<2><<<512, 512, 0, stream>>>(ab, wq, bq, qt);
    cast_f2b<<<16384, 256, 0, stream>>>(keys, ab);
    gemm256<2><<<512, 512, 0, stream>>>(ab, wk, bk, kt);
    cast_f2b<<<16384, 256, 0, stream>>>(values, vb);

    // correlation -> top-k -> aggregation -> fused output GEMM
    fft_corr<<<2048, 256, 0, stream>>>(qt, kt, G);
    irfft_mean<<<16, 256, 0, stream>>>(G, mv);
    topk_softmax<<<1, 256, 0, stream>>>(mv, idx, wsm);
    agg_kernel<<<dim3(1024, 16), 256, 0, stream>>>(vb, idx, wsm, agg);
    gemm256<1><<<512, 512, 0, stream>>>(agg, W2, b2, out);
}

// Round 8
// 569.913 us; speedup vs baseline: 1.7907x; 1.0481x over previous
//
#include <hip/hip_runtime.h>

typedef __attribute__((ext_vector_type(8))) short bf16x8;
typedef __attribute__((ext_vector_type(4))) short s16x4;
typedef __attribute__((ext_vector_type(4))) float f32x4;

__device__ __forceinline__ float bf2f(unsigned short u) {
    union { unsigned int u; float f; } x; x.u = ((unsigned int)u) << 16; return x.f;
}
__device__ __forceinline__ unsigned short f2bf(float f) {
    union { float f; unsigned int u; } x; x.f = f;
    unsigned int u = x.u;
    unsigned int r = (u + 0x7fffu + ((u >> 16) & 1u)) >> 16;
    return (unsigned short)r;
}

#define GLDS16(gp, lp)                                                        \
    __builtin_amdgcn_global_load_lds(                                         \
        (const __attribute__((address_space(1))) void*)(gp),                  \
        (__attribute__((address_space(3))) void*)(lp), 16, 0, 0)

// ---------------------------------------------------------------------------
// GEMM: C[M, N=1024] = A[M,K=1024] @ W^T + bias. A,W bf16 (W=[N,K]).
// 256x256 tile, BK=64, 8 waves, 128KB LDS dbuf, depth-2 prefetch, counted
// vmcnt(8), raw s_barrier, setprio, XOR-swizzled staging (verified conflicts=0).
// OUT_MODE: 0 = bf16 [row][col], 1 = f32 [row][col], 2 = bf16 transposed
//           [b][col][t] (row = b*2048+t).
// grid = (M/256)*(N/256), requires grid % 8 == 0 or grid <= 16. block 512.
// ---------------------------------------------------------------------------
template<int OUT_MODE>
__global__ __launch_bounds__(512, 2)
void gemm256(const unsigned short* __restrict__ A, const unsigned short* __restrict__ Bw,
             const float* __restrict__ bias, void* __restrict__ out_) {
    __shared__ __align__(16) unsigned short sA[2][16384];
    __shared__ __align__(16) unsigned short sB[2][16384];

    const int tid  = threadIdx.x;
    const int lane = tid & 63;
    const int w    = tid >> 6;
    const int wr   = w >> 2, wc = w & 3;
    const int fr   = lane & 15, g4 = lane >> 4;

    const int bid = blockIdx.x;
    const int qq  = (int)gridDim.x >> 3;
    const int swz = qq ? (bid & 7) * qq + (bid >> 3) : bid;
    const int  col0 = (swz & 3) * 256;
    const long row0 = (long)(swz >> 2) * 256;

    const int srow = tid >> 3;
    const int sj   = (tid & 7) ^ (srow & 7);
    const unsigned short* gA = A  + (size_t)(row0 + srow) * 1024 + sj * 8;
    const unsigned short* gB = Bw + (size_t)(col0 + srow) * 1024 + sj * 8;
    const int ldst = w * 1024;

    auto stage = [&](int buf, int t) {
        const unsigned short* a = gA + t * 64;
        const unsigned short* b = gB + t * 64;
        char* dA = (char*)&sA[buf][0];
        char* dB = (char*)&sB[buf][0];
#pragma unroll
        for (int r = 0; r < 4; ++r)
            GLDS16(a + r * 65536, (__attribute__((address_space(3))) char*)(dA + r * 8192 + ldst));
#pragma unroll
        for (int r = 0; r < 4; ++r)
            GLDS16(b + r * 65536, (__attribute__((address_space(3))) char*)(dB + r * 8192 + ldst));
    };

    f32x4 acc[8][4];
#pragma unroll
    for (int m = 0; m < 8; ++m)
#pragma unroll
        for (int n = 0; n < 4; ++n) acc[m][n] = (f32x4){0.f, 0.f, 0.f, 0.f};

    stage(0, 0);
    stage(1, 1);

    const int mskK = (fr & 7) << 4;

    for (int t = 0; t < 16; ++t) {
        if (t < 15) asm volatile("s_waitcnt vmcnt(8)" ::: "memory");
        else        asm volatile("s_waitcnt vmcnt(0)" ::: "memory");
        asm volatile("s_barrier" ::: "memory");
        __builtin_amdgcn_sched_barrier(0);

        const char* la = (const char*)&sA[t & 1][0];
        const char* lb = (const char*)&sB[t & 1][0];

        bf16x8 bF[2][4];
#pragma unroll
        for (int c = 0; c < 2; ++c)
#pragma unroll
            for (int n = 0; n < 4; ++n) {
                const int row = wc * 64 + n * 16 + fr;
                bF[c][n] = *(const bf16x8*)(lb + row * 128 + ((c * 64 + g4 * 16) ^ mskK));
            }
#pragma unroll
        for (int mh = 0; mh < 2; ++mh) {
            bf16x8 aF[2][4];
#pragma unroll
            for (int c = 0; c < 2; ++c)
#pragma unroll
                for (int m = 0; m < 4; ++m) {
                    const int row = wr * 128 + mh * 64 + m * 16 + fr;
                    aF[c][m] = *(const bf16x8*)(la + row * 128 + ((c * 64 + g4 * 16) ^ mskK));
                }
            __builtin_amdgcn_s_setprio(1);
#pragma unroll
            for (int c = 0; c < 2; ++c)
#pragma unroll
                for (int n = 0; n < 4; ++n)
#pragma unroll
                    for (int m = 0; m < 4; ++m)
                        acc[mh * 4 + m][n] =
                            __builtin_amdgcn_mfma_f32_16x16x32_bf16(aF[c][m], bF[c][n], acc[mh * 4 + m][n], 0, 0, 0);
            __builtin_amdgcn_s_setprio(0);
        }

        __builtin_amdgcn_sched_barrier(0);
        asm volatile("s_barrier" ::: "memory");
        if (t + 2 < 16) stage(t & 1, t + 2);
    }

    const int cr = g4 * 4;
    const int cc = fr;
    if constexpr (OUT_MODE == 2) {
        const int b  = (int)(row0 >> 11);
        const int tb = ((int)row0 & 2047) + wr * 128 + cr;
#pragma unroll
        for (int m = 0; m < 8; ++m) {
#pragma unroll
            for (int n = 0; n < 4; ++n) {
                int col = col0 + wc * 64 + n * 16 + cc;
                float bv = bias[col];
                s16x4 o;
#pragma unroll
                for (int j = 0; j < 4; ++j) o[j] = (short)f2bf(acc[m][n][j] + bv);
                *(s16x4*)&((unsigned short*)out_)[((size_t)b * 1024 + col) * 2048 + tb + m * 16] = o;
            }
        }
    } else {
#pragma unroll
        for (int m = 0; m < 8; ++m) {
            long row = row0 + wr * 128 + m * 16 + cr;
#pragma unroll
            for (int n = 0; n < 4; ++n) {
                int col = col0 + wc * 64 + n * 16 + cc;
                float bv = bias[col];
#pragma unroll
                for (int j = 0; j < 4; ++j) {
                    float v = acc[m][n][j] + bv;
                    if constexpr (OUT_MODE == 1) ((float*)out_)[(row + j) * 1024 + col] = v;
                    else ((unsigned short*)out_)[(row + j) * 1024 + col] = f2bf(v);
                }
            }
        }
    }
}

// ---------------------------------------------------------------------------
// fp32 -> bf16 cast, 8 elems/thread (grid 16384 x 256 for 33.5M elems).
// ---------------------------------------------------------------------------
__global__ __launch_bounds__(256)
void cast_f2b(const float* __restrict__ src, unsigned short* __restrict__ dst) {
    const size_t i = ((size_t)blockIdx.x * 256 + threadIdx.x) * 8;
    f32x4 v0 = *(const f32x4*)(src + i);
    f32x4 v1 = *(const f32x4*)(src + i + 4);
    bf16x8 o;
#pragma unroll
    for (int j = 0; j < 4; ++j) o[j] = (short)f2bf(v0[j]);
#pragma unroll
    for (int j = 0; j < 4; ++j) o[4 + j] = (short)f2bf(v1[j]);
    *(bf16x8*)(dst + i) = o;
}

// ---------------------------------------------------------------------------
// transpose-cast per batch: dst[b][d][t] = bf16(src[b][t][d]).
// grid dim3(32 /*t tiles*/, 16 /*d tiles*/, 16 /*b*/), block 256.
// ---------------------------------------------------------------------------
__global__ __launch_bounds__(256)
void cast_tq(const float* __restrict__ src, unsigned short* __restrict__ dst) {
    __shared__ float t[64][65];
    const int b  = blockIdx.z;
    const int t0 = blockIdx.x * 64;
    const int d0 = blockIdx.y * 64;
    const int tx = threadIdx.x & 63, ty = threadIdx.x >> 6;
    const float* s = src + ((size_t)b * 2048 + t0) * 1024 + d0;
    for (int r = ty; r < 64; r += 4)
        t[r][tx] = s[(size_t)r * 1024 + tx];
    __syncthreads();
    unsigned short* d = dst + ((size_t)b * 1024 + d0) * 2048 + t0;
    for (int r = ty; r < 64; r += 4)
        d[(size_t)r * 2048 + tx] = f2bf(t[tx][r]);
}

// ---------------------------------------------------------------------------
// transpose-cast: dst[j][i] = bf16(src[i][j]), 1024x1024. grid (16,16), 256 thr.
// ---------------------------------------------------------------------------
__global__ __launch_bounds__(256)
void cast_wT(const float* __restrict__ src, unsigned short* __restrict__ dst) {
    __shared__ float t[64][65];
    const int bx = blockIdx.x * 64, by = blockIdx.y * 64;
    const int tx = threadIdx.x & 63, ty = threadIdx.x >> 6;
    for (int r = ty; r < 64; r += 4)
        t[r][tx] = src[(size_t)(by + r) * 1024 + bx + tx];
    __syncthreads();
    for (int r = ty; r < 64; r += 4)
        dst[(size_t)(bx + r) * 1024 + by + tx] = f2bf(t[tx][r]);
}

// ---------------------------------------------------------------------------
// b2[n] = dot(Wo[n,:], bv) + bo[n].  grid 256 x 256 (one wave per n).
// ---------------------------------------------------------------------------
__global__ __launch_bounds__(256)
void bias2_kernel(const float* __restrict__ Wo, const float* __restrict__ bv,
                  const float* __restrict__ bo, float* __restrict__ b2) {
    const int n = blockIdx.x * 4 + (threadIdx.x >> 6);
    const int lane = threadIdx.x & 63;
    float s = 0.f;
    for (int k = lane; k < 1024; k += 64) s += Wo[(size_t)n * 1024 + k] * bv[k];
#pragma unroll
    for (int off = 32; off > 0; off >>= 1) s += __shfl_xor(s, off, 64);
    if (lane == 0) b2[n] = s + bo[n];
}

// ---------------------------------------------------------------------------
// 8-point DFT (negative exponent), in place on xr/xi[8].
// ---------------------------------------------------------------------------
__device__ __forceinline__ void dft8(float* xr, float* xi) {
    const float c8 = 0.70710678118654752440f;
    float es0r = xr[0] + xr[4], es0i = xi[0] + xi[4];
    float es1r = xr[0] - xr[4], es1i = xi[0] - xi[4];
    float es2r = xr[2] + xr[6], es2i = xi[2] + xi[6];
    float es3r = xr[2] - xr[6], es3i = xi[2] - xi[6];
    float E0r = es0r + es2r, E0i = es0i + es2i;
    float E2r = es0r - es2r, E2i = es0i - es2i;
    float E1r = es1r + es3i, E1i = es1i - es3r;
    float E3r = es1r - es3i, E3i = es1i + es3r;
    float os0r = xr[1] + xr[5], os0i = xi[1] + xi[5];
    float os1r = xr[1] - xr[5], os1i = xi[1] - xi[5];
    float os2r = xr[3] + xr[7], os2i = xi[3] + xi[7];
    float os3r = xr[3] - xr[7], os3i = xi[3] - xi[7];
    float O0r = os0r + os2r, O0i = os0i + os2i;
    float O2r = os0r - os2r, O2i = os0i - os2i;
    float O1r = os1r + os3i, O1i = os1i - os3r;
    float O3r = os1r - os3i, O3i = os1i + os3r;
    float p1 = c8 * (O1r + O1i), q1 = c8 * (O1i - O1r);
    float p3 = c8 * (O3r + O3i), q3 = c8 * (O3i - O3r);
    xr[0] = E0r + O0r; xi[0] = E0i + O0i;
    xr[4] = E0r - O0r; xi[4] = E0i - O0i;
    xr[1] = E1r + p1;  xi[1] = E1i + q1;
    xr[5] = E1r - p1;  xi[5] = E1i - q1;
    xr[2] = E2r + O2i; xi[2] = E2i - O2r;
    xr[6] = E2r - O2i; xi[6] = E2i + O2r;
    xr[3] = E3r + q3;  xi[3] = E3i - p3;
    xr[7] = E3r - q3;  xi[7] = E3i + p3;
}

__device__ __forceinline__ int padc(int p) { return p + (p >> 5); }

// apply W^{k} chain (base wr_,wi_) to both streams a and b
#define TWIDDLE2(wr_, wi_)                                                    \
    {                                                                         \
        float cr_ = (wr_), ci_ = (wi_);                                       \
        _Pragma("unroll")                                                     \
        for (int k = 1; k < 8; ++k) {                                         \
            float t0 = ar[k] * cr_ - ai[k] * ci_;                             \
            float t1 = ar[k] * ci_ + ai[k] * cr_;                             \
            ar[k] = t0; ai[k] = t1;                                           \
            float t2 = br[k] * cr_ - bi[k] * ci_;                             \
            float t3 = br[k] * ci_ + bi[k] * cr_;                             \
            br[k] = t2; bi[k] = t3;                                           \
            if (k < 7) {                                                      \
                float nr = cr_ * (wr_) - ci_ * (wi_);                         \
                float ni = cr_ * (wi_) + ci_ * (wr_);                         \
                cr_ = nr; ci_ = ni;                                           \
            }                                                                 \
        }                                                                     \
    }

// ---------------------------------------------------------------------------
// fft_corr v3: dual-column batching, register accumulators, and SEPARATE
// re/im float planes (4B elements -> stride patterns are 2-way = free,
// vs float2's inherent 4-way). grid = 2048 (16 b x 128 chunks), block = 256.
// ---------------------------------------------------------------------------
__global__ __launch_bounds__(256)
void fft_corr(const unsigned short* __restrict__ qt, const unsigned short* __restrict__ kt,
              float* __restrict__ G) {
    __shared__ float sar[2112], sai[2112], sbr[2112], sbi[2112];
    const int tid = threadIdx.x;
    const int b = blockIdx.x >> 7;
    const int chunk = blockIdx.x & 127;

    const float N2PI = -6.28318530717958647692f;
    float w1r, w1i, w2r, w2i, w3r, w3i;
    {
        float s, c;
        __sincosf(N2PI * (float)tid * (1.0f / 2048.0f), &s, &c); w1r = c; w1i = s;
        __sincosf(N2PI * (float)(tid & 31) * (1.0f / 256.0f), &s, &c); w2r = c; w2i = s;
        __sincosf(N2PI * (float)(tid & 3) * (1.0f / 32.0f),  &s, &c); w3r = c; w3i = s;
    }

    float aR0 = 0.f, aI0 = 0.f, aR1 = 0.f, aI1 = 0.f;
    float aR2 = 0.f, aI2 = 0.f, aR3 = 0.f, aI3 = 0.f, aR4 = 0.f;

    const int beta = tid >> 5, s2 = tid & 31;
    const int gam  = tid >> 2, u3 = tid & 3;

    for (int it = 0; it < 4; ++it) {
        const int d0 = chunk * 8 + it * 2;
        const unsigned short* q0 = qt + ((size_t)b * 1024 + d0) * 2048;
        const unsigned short* k0 = kt + ((size_t)b * 1024 + d0) * 2048;
        const unsigned short* q1 = q0 + 2048;
        const unsigned short* k1 = k0 + 2048;

        float ar[8], ai[8], br[8], bi[8];
#pragma unroll
        for (int k = 0; k < 8; ++k) {
            ar[k] = bf2f(q0[tid + 256 * k]); ai[k] = bf2f(k0[tid + 256 * k]);
            br[k] = bf2f(q1[tid + 256 * k]); bi[k] = bf2f(k1[tid + 256 * k]);
        }
        dft8(ar, ai); dft8(br, bi);
        TWIDDLE2(w1r, w1i)
#pragma unroll
        for (int k = 0; k < 8; ++k) {
            const int p = padc(256 * k + tid);
            sar[p] = ar[k]; sai[p] = ai[k]; sbr[p] = br[k]; sbi[p] = bi[k];
        }
        __syncthreads();

        // R2: read/write own positions (no intra-round barrier needed)
#pragma unroll
        for (int k = 0; k < 8; ++k) {
            const int p = padc(256 * beta + 32 * k + s2);
            ar[k] = sar[p]; ai[k] = sai[p]; br[k] = sbr[p]; bi[k] = sbi[p];
        }
        dft8(ar, ai); dft8(br, bi);
        TWIDDLE2(w2r, w2i)
#pragma unroll
        for (int k = 0; k < 8; ++k) {
            const int p = padc(256 * beta + 32 * k + s2);
            sar[p] = ar[k]; sai[p] = ai[k]; sbr[p] = br[k]; sbi[p] = bi[k];
        }
        __syncthreads();

        // R3
#pragma unroll
        for (int k = 0; k < 8; ++k) {
            const int p = padc(32 * gam + 4 * k + u3);
            ar[k] = sar[p]; ai[k] = sai[p]; br[k] = sbr[p]; bi[k] = sbi[p];
        }
        dft8(ar, ai); dft8(br, bi);
        TWIDDLE2(w3r, w3i)
#pragma unroll
        for (int k = 0; k < 8; ++k) {
            const int p = padc(32 * gam + 4 * k + u3);
            sar[p] = ar[k]; sai[p] = ai[k]; sbr[p] = br[k]; sbi[p] = bi[k];
        }
        __syncthreads();

        // R4: read 8t..8t+7
#pragma unroll
        for (int k = 0; k < 8; ++k) {
            const int p = padc(8 * tid + k);
            ar[k] = sar[p]; ai[k] = sai[p]; br[k] = sbr[p]; bi[k] = sbi[p];
        }
        __syncthreads();   // all reads done before natural-order scatter

#pragma unroll
        for (int blk = 0; blk < 2; ++blk) {
            const int o = 4 * blk;
            {
                float s0r = ar[o] + ar[o + 2], s0i = ai[o] + ai[o + 2];
                float s1r = ar[o] - ar[o + 2], s1i = ai[o] - ai[o + 2];
                float s2r = ar[o + 1] + ar[o + 3], s2i = ai[o + 1] + ai[o + 3];
                float s3r = ar[o + 1] - ar[o + 3], s3i = ai[o + 1] - ai[o + 3];
                ar[o + 0] = s0r + s2r; ai[o + 0] = s0i + s2i;
                ar[o + 2] = s0r - s2r; ai[o + 2] = s0i - s2i;
                ar[o + 1] = s1r + s3i; ai[o + 1] = s1i - s3r;
                ar[o + 3] = s1r - s3i; ai[o + 3] = s1i + s3r;
            }
            {
                float s0r = br[o] + br[o + 2], s0i = bi[o] + bi[o + 2];
                float s1r = br[o] - br[o + 2], s1i = bi[o] - bi[o + 2];
                float s2r = br[o + 1] + br[o + 3], s2i = bi[o + 1] + bi[o + 3];
                float s3r = br[o + 1] - br[o + 3], s3i = bi[o + 1] - bi[o + 3];
                br[o + 0] = s0r + s2r; bi[o + 0] = s0i + s2i;
                br[o + 2] = s0r - s2r; bi[o + 2] = s0i - s2i;
                br[o + 1] = s1r + s3i; bi[o + 1] = s1i - s3r;
                br[o + 3] = s1r - s3i; bi[o + 3] = s1i + s3r;
            }
        }
        {
            const int k1 = tid >> 5;
            const int k2 = (tid >> 2) & 7;
            const int fb = k1 + 8 * k2;
#pragma unroll
            for (int blk = 0; blk < 2; ++blk) {
                const int k3 = (2 * (tid & 3) + blk) & 7;
#pragma unroll
                for (int k4 = 0; k4 < 4; ++k4) {
                    const int f = fb + 64 * k3 + 512 * k4;
                    const int pf = padc(f);
                    sar[pf] = ar[4 * blk + k4]; sai[pf] = ai[4 * blk + k4];
                    sbr[pf] = br[4 * blk + k4]; sbi[pf] = bi[4 * blk + k4];
                }
            }
        }
        __syncthreads();

        // Hermitian split + accumulate (registers)
#pragma unroll
        for (int k = 0; k < 4; ++k) {
            const int f = tid + 256 * k;
            const int f2 = (2048 - f) & 2047;
            const int pf = padc(f), pf2 = padc(f2);
            float Zr = sar[pf],  Zi = sai[pf];
            float Yr = sar[pf2], Yi = -sai[pf2];
            float Qr = 0.5f * (Zr + Yr), Qi = 0.5f * (Zi + Yi);
            float Kr = 0.5f * (Zi - Yi), Ki = -0.5f * (Zr - Yr);
            float dR = Qr * Kr + Qi * Ki;
            float dI = Qi * Kr - Qr * Ki;
            Zr = sbr[pf];  Zi = sbi[pf];
            Yr = sbr[pf2]; Yi = -sbi[pf2];
            Qr = 0.5f * (Zr + Yr); Qi = 0.5f * (Zi + Yi);
            Kr = 0.5f * (Zi - Yi); Ki = -0.5f * (Zr - Yr);
            dR += Qr * Kr + Qi * Ki;
            dI += Qi * Kr - Qr * Ki;
            if      (k == 0) { aR0 += dR; aI0 += dI; }
            else if (k == 1) { aR1 += dR; aI1 += dI; }
            else if (k == 2) { aR2 += dR; aI2 += dI; }
            else             { aR3 += dR; aI3 += dI; }
        }
        if (tid == 0) {   // f = 1024: Q = Re(Z), K = Im(Z), P imag = 0
            const int pf = padc(1024);
            aR4 += sar[pf] * sai[pf] + sbr[pf] * sbi[pf];
        }
        __syncthreads();
    }

    atomicAdd(&G[((size_t)b * 1025 + tid +   0) * 2 + 0], aR0);
    atomicAdd(&G[((size_t)b * 1025 + tid +   0) * 2 + 1], aI0);
    atomicAdd(&G[((size_t)b * 1025 + tid + 256) * 2 + 0], aR1);
    atomicAdd(&G[((size_t)b * 1025 + tid + 256) * 2 + 1], aI1);
    atomicAdd(&G[((size_t)b * 1025 + tid + 512) * 2 + 0], aR2);
    atomicAdd(&G[((size_t)b * 1025 + tid + 512) * 2 + 1], aI2);
    atomicAdd(&G[((size_t)b * 1025 + tid + 768) * 2 + 0], aR3);
    atomicAdd(&G[((size_t)b * 1025 + tid + 768) * 2 + 1], aI3);
    if (tid == 0)
        atomicAdd(&G[((size_t)b * 1025 + 1024) * 2 + 0], aR4);
}

// ---------------------------------------------------------------------------
// In-LDS radix-2 DIT FFT, N=2048 (only used by irfft_mean: 16 blocks, cheap).
// ---------------------------------------------------------------------------
__device__ __forceinline__ void fft2048(float* zr, float* zi,
                                        const float* twr, const float* twi, int tid) {
    for (int t = tid; t < 2048; t += 256) {
        int j = __brev((unsigned)t) >> 21;
        if (j > t) {
            float a = zr[t]; zr[t] = zr[j]; zr[j] = a;
            float c = zi[t]; zi[t] = zi[j]; zi[j] = c;
        }
    }
    __syncthreads();
    for (int s = 0; s < 11; ++s) {
        const int m = 1 << s;
        for (int i = tid; i < 1024; i += 256) {
            const int pos = i & (m - 1);
            const int i1  = ((i >> s) << (s + 1)) + pos;
            const int i2  = i1 + m;
            const int tw  = pos << (10 - s);
            float wr = twr[tw], wi = twi[tw];
            float xr = zr[i2], xi = zi[i2];
            float tr = wr * xr - wi * xi;
            float ti = wr * xi + wi * xr;
            float ur = zr[i1], ui = zi[i1];
            zr[i2] = ur - tr; zi[i2] = ui - ti;
            zr[i1] = ur + tr; zi[i1] = ui + ti;
        }
        __syncthreads();
    }
}

__device__ __forceinline__ void init_twiddle(float* twr, float* twi, int tid) {
    for (int j = tid; j < 1024; j += 256) {
        float ang = -6.28318530717958647692f * (float)j * (1.0f / 2048.0f);
        twr[j] = cosf(ang);
        twi[j] = sinf(ang);
    }
}

// ---------------------------------------------------------------------------
// Per-batch irfft of G -> mean_value[b][t], scale 1/(2048*1024). grid = 16.
// ---------------------------------------------------------------------------
__global__ __launch_bounds__(256)
void irfft_mean(const float* __restrict__ G, float* __restrict__ mv) {
    __shared__ float zr[2048], zi[2048];
    __shared__ float twr[1024], twi[1024];
    const int tid = threadIdx.x;
    const int b = blockIdx.x;
    init_twiddle(twr, twi, tid);
    for (int f = tid; f < 2048; f += 256) {
        int g = (f <= 1024) ? f : 2048 - f;
        float gr = G[((size_t)b * 1025 + g) * 2 + 0];
        float gi = G[((size_t)b * 1025 + g) * 2 + 1];
        zr[f] = gr;
        zi[f] = (f <= 1024) ? -gi : gi;
    }
    __syncthreads();
    fft2048(zr, zi, twr, twi, tid);
    const float sc = 1.0f / (2048.0f * 1024.0f);
    for (int t = tid; t < 2048; t += 256) mv[b * 2048 + t] = zr[t] * sc;
}

// ---------------------------------------------------------------------------
// Top-7 over batch-mean + per-batch softmax (parallel argmax).
// ---------------------------------------------------------------------------
__global__ __launch_bounds__(256)
void topk_softmax(const float* __restrict__ mv, int* __restrict__ idx_out,
                  float* __restrict__ w_out) {
    __shared__ float cm[2048];
    __shared__ float wv4[4];
    __shared__ int   wi4[4];
    __shared__ int   sel[7];
    const int tid  = threadIdx.x;
    const int lane = tid & 63;
    const int wvid = tid >> 6;

    for (int t = tid; t < 2048; t += 256) {
        float s = 0.f;
        for (int b = 0; b < 16; ++b) s += mv[b * 2048 + t];
        cm[t] = s * (1.0f / 16.0f);
    }
    __syncthreads();

    for (int it = 0; it < 7; ++it) {
        float best = -3.4e38f; int bi = 1 << 30;
#pragma unroll
        for (int q = 0; q < 8; ++q) {
            const int t = tid + q * 256;
            float v = cm[t];
            if (v > best || (v == best && t < bi)) { best = v; bi = t; }
        }
#pragma unroll
        for (int off = 32; off > 0; off >>= 1) {
            float ov = __shfl_xor(best, off, 64);
            int   oi = __shfl_xor(bi,   off, 64);
            if (ov > best || (ov == best && oi < bi)) { best = ov; bi = oi; }
        }
        if (lane == 0) { wv4[wvid] = best; wi4[wvid] = bi; }
        __syncthreads();
        if (tid == 0) {
            float bb = wv4[0]; int bj = wi4[0];
#pragma unroll
            for (int u = 1; u < 4; ++u)
                if (wv4[u] > bb || (wv4[u] == bb && wi4[u] < bj)) { bb = wv4[u]; bj = wi4[u]; }
            sel[it] = bj;
            idx_out[it] = bj;
            cm[bj] = -3.4e38f;
        }
        __syncthreads();
    }

    if (tid < 16) {
        const int b = tid;
        float wv[7]; float mx = -3.4e38f;
#pragma unroll
        for (int i = 0; i < 7; ++i) { wv[i] = mv[b * 2048 + sel[i]]; mx = fmaxf(mx, wv[i]); }
        float s = 0.f;
#pragma unroll
        for (int i = 0; i < 7; ++i) { wv[i] = expf(wv[i] - mx); s += wv[i]; }
        float inv = 1.0f / s;
#pragma unroll
        for (int i = 0; i < 7; ++i) w_out[b * 7 + i] = wv[i] * inv;
    }
}

// ---------------------------------------------------------------------------
// agg[b,t,d] = sum_i w[b,i] * vb[b,(t+idx[i])%2048,d]  (bf16 in/out)
// ---------------------------------------------------------------------------
__global__ __launch_bounds__(256)
void agg_kernel(const unsigned short* __restrict__ vb, const int* __restrict__ idx,
                const float* __restrict__ w, unsigned short* __restrict__ agg) {
    const int b  = blockIdx.y;
    const int t  = blockIdx.x * 2 + (threadIdx.x >> 7);
    const int d8 = (threadIdx.x & 127) * 8;
    float av[8] = {0.f, 0.f, 0.f, 0.f, 0.f, 0.f, 0.f, 0.f};
#pragma unroll
    for (int i = 0; i < 7; ++i) {
        const int srow = (t + idx[i]) & 2047;
        const float wi = w[b * 7 + i];
        bf16x8 v = *(const bf16x8*)&vb[((size_t)b * 2048 + srow) * 1024 + d8];
#pragma unroll
        for (int j = 0; j < 8; ++j) av[j] += wi * bf2f((unsigned short)v[j]);
    }
    bf16x8 o;
#pragma unroll
    for (int j = 0; j < 8; ++j) o[j] = (short)f2bf(av[j]);
    *(bf16x8*)&agg[((size_t)b * 2048 + t) * 1024 + d8] = o;
}

// ---------------------------------------------------------------------------
__global__ __launch_bounds__(256)
void cast_w(const float* __restrict__ src, unsigned short* __restrict__ dst) {
    const int i = (blockIdx.x * 256 + threadIdx.x) * 4;   // n = 1048576 exact
    f32x4 v = *(const f32x4*)(src + i);
    s16x4 o;
#pragma unroll
    for (int j = 0; j < 4; ++j) o[j] = (short)f2bf(v[j]);
    *(s16x4*)(dst + i) = o;
}

__global__ __launch_bounds__(256)
void zero_f32(float* __restrict__ p, int n) {
    const int i = blockIdx.x * 256 + threadIdx.x;
    if (i < n) p[i] = 0.0f;
}

// ---------------------------------------------------------------------------
extern "C" void kernel_launch(void* const* d_in, const int* in_sizes, int n_in,
                              void* d_out, int out_size, void* d_ws, size_t ws_size,
                              hipStream_t stream) {
    const float* queries = (const float*)d_in[0];
    const float* keys    = (const float*)d_in[1];
    const float* values  = (const float*)d_in[2];
    const float* Wq = (const float*)d_in[3];  const float* bq = (const float*)d_in[4];
    const float* Wk = (const float*)d_in[5];  const float* bk = (const float*)d_in[6];
    const float* Wv = (const float*)d_in[7];  const float* bv = (const float*)d_in[8];
    const float* Wo = (const float*)d_in[9];  const float* bo = (const float*)d_in[10];
    float* out = (float*)d_out;

    char* ws = (char*)d_ws;
    constexpr size_t SZP = (size_t)32768 * 1024 * 2;           // 64 MB (bf16 B*L*D)
    unsigned short* qt  = (unsigned short*)(ws);               // raw-q^T [b][d][t]; reused as agg
    unsigned short* kt  = (unsigned short*)(ws + SZP);         // k~^T [b][d][t]
    unsigned short* vb  = (unsigned short*)(ws + 2 * SZP);     // cast values [b][t][d]
    unsigned short* ab  = (unsigned short*)(ws + 3 * SZP);     // staging (64MB)
    // weight temps live in ab until cast_f2b(keys) overwrites (all consumed by then)
    unsigned short* wo  = ab;                                  // bf16 Wo
    unsigned short* wvT = ab + 1048576;                        // bf16 Wv^T
    unsigned short* wqT = ab + 2097152;                        // bf16 Wq^T
    unsigned short* wkT = ab + 3145728;                        // bf16 Wk^T
    unsigned short* W2  = (unsigned short*)(ws + 4 * SZP);     // bf16 Wo@Wv   [N][K]
    unsigned short* M   = W2 + 1048576;                        // bf16 Wq^T@Wk [N][K]
    char* tail = ws + 4 * SZP + 4194304;
    float* zb1024 = (float*)(tail);                            // 4KB zero bias
    float* b2     = (float*)(tail + 4096);
    float* G      = (float*)(tail + 8192);                     // 16*1025*2 f32
    float* mv     = (float*)(tail + 8192 + 131328);
    int*   idx    = (int*)  (tail + 8192 + 131328 + 131072);
    float* wsm    = (float*)(tail + 8192 + 131328 + 131072 + 64);
    unsigned short* agg = qt;

    // weight prep: W2 = Wo@Wv, b2 = Wo@bv + bo, M = Wq^T@Wk
    cast_w<<<1024, 256, 0, stream>>>(Wo, wo);
    cast_wT<<<dim3(16, 16), 256, 0, stream>>>(Wv, wvT);
    cast_wT<<<dim3(16, 16), 256, 0, stream>>>(Wq, wqT);
    cast_wT<<<dim3(16, 16), 256, 0, stream>>>(Wk, wkT);
    zero_f32<<<(32800 + 255) / 256, 256, 0, stream>>>(G, 32800);
    zero_f32<<<4, 256, 0, stream>>>(zb1024, 1024);
    bias2_kernel<<<256, 256, 0, stream>>>(Wo, bv, bo, b2);
    gemm256<0><<<16, 512, 0, stream>>>(wo, wvT, zb1024, W2);
    gemm256<0><<<16, 512, 0, stream>>>(wqT, wkT, zb1024, M);

    // k~ = k @ M^T (transposed out); raw q transpose-cast; values cast
    cast_f2b<<<16384, 256, 0, stream>>>(keys, ab);
    gemm256<2><<<512, 512, 0, stream>>>(ab, M, zb1024, kt);
    cast_tq<<<dim3(32, 16, 16), 256, 0, stream>>>(queries, qt);
    cast_f2b<<<16384, 256, 0, stream>>>(values, vb);

    // correlation -> top-k -> aggregation -> fused output GEMM
    fft_corr<<<2048, 256, 0, stream>>>(qt, kt, G);
    irfft_mean<<<16, 256, 0, stream>>>(G, mv);
    topk_softmax<<<1, 256, 0, stream>>>(mv, idx, wsm);
    agg_kernel<<<dim3(1024, 16), 256, 0, stream>>>(vb, idx, wsm, agg);
    gemm256<1><<<512, 512, 0, stream>>>(agg, W2, b2, out);
}

// Round 9
// 561.822 us; speedup vs baseline: 1.8165x; 1.0144x over previous
//
#include <hip/hip_runtime.h>

typedef __attribute__((ext_vector_type(8))) short bf16x8;
typedef __attribute__((ext_vector_type(4))) short s16x4;
typedef __attribute__((ext_vector_type(4))) float f32x4;

__device__ __forceinline__ float bf2f(unsigned short u) {
    union { unsigned int u; float f; } x; x.u = ((unsigned int)u) << 16; return x.f;
}
__device__ __forceinline__ unsigned short f2bf(float f) {
    union { float f; unsigned int u; } x; x.f = f;
    unsigned int u = x.u;
    unsigned int r = (u + 0x7fffu + ((u >> 16) & 1u)) >> 16;
    return (unsigned short)r;
}

#define GLDS16(gp, lp)                                                        \
    __builtin_amdgcn_global_load_lds(                                         \
        (const __attribute__((address_space(1))) void*)(gp),                  \
        (__attribute__((address_space(3))) void*)(lp), 16, 0, 0)

// ---------------------------------------------------------------------------
// GEMM: C[M, N=1024] = A[M,K=1024] @ W^T + bias. A,W bf16 (W=[N,K]).
// 256x256 tile, BK=64, 8 waves, 128KB LDS dbuf, depth-2 prefetch, counted
// vmcnt(8), raw s_barrier, setprio, XOR-swizzled staging (verified conflicts=0).
// OUT_MODE: 0 = bf16 [row][col], 1 = f32 [row][col], 2 = bf16 transposed
//           [b][col][t] (row = b*2048+t).
// ---------------------------------------------------------------------------
template<int OUT_MODE>
__global__ __launch_bounds__(512, 2)
void gemm256(const unsigned short* __restrict__ A, const unsigned short* __restrict__ Bw,
             const float* __restrict__ bias, void* __restrict__ out_) {
    __shared__ __align__(16) unsigned short sA[2][16384];
    __shared__ __align__(16) unsigned short sB[2][16384];

    const int tid  = threadIdx.x;
    const int lane = tid & 63;
    const int w    = tid >> 6;
    const int wr   = w >> 2, wc = w & 3;
    const int fr   = lane & 15, g4 = lane >> 4;

    const int bid = blockIdx.x;
    const int qq  = (int)gridDim.x >> 3;
    const int swz = qq ? (bid & 7) * qq + (bid >> 3) : bid;
    const int  col0 = (swz & 3) * 256;
    const long row0 = (long)(swz >> 2) * 256;

    const int srow = tid >> 3;
    const int sj   = (tid & 7) ^ (srow & 7);
    const unsigned short* gA = A  + (size_t)(row0 + srow) * 1024 + sj * 8;
    const unsigned short* gB = Bw + (size_t)(col0 + srow) * 1024 + sj * 8;
    const int ldst = w * 1024;

    auto stage = [&](int buf, int t) {
        const unsigned short* a = gA + t * 64;
        const unsigned short* b = gB + t * 64;
        char* dA = (char*)&sA[buf][0];
        char* dB = (char*)&sB[buf][0];
#pragma unroll
        for (int r = 0; r < 4; ++r)
            GLDS16(a + r * 65536, (__attribute__((address_space(3))) char*)(dA + r * 8192 + ldst));
#pragma unroll
        for (int r = 0; r < 4; ++r)
            GLDS16(b + r * 65536, (__attribute__((address_space(3))) char*)(dB + r * 8192 + ldst));
    };

    f32x4 acc[8][4];
#pragma unroll
    for (int m = 0; m < 8; ++m)
#pragma unroll
        for (int n = 0; n < 4; ++n) acc[m][n] = (f32x4){0.f, 0.f, 0.f, 0.f};

    stage(0, 0);
    stage(1, 1);

    const int mskK = (fr & 7) << 4;

    for (int t = 0; t < 16; ++t) {
        if (t < 15) asm volatile("s_waitcnt vmcnt(8)" ::: "memory");
        else        asm volatile("s_waitcnt vmcnt(0)" ::: "memory");
        asm volatile("s_barrier" ::: "memory");
        __builtin_amdgcn_sched_barrier(0);

        const char* la = (const char*)&sA[t & 1][0];
        const char* lb = (const char*)&sB[t & 1][0];

        bf16x8 bF[2][4];
#pragma unroll
        for (int c = 0; c < 2; ++c)
#pragma unroll
            for (int n = 0; n < 4; ++n) {
                const int row = wc * 64 + n * 16 + fr;
                bF[c][n] = *(const bf16x8*)(lb + row * 128 + ((c * 64 + g4 * 16) ^ mskK));
            }
#pragma unroll
        for (int mh = 0; mh < 2; ++mh) {
            bf16x8 aF[2][4];
#pragma unroll
            for (int c = 0; c < 2; ++c)
#pragma unroll
                for (int m = 0; m < 4; ++m) {
                    const int row = wr * 128 + mh * 64 + m * 16 + fr;
                    aF[c][m] = *(const bf16x8*)(la + row * 128 + ((c * 64 + g4 * 16) ^ mskK));
                }
            __builtin_amdgcn_s_setprio(1);
#pragma unroll
            for (int c = 0; c < 2; ++c)
#pragma unroll
                for (int n = 0; n < 4; ++n)
#pragma unroll
                    for (int m = 0; m < 4; ++m)
                        acc[mh * 4 + m][n] =
                            __builtin_amdgcn_mfma_f32_16x16x32_bf16(aF[c][m], bF[c][n], acc[mh * 4 + m][n], 0, 0, 0);
            __builtin_amdgcn_s_setprio(0);
        }

        __builtin_amdgcn_sched_barrier(0);
        asm volatile("s_barrier" ::: "memory");
        if (t + 2 < 16) stage(t & 1, t + 2);
    }

    const int cr = g4 * 4;
    const int cc = fr;
    if constexpr (OUT_MODE == 2) {
        const int b  = (int)(row0 >> 11);
        const int tb = ((int)row0 & 2047) + wr * 128 + cr;
#pragma unroll
        for (int m = 0; m < 8; ++m) {
#pragma unroll
            for (int n = 0; n < 4; ++n) {
                int col = col0 + wc * 64 + n * 16 + cc;
                float bv = bias[col];
                s16x4 o;
#pragma unroll
                for (int j = 0; j < 4; ++j) o[j] = (short)f2bf(acc[m][n][j] + bv);
                *(s16x4*)&((unsigned short*)out_)[((size_t)b * 1024 + col) * 2048 + tb + m * 16] = o;
            }
        }
    } else {
#pragma unroll
        for (int m = 0; m < 8; ++m) {
            long row = row0 + wr * 128 + m * 16 + cr;
#pragma unroll
            for (int n = 0; n < 4; ++n) {
                int col = col0 + wc * 64 + n * 16 + cc;
                float bv = bias[col];
#pragma unroll
                for (int j = 0; j < 4; ++j) {
                    float v = acc[m][n][j] + bv;
                    if constexpr (OUT_MODE == 1) ((float*)out_)[(row + j) * 1024 + col] = v;
                    else ((unsigned short*)out_)[(row + j) * 1024 + col] = f2bf(v);
                }
            }
        }
    }
}

// ---------------------------------------------------------------------------
// fp32 -> bf16 cast, 8 elems/thread (grid 16384 x 256 for 33.5M elems).
// ---------------------------------------------------------------------------
__global__ __launch_bounds__(256)
void cast_f2b(const float* __restrict__ src, unsigned short* __restrict__ dst) {
    const size_t i = ((size_t)blockIdx.x * 256 + threadIdx.x) * 8;
    f32x4 v0 = *(const f32x4*)(src + i);
    f32x4 v1 = *(const f32x4*)(src + i + 4);
    bf16x8 o;
#pragma unroll
    for (int j = 0; j < 4; ++j) o[j] = (short)f2bf(v0[j]);
#pragma unroll
    for (int j = 0; j < 4; ++j) o[4 + j] = (short)f2bf(v1[j]);
    *(bf16x8*)(dst + i) = o;
}

// ---------------------------------------------------------------------------
// transpose-cast: dst[j][i] = bf16(src[i][j]), 1024x1024. grid (16,16), 256 thr.
// ---------------------------------------------------------------------------
__global__ __launch_bounds__(256)
void cast_wT(const float* __restrict__ src, unsigned short* __restrict__ dst) {
    __shared__ float t[64][65];
    const int bx = blockIdx.x * 64, by = blockIdx.y * 64;
    const int tx = threadIdx.x & 63, ty = threadIdx.x >> 6;
    for (int r = ty; r < 64; r += 4)
        t[r][tx] = src[(size_t)(by + r) * 1024 + bx + tx];
    __syncthreads();
    for (int r = ty; r < 64; r += 4)
        dst[(size_t)(bx + r) * 1024 + by + tx] = f2bf(t[tx][r]);
}

// ---------------------------------------------------------------------------
// b2[n] = dot(Wo[n,:], bv) + bo[n].  grid 256 (one wave per n, 4 waves/block).
// ---------------------------------------------------------------------------
__global__ __launch_bounds__(256)
void bias2_kernel(const float* __restrict__ Wo, const float* __restrict__ bv,
                  const float* __restrict__ bo, float* __restrict__ b2) {
    const int n = blockIdx.x * 4 + (threadIdx.x >> 6);
    const int lane = threadIdx.x & 63;
    float s = 0.f;
    for (int k = lane; k < 1024; k += 64) s += Wo[(size_t)n * 1024 + k] * bv[k];
#pragma unroll
    for (int off = 32; off > 0; off >>= 1) s += __shfl_xor(s, off, 64);
    if (lane == 0) b2[n] = s + bo[n];
}

// ---------------------------------------------------------------------------
// 8-point DFT (negative exponent), in place on xr/xi[8].
// ---------------------------------------------------------------------------
__device__ __forceinline__ void dft8(float* xr, float* xi) {
    const float c8 = 0.70710678118654752440f;
    float es0r = xr[0] + xr[4], es0i = xi[0] + xi[4];
    float es1r = xr[0] - xr[4], es1i = xi[0] - xi[4];
    float es2r = xr[2] + xr[6], es2i = xi[2] + xi[6];
    float es3r = xr[2] - xr[6], es3i = xi[2] - xi[6];
    float E0r = es0r + es2r, E0i = es0i + es2i;
    float E2r = es0r - es2r, E2i = es0i - es2i;
    float E1r = es1r + es3i, E1i = es1i - es3r;
    float E3r = es1r - es3i, E3i = es1i + es3r;
    float os0r = xr[1] + xr[5], os0i = xi[1] + xi[5];
    float os1r = xr[1] - xr[5], os1i = xi[1] - xi[5];
    float os2r = xr[3] + xr[7], os2i = xi[3] + xi[7];
    float os3r = xr[3] - xr[7], os3i = xi[3] - xi[7];
    float O0r = os0r + os2r, O0i = os0i + os2i;
    float O2r = os0r - os2r, O2i = os0i - os2i;
    float O1r = os1r + os3i, O1i = os1i - os3r;
    float O3r = os1r - os3i, O3i = os1i + os3r;
    float p1 = c8 * (O1r + O1i), q1 = c8 * (O1i - O1r);
    float p3 = c8 * (O3r + O3i), q3 = c8 * (O3i - O3r);
    xr[0] = E0r + O0r; xi[0] = E0i + O0i;
    xr[4] = E0r - O0r; xi[4] = E0i - O0i;
    xr[1] = E1r + p1;  xi[1] = E1i + q1;
    xr[5] = E1r - p1;  xi[5] = E1i - q1;
    xr[2] = E2r + O2i; xi[2] = E2i - O2r;
    xr[6] = E2r - O2i; xi[6] = E2i + O2r;
    xr[3] = E3r + q3;  xi[3] = E3i - p3;
    xr[7] = E3r - q3;  xi[7] = E3i + p3;
}

// XOR swizzle on element index (involution): folds bits [5:8) into [2:5).
// Fixes R3's structural 16-way (32-aligned blocks) while keeping R1/R2 dense.
__device__ __forceinline__ int ps(int p) { return p ^ (((p >> 5) & 7) << 2); }

// apply W^{k} chain (base wr_,wi_) to both streams a and b
#define TWIDDLE2(wr_, wi_)                                                    \
    {                                                                         \
        float cr_ = (wr_), ci_ = (wi_);                                       \
        _Pragma("unroll")                                                     \
        for (int k = 1; k < 8; ++k) {                                         \
            float t0 = ar[k] * cr_ - ai[k] * ci_;                             \
            float t1 = ar[k] * ci_ + ai[k] * cr_;                             \
            ar[k] = t0; ai[k] = t1;                                           \
            float t2 = br[k] * cr_ - bi[k] * ci_;                             \
            float t3 = br[k] * ci_ + bi[k] * cr_;                             \
            br[k] = t2; bi[k] = t3;                                           \
            if (k < 7) {                                                      \
                float nr = cr_ * (wr_) - ci_ * (wi_);                         \
                float ni = cr_ * (wi_) + ci_ * (wr_);                         \
                cr_ = nr; ci_ = ni;                                           \
            }                                                                 \
        }                                                                     \
    }

// ---------------------------------------------------------------------------
// fft_corr v4: q read DIRECTLY from fp32 [b][t][d] (dwordx2 per 2 cols; the
// 64B line spans d0..d0+15 -> reused by all 4 iters + sibling chunk on the
// same XCD via chunked block swizzle). float2 planes + XOR swizzle ps():
// all rounds bank-dense. Register accumulators. 2048 blocks x 256.
// ---------------------------------------------------------------------------
__global__ __launch_bounds__(256)
void fft_corr(const float* __restrict__ qf, const unsigned short* __restrict__ kt,
              float* __restrict__ G) {
    __shared__ float2 za[2048];
    __shared__ float2 zb[2048];
    const int tid = threadIdx.x;
    const int bid = blockIdx.x;
    const int swzb = (bid & 7) * 256 + (bid >> 3);   // sibling chunks -> same XCD
    const int b = swzb >> 7;
    const int chunk = swzb & 127;

    const float N2PI = -6.28318530717958647692f;
    float w1r, w1i, w2r, w2i, w3r, w3i;
    {
        float s, c;
        __sincosf(N2PI * (float)tid * (1.0f / 2048.0f), &s, &c); w1r = c; w1i = s;
        __sincosf(N2PI * (float)(tid & 31) * (1.0f / 256.0f), &s, &c); w2r = c; w2i = s;
        __sincosf(N2PI * (float)(tid & 3) * (1.0f / 32.0f),  &s, &c); w3r = c; w3i = s;
    }

    float aR0 = 0.f, aI0 = 0.f, aR1 = 0.f, aI1 = 0.f;
    float aR2 = 0.f, aI2 = 0.f, aR3 = 0.f, aI3 = 0.f, aR4 = 0.f;

    const int beta = tid >> 5, s2 = tid & 31;
    const int gam  = tid >> 2, u3 = tid & 3;

    for (int it = 0; it < 4; ++it) {
        const int d0 = chunk * 8 + it * 2;           // even -> 8B aligned
        const float* qbase = qf + (size_t)b * 2048 * 1024 + d0;
        const unsigned short* k0 = kt + ((size_t)b * 1024 + d0) * 2048;
        const unsigned short* k1 = k0 + 2048;

        float ar[8], ai[8], br[8], bi[8];
        // R1: q fp32 direct (dwordx2), k~ bf16 coalesced
#pragma unroll
        for (int k = 0; k < 8; ++k) {
            const int t = tid + 256 * k;
            float2 qv = *(const float2*)(qbase + (size_t)t * 1024);
            ar[k] = qv.x; br[k] = qv.y;
            ai[k] = bf2f(k0[t]); bi[k] = bf2f(k1[t]);
        }
        dft8(ar, ai); dft8(br, bi);
        TWIDDLE2(w1r, w1i)
#pragma unroll
        for (int k = 0; k < 8; ++k) {
            const int p = ps(256 * k + tid);
            za[p] = make_float2(ar[k], ai[k]);
            zb[p] = make_float2(br[k], bi[k]);
        }
        __syncthreads();

        // R2 (read own set / write own set)
#pragma unroll
        for (int k = 0; k < 8; ++k) {
            const int p = ps(256 * beta + 32 * k + s2);
            float2 va = za[p]; ar[k] = va.x; ai[k] = va.y;
            float2 vb = zb[p]; br[k] = vb.x; bi[k] = vb.y;
        }
        dft8(ar, ai); dft8(br, bi);
        TWIDDLE2(w2r, w2i)
#pragma unroll
        for (int k = 0; k < 8; ++k) {
            const int p = ps(256 * beta + 32 * k + s2);
            za[p] = make_float2(ar[k], ai[k]);
            zb[p] = make_float2(br[k], bi[k]);
        }
        __syncthreads();

        // R3
#pragma unroll
        for (int k = 0; k < 8; ++k) {
            const int p = ps(32 * gam + 4 * k + u3);
            float2 va = za[p]; ar[k] = va.x; ai[k] = va.y;
            float2 vb = zb[p]; br[k] = vb.x; bi[k] = vb.y;
        }
        dft8(ar, ai); dft8(br, bi);
        TWIDDLE2(w3r, w3i)
#pragma unroll
        for (int k = 0; k < 8; ++k) {
            const int p = ps(32 * gam + 4 * k + u3);
            za[p] = make_float2(ar[k], ai[k]);
            zb[p] = make_float2(br[k], bi[k]);
        }
        __syncthreads();

        // R4: read 8t..8t+7
#pragma unroll
        for (int k = 0; k < 8; ++k) {
            const int p = ps(8 * tid + k);
            float2 va = za[p]; ar[k] = va.x; ai[k] = va.y;
            float2 vb = zb[p]; br[k] = vb.x; bi[k] = vb.y;
        }
        __syncthreads();   // reads done before natural-order scatter overwrites

        // radix-4 pairs (no twiddle), then scatter to natural order
#pragma unroll
        for (int blk = 0; blk < 2; ++blk) {
            const int o = 4 * blk;
            {
                float s0r = ar[o] + ar[o + 2], s0i = ai[o] + ai[o + 2];
                float s1r = ar[o] - ar[o + 2], s1i = ai[o] - ai[o + 2];
                float s2r = ar[o + 1] + ar[o + 3], s2i = ai[o + 1] + ai[o + 3];
                float s3r = ar[o + 1] - ar[o + 3], s3i = ai[o + 1] - ai[o + 3];
                ar[o + 0] = s0r + s2r; ai[o + 0] = s0i + s2i;
                ar[o + 2] = s0r - s2r; ai[o + 2] = s0i - s2i;
                ar[o + 1] = s1r + s3i; ai[o + 1] = s1i - s3r;
                ar[o + 3] = s1r - s3i; ai[o + 3] = s1i + s3r;
            }
            {
                float s0r = br[o] + br[o + 2], s0i = bi[o] + bi[o + 2];
                float s1r = br[o] - br[o + 2], s1i = bi[o] - bi[o + 2];
                float s2r = br[o + 1] + br[o + 3], s2i = bi[o + 1] + bi[o + 3];
                float s3r = br[o + 1] - br[o + 3], s3i = bi[o + 1] - bi[o + 3];
                br[o + 0] = s0r + s2r; bi[o + 0] = s0i + s2i;
                br[o + 2] = s0r - s2r; bi[o + 2] = s0i - s2i;
                br[o + 1] = s1r + s3i; bi[o + 1] = s1i - s3r;
                br[o + 3] = s1r - s3i; bi[o + 3] = s1i + s3r;
            }
        }
        {
            const int k1d = tid >> 5;
            const int k2d = (tid >> 2) & 7;
            const int fb = k1d + 8 * k2d;
#pragma unroll
            for (int blk = 0; blk < 2; ++blk) {
                const int k3d = (2 * (tid & 3) + blk) & 7;
#pragma unroll
                for (int k4 = 0; k4 < 4; ++k4) {
                    const int f = fb + 64 * k3d + 512 * k4;
                    const int pf = ps(f);
                    za[pf] = make_float2(ar[4 * blk + k4], ai[4 * blk + k4]);
                    zb[pf] = make_float2(br[4 * blk + k4], bi[4 * blk + k4]);
                }
            }
        }
        __syncthreads();

        // Hermitian split + accumulate (registers)
#pragma unroll
        for (int k = 0; k < 4; ++k) {
            const int f = tid + 256 * k;
            const int f2 = (2048 - f) & 2047;
            const int pf = ps(f), pf2 = ps(f2);
            float2 Za = za[pf], Ya = za[pf2];
            float Qr = 0.5f * (Za.x + Ya.x), Qi = 0.5f * (Za.y - Ya.y);
            float Kr = 0.5f * (Za.y + Ya.y), Ki = -0.5f * (Za.x - Ya.x);
            float dR = Qr * Kr + Qi * Ki;
            float dI = Qi * Kr - Qr * Ki;
            float2 Zb = zb[pf], Yb = zb[pf2];
            Qr = 0.5f * (Zb.x + Yb.x); Qi = 0.5f * (Zb.y - Yb.y);
            Kr = 0.5f * (Zb.y + Yb.y); Ki = -0.5f * (Zb.x - Yb.x);
            dR += Qr * Kr + Qi * Ki;
            dI += Qi * Kr - Qr * Ki;
            if      (k == 0) { aR0 += dR; aI0 += dI; }
            else if (k == 1) { aR1 += dR; aI1 += dI; }
            else if (k == 2) { aR2 += dR; aI2 += dI; }
            else             { aR3 += dR; aI3 += dI; }
        }
        if (tid == 0) {   // f = 1024: Q = Re(Z), K = Im(Z), P imag = 0
            const int pf = ps(1024);
            aR4 += za[pf].x * za[pf].y + zb[pf].x * zb[pf].y;
        }
        __syncthreads();
    }

    atomicAdd(&G[((size_t)b * 1025 + tid +   0) * 2 + 0], aR0);
    atomicAdd(&G[((size_t)b * 1025 + tid +   0) * 2 + 1], aI0);
    atomicAdd(&G[((size_t)b * 1025 + tid + 256) * 2 + 0], aR1);
    atomicAdd(&G[((size_t)b * 1025 + tid + 256) * 2 + 1], aI1);
    atomicAdd(&G[((size_t)b * 1025 + tid + 512) * 2 + 0], aR2);
    atomicAdd(&G[((size_t)b * 1025 + tid + 512) * 2 + 1], aI2);
    atomicAdd(&G[((size_t)b * 1025 + tid + 768) * 2 + 0], aR3);
    atomicAdd(&G[((size_t)b * 1025 + tid + 768) * 2 + 1], aI3);
    if (tid == 0)
        atomicAdd(&G[((size_t)b * 1025 + 1024) * 2 + 0], aR4);
}

// ---------------------------------------------------------------------------
// In-LDS radix-2 DIT FFT, N=2048 (only used by irfft_mean: 16 blocks, cheap).
// ---------------------------------------------------------------------------
__device__ __forceinline__ void fft2048(float* zr, float* zi,
                                        const float* twr, const float* twi, int tid) {
    for (int t = tid; t < 2048; t += 256) {
        int j = __brev((unsigned)t) >> 21;
        if (j > t) {
            float a = zr[t]; zr[t] = zr[j]; zr[j] = a;
            float c = zi[t]; zi[t] = zi[j]; zi[j] = c;
        }
    }
    __syncthreads();
    for (int s = 0; s < 11; ++s) {
        const int m = 1 << s;
        for (int i = tid; i < 1024; i += 256) {
            const int pos = i & (m - 1);
            const int i1  = ((i >> s) << (s + 1)) + pos;
            const int i2  = i1 + m;
            const int tw  = pos << (10 - s);
            float wr = twr[tw], wi = twi[tw];
            float xr = zr[i2], xi = zi[i2];
            float tr = wr * xr - wi * xi;
            float ti = wr * xi + wi * xr;
            float ur = zr[i1], ui = zi[i1];
            zr[i2] = ur - tr; zi[i2] = ui - ti;
            zr[i1] = ur + tr; zi[i1] = ui + ti;
        }
        __syncthreads();
    }
}

__device__ __forceinline__ void init_twiddle(float* twr, float* twi, int tid) {
    for (int j = tid; j < 1024; j += 256) {
        float ang = -6.28318530717958647692f * (float)j * (1.0f / 2048.0f);
        twr[j] = cosf(ang);
        twi[j] = sinf(ang);
    }
}

// ---------------------------------------------------------------------------
// Per-batch irfft of G -> mean_value[b][t], scale 1/(2048*1024). grid = 16.
// ---------------------------------------------------------------------------
__global__ __launch_bounds__(256)
void irfft_mean(const float* __restrict__ G, float* __restrict__ mv) {
    __shared__ float zr[2048], zi[2048];
    __shared__ float twr[1024], twi[1024];
    const int tid = threadIdx.x;
    const int b = blockIdx.x;
    init_twiddle(twr, twi, tid);
    for (int f = tid; f < 2048; f += 256) {
        int g = (f <= 1024) ? f : 2048 - f;
        float gr = G[((size_t)b * 1025 + g) * 2 + 0];
        float gi = G[((size_t)b * 1025 + g) * 2 + 1];
        zr[f] = gr;
        zi[f] = (f <= 1024) ? -gi : gi;
    }
    __syncthreads();
    fft2048(zr, zi, twr, twi, tid);
    const float sc = 1.0f / (2048.0f * 1024.0f);
    for (int t = tid; t < 2048; t += 256) mv[b * 2048 + t] = zr[t] * sc;
}

// ---------------------------------------------------------------------------
// Top-7 over batch-mean + per-batch softmax (parallel argmax).
// ---------------------------------------------------------------------------
__global__ __launch_bounds__(256)
void topk_softmax(const float* __restrict__ mv, int* __restrict__ idx_out,
                  float* __restrict__ w_out) {
    __shared__ float cm[2048];
    __shared__ float wv4[4];
    __shared__ int   wi4[4];
    __shared__ int   sel[7];
    const int tid  = threadIdx.x;
    const int lane = tid & 63;
    const int wvid = tid >> 6;

    for (int t = tid; t < 2048; t += 256) {
        float s = 0.f;
        for (int b = 0; b < 16; ++b) s += mv[b * 2048 + t];
        cm[t] = s * (1.0f / 16.0f);
    }
    __syncthreads();

    for (int it = 0; it < 7; ++it) {
        float best = -3.4e38f; int bi = 1 << 30;
#pragma unroll
        for (int q = 0; q < 8; ++q) {
            const int t = tid + q * 256;
            float v = cm[t];
            if (v > best || (v == best && t < bi)) { best = v; bi = t; }
        }
#pragma unroll
        for (int off = 32; off > 0; off >>= 1) {
            float ov = __shfl_xor(best, off, 64);
            int   oi = __shfl_xor(bi,   off, 64);
            if (ov > best || (ov == best && oi < bi)) { best = ov; bi = oi; }
        }
        if (lane == 0) { wv4[wvid] = best; wi4[wvid] = bi; }
        __syncthreads();
        if (tid == 0) {
            float bb = wv4[0]; int bj = wi4[0];
#pragma unroll
            for (int u = 1; u < 4; ++u)
                if (wv4[u] > bb || (wv4[u] == bb && wi4[u] < bj)) { bb = wv4[u]; bj = wi4[u]; }
            sel[it] = bj;
            idx_out[it] = bj;
            cm[bj] = -3.4e38f;
        }
        __syncthreads();
    }

    if (tid < 16) {
        const int b = tid;
        float wv[7]; float mx = -3.4e38f;
#pragma unroll
        for (int i = 0; i < 7; ++i) { wv[i] = mv[b * 2048 + sel[i]]; mx = fmaxf(mx, wv[i]); }
        float s = 0.f;
#pragma unroll
        for (int i = 0; i < 7; ++i) { wv[i] = expf(wv[i] - mx); s += wv[i]; }
        float inv = 1.0f / s;
#pragma unroll
        for (int i = 0; i < 7; ++i) w_out[b * 7 + i] = wv[i] * inv;
    }
}

// ---------------------------------------------------------------------------
// agg[b,t,d] = bf16( sum_i w[b,i] * values[b,(t+idx[i])%2048,d] )  (fp32 in)
// ---------------------------------------------------------------------------
__global__ __launch_bounds__(256)
void agg_kernel(const float* __restrict__ vsrc, const int* __restrict__ idx,
                const float* __restrict__ w, unsigned short* __restrict__ agg) {
    const int b  = blockIdx.y;
    const int t  = blockIdx.x * 2 + (threadIdx.x >> 7);
    const int d8 = (threadIdx.x & 127) * 8;
    float av[8] = {0.f, 0.f, 0.f, 0.f, 0.f, 0.f, 0.f, 0.f};
#pragma unroll
    for (int i = 0; i < 7; ++i) {
        const int srow = (t + idx[i]) & 2047;
        const float wi = w[b * 7 + i];
        const float* src = vsrc + ((size_t)b * 2048 + srow) * 1024 + d8;
        f32x4 v0 = *(const f32x4*)src;
        f32x4 v1 = *(const f32x4*)(src + 4);
#pragma unroll
        for (int j = 0; j < 4; ++j) av[j] += wi * v0[j];
#pragma unroll
        for (int j = 0; j < 4; ++j) av[4 + j] += wi * v1[j];
    }
    bf16x8 o;
#pragma unroll
    for (int j = 0; j < 8; ++j) o[j] = (short)f2bf(av[j]);
    *(bf16x8*)&agg[((size_t)b * 2048 + t) * 1024 + d8] = o;
}

// ---------------------------------------------------------------------------
__global__ __launch_bounds__(256)
void cast_w(const float* __restrict__ src, unsigned short* __restrict__ dst) {
    const int i = (blockIdx.x * 256 + threadIdx.x) * 4;   // n = 1048576 exact
    f32x4 v = *(const f32x4*)(src + i);
    s16x4 o;
#pragma unroll
    for (int j = 0; j < 4; ++j) o[j] = (short)f2bf(v[j]);
    *(s16x4*)(dst + i) = o;
}

__global__ __launch_bounds__(256)
void zero_f32(float* __restrict__ p, int n) {
    const int i = blockIdx.x * 256 + threadIdx.x;
    if (i < n) p[i] = 0.0f;
}

// ---------------------------------------------------------------------------
extern "C" void kernel_launch(void* const* d_in, const int* in_sizes, int n_in,
                              void* d_out, int out_size, void* d_ws, size_t ws_size,
                              hipStream_t stream) {
    const float* queries = (const float*)d_in[0];
    const float* keys    = (const float*)d_in[1];
    const float* values  = (const float*)d_in[2];
    const float* Wq = (const float*)d_in[3];  const float* bq = (const float*)d_in[4];
    const float* Wk = (const float*)d_in[5];  const float* bk = (const float*)d_in[6];
    const float* Wv = (const float*)d_in[7];  const float* bv = (const float*)d_in[8];
    const float* Wo = (const float*)d_in[9];  const float* bo = (const float*)d_in[10];
    float* out = (float*)d_out;

    char* ws = (char*)d_ws;
    constexpr size_t SZP = (size_t)32768 * 1024 * 2;           // 64 MB (bf16 B*L*D)
    unsigned short* agg = (unsigned short*)(ws);               // agg output [b][t][d]
    unsigned short* kt  = (unsigned short*)(ws + SZP);         // k~^T [b][d][t]
    unsigned short* ab  = (unsigned short*)(ws + 3 * SZP);     // staging (64MB)
    // weight temps live in ab until cast_f2b(keys) overwrites (all consumed by then)
    unsigned short* wo  = ab;                                  // bf16 Wo
    unsigned short* wvT = ab + 1048576;                        // bf16 Wv^T
    unsigned short* wqT = ab + 2097152;                        // bf16 Wq^T
    unsigned short* wkT = ab + 3145728;                        // bf16 Wk^T
    unsigned short* W2  = (unsigned short*)(ws + 4 * SZP);     // bf16 Wo@Wv   [N][K]
    unsigned short* M   = W2 + 1048576;                        // bf16 Wq^T@Wk [N][K]
    char* tail = ws + 4 * SZP + 4194304;
    float* zb1024 = (float*)(tail);                            // 4KB zero bias
    float* b2     = (float*)(tail + 4096);
    float* G      = (float*)(tail + 8192);                     // 16*1025*2 f32
    float* mv     = (float*)(tail + 8192 + 131328);
    int*   idx    = (int*)  (tail + 8192 + 131328 + 131072);
    float* wsm    = (float*)(tail + 8192 + 131328 + 131072 + 64);

    // weight prep: W2 = Wo@Wv, b2 = Wo@bv + bo, M = Wq^T@Wk
    cast_w<<<1024, 256, 0, stream>>>(Wo, wo);
    cast_wT<<<dim3(16, 16), 256, 0, stream>>>(Wv, wvT);
    cast_wT<<<dim3(16, 16), 256, 0, stream>>>(Wq, wqT);
    cast_wT<<<dim3(16, 16), 256, 0, stream>>>(Wk, wkT);
    zero_f32<<<(32800 + 255) / 256, 256, 0, stream>>>(G, 32800);
    zero_f32<<<4, 256, 0, stream>>>(zb1024, 1024);
    bias2_kernel<<<256, 256, 0, stream>>>(Wo, bv, bo, b2);
    gemm256<0><<<16, 512, 0, stream>>>(wo, wvT, zb1024, W2);
    gemm256<0><<<16, 512, 0, stream>>>(wqT, wkT, zb1024, M);

    // k~ = k @ M^T (transposed out)
    cast_f2b<<<16384, 256, 0, stream>>>(keys, ab);
    gemm256<2><<<512, 512, 0, stream>>>(ab, M, zb1024, kt);

    // correlation (q read fp32-direct) -> top-k -> aggregation -> output GEMM
    fft_corr<<<2048, 256, 0, stream>>>(queries, kt, G);
    irfft_mean<<<16, 256, 0, stream>>>(G, mv);
    topk_softmax<<<1, 256, 0, stream>>>(mv, idx, wsm);
    agg_kernel<<<dim3(1024, 16), 256, 0, stream>>>(values, idx, wsm, agg);
    gemm256<1><<<512, 512, 0, stream>>>(agg, W2, b2, out);
}

// Round 10
// 536.828 us; speedup vs baseline: 1.9011x; 1.0466x over previous
//
#include <hip/hip_runtime.h>

typedef __attribute__((ext_vector_type(8))) short bf16x8;
typedef __attribute__((ext_vector_type(4))) short s16x4;
typedef __attribute__((ext_vector_type(4))) float f32x4;
typedef unsigned short ushort_t;

__device__ __forceinline__ float bf2f(unsigned short u) {
    union { unsigned int u; float f; } x; x.u = ((unsigned int)u) << 16; return x.f;
}
__device__ __forceinline__ unsigned short f2bf(float f) {
    union { float f; unsigned int u; } x; x.f = f;
    unsigned int u = x.u;
    unsigned int r = (u + 0x7fffu + ((u >> 16) & 1u)) >> 16;
    return (unsigned short)r;
}

#define GLDS16(gp, lp)                                                        \
    __builtin_amdgcn_global_load_lds(                                         \
        (const __attribute__((address_space(1))) void*)(gp),                  \
        (__attribute__((address_space(3))) void*)(lp), 16, 0, 0)

// ---------------------------------------------------------------------------
// GEMM body: C[M, N=1024] = A[M,K=1024] @ W^T + bias. A,W bf16 (W=[N,K]).
// 256x256 tile, BK=64, 8 waves, 128KB LDS dbuf, depth-2 prefetch, counted
// vmcnt(8), raw s_barrier, setprio, XOR-swizzled staging (verified conflicts=0).
// OUT_MODE: 0 = bf16 [row][col], 1 = f32 [row][col], 2 = bf16 transposed
//           [b][col][t] (row = b*2048+t).
// ---------------------------------------------------------------------------
template<int OUT_MODE>
__device__ __forceinline__
void gemm_body(const unsigned short* __restrict__ A, const unsigned short* __restrict__ Bw,
               const float* __restrict__ bias, void* __restrict__ out_,
               int bid, int nb, unsigned short* sAp, unsigned short* sBp) {
    const int tid  = threadIdx.x;
    const int lane = tid & 63;
    const int w    = tid >> 6;
    const int wr   = w >> 2, wc = w & 3;
    const int fr   = lane & 15, g4 = lane >> 4;

    const int qq  = nb >> 3;
    const int swz = qq ? (bid & 7) * qq + (bid >> 3) : bid;
    const int  col0 = (swz & 3) * 256;
    const long row0 = (long)(swz >> 2) * 256;

    const int srow = tid >> 3;
    const int sj   = (tid & 7) ^ (srow & 7);
    const unsigned short* gA = A  + (size_t)(row0 + srow) * 1024 + sj * 8;
    const unsigned short* gB = Bw + (size_t)(col0 + srow) * 1024 + sj * 8;
    const int ldst = w * 1024;

    auto stage = [&](int buf, int t) {
        const unsigned short* a = gA + t * 64;
        const unsigned short* b = gB + t * 64;
        char* dA = (char*)(sAp + buf * 16384);
        char* dB = (char*)(sBp + buf * 16384);
#pragma unroll
        for (int r = 0; r < 4; ++r)
            GLDS16(a + r * 65536, (__attribute__((address_space(3))) char*)(dA + r * 8192 + ldst));
#pragma unroll
        for (int r = 0; r < 4; ++r)
            GLDS16(b + r * 65536, (__attribute__((address_space(3))) char*)(dB + r * 8192 + ldst));
    };

    f32x4 acc[8][4];
#pragma unroll
    for (int m = 0; m < 8; ++m)
#pragma unroll
        for (int n = 0; n < 4; ++n) acc[m][n] = (f32x4){0.f, 0.f, 0.f, 0.f};

    stage(0, 0);
    stage(1, 1);

    const int mskK = (fr & 7) << 4;

    for (int t = 0; t < 16; ++t) {
        if (t < 15) asm volatile("s_waitcnt vmcnt(8)" ::: "memory");
        else        asm volatile("s_waitcnt vmcnt(0)" ::: "memory");
        asm volatile("s_barrier" ::: "memory");
        __builtin_amdgcn_sched_barrier(0);

        const char* la = (const char*)(sAp + (t & 1) * 16384);
        const char* lb = (const char*)(sBp + (t & 1) * 16384);

        bf16x8 bF[2][4];
#pragma unroll
        for (int c = 0; c < 2; ++c)
#pragma unroll
            for (int n = 0; n < 4; ++n) {
                const int row = wc * 64 + n * 16 + fr;
                bF[c][n] = *(const bf16x8*)(lb + row * 128 + ((c * 64 + g4 * 16) ^ mskK));
            }
#pragma unroll
        for (int mh = 0; mh < 2; ++mh) {
            bf16x8 aF[2][4];
#pragma unroll
            for (int c = 0; c < 2; ++c)
#pragma unroll
                for (int m = 0; m < 4; ++m) {
                    const int row = wr * 128 + mh * 64 + m * 16 + fr;
                    aF[c][m] = *(const bf16x8*)(la + row * 128 + ((c * 64 + g4 * 16) ^ mskK));
                }
            __builtin_amdgcn_s_setprio(1);
#pragma unroll
            for (int c = 0; c < 2; ++c)
#pragma unroll
                for (int n = 0; n < 4; ++n)
#pragma unroll
                    for (int m = 0; m < 4; ++m)
                        acc[mh * 4 + m][n] =
                            __builtin_amdgcn_mfma_f32_16x16x32_bf16(aF[c][m], bF[c][n], acc[mh * 4 + m][n], 0, 0, 0);
            __builtin_amdgcn_s_setprio(0);
        }

        __builtin_amdgcn_sched_barrier(0);
        asm volatile("s_barrier" ::: "memory");
        if (t + 2 < 16) stage(t & 1, t + 2);
    }

    const int cr = g4 * 4;
    const int cc = fr;
    if constexpr (OUT_MODE == 2) {
        const int b  = (int)(row0 >> 11);
        const int tb = ((int)row0 & 2047) + wr * 128 + cr;
#pragma unroll
        for (int m = 0; m < 8; ++m) {
#pragma unroll
            for (int n = 0; n < 4; ++n) {
                int col = col0 + wc * 64 + n * 16 + cc;
                float bv = bias[col];
                s16x4 o;
#pragma unroll
                for (int j = 0; j < 4; ++j) o[j] = (short)f2bf(acc[m][n][j] + bv);
                *(s16x4*)&((unsigned short*)out_)[((size_t)b * 1024 + col) * 2048 + tb + m * 16] = o;
            }
        }
    } else {
#pragma unroll
        for (int m = 0; m < 8; ++m) {
            long row = row0 + wr * 128 + m * 16 + cr;
#pragma unroll
            for (int n = 0; n < 4; ++n) {
                int col = col0 + wc * 64 + n * 16 + cc;
                float bv = bias[col];
#pragma unroll
                for (int j = 0; j < 4; ++j) {
                    float v = acc[m][n][j] + bv;
                    if constexpr (OUT_MODE == 1) ((float*)out_)[(row + j) * 1024 + col] = v;
                    else ((unsigned short*)out_)[(row + j) * 1024 + col] = f2bf(v);
                }
            }
        }
    }
}

template<int OUT_MODE>
__global__ __launch_bounds__(512, 2)
void gemm256(const unsigned short* __restrict__ A, const unsigned short* __restrict__ Bw,
             const float* __restrict__ bias, void* __restrict__ out_) {
    __shared__ __align__(16) unsigned short sA[2][16384];
    __shared__ __align__(16) unsigned short sB[2][16384];
    gemm_body<OUT_MODE>(A, Bw, bias, out_, blockIdx.x, gridDim.x, &sA[0][0], &sB[0][0]);
}

// two independent 1024x1024 GEMMs in one launch (grid = 32)
__global__ __launch_bounds__(512, 2)
void gemm_pair(const unsigned short* __restrict__ A0, const unsigned short* __restrict__ B0,
               const float* __restrict__ bias0, void* __restrict__ o0,
               const unsigned short* __restrict__ A1, const unsigned short* __restrict__ B1,
               const float* __restrict__ bias1, void* __restrict__ o1) {
    __shared__ __align__(16) unsigned short sA[2][16384];
    __shared__ __align__(16) unsigned short sB[2][16384];
    if (blockIdx.x < 16)
        gemm_body<0>(A0, B0, bias0, o0, blockIdx.x, 16, &sA[0][0], &sB[0][0]);
    else
        gemm_body<0>(A1, B1, bias1, o1, blockIdx.x - 16, 16, &sA[0][0], &sB[0][0]);
}

// ---------------------------------------------------------------------------
// fp32 -> bf16 cast, 8 elems/thread (grid 16384 x 256 for 33.5M elems).
// ---------------------------------------------------------------------------
__global__ __launch_bounds__(256)
void cast_f2b(const float* __restrict__ src, unsigned short* __restrict__ dst) {
    const size_t i = ((size_t)blockIdx.x * 256 + threadIdx.x) * 8;
    f32x4 v0 = *(const f32x4*)(src + i);
    f32x4 v1 = *(const f32x4*)(src + i + 4);
    bf16x8 o;
#pragma unroll
    for (int j = 0; j < 4; ++j) o[j] = (short)f2bf(v0[j]);
#pragma unroll
    for (int j = 0; j < 4; ++j) o[4 + j] = (short)f2bf(v1[j]);
    *(bf16x8*)(dst + i) = o;
}

// ---------------------------------------------------------------------------
// prep_all: ALL weight preprocessing in one launch. grid = 1290, block 256.
//  [0,256)    : Wv^T transpose-cast -> wvT
//  [256,512)  : Wq^T -> wqT
//  [512,768)  : Wk^T -> wkT
//  [768,1024) : Wo cast -> wo
//  [1024,1033): zero G (32800 f32)
//  1033       : zero zb1024
//  [1034,1290): b2[n] = Wo[n,:]·bv + bo[n]
// ---------------------------------------------------------------------------
__global__ __launch_bounds__(256)
void prep_all(const float* __restrict__ Wq, const float* __restrict__ Wk,
              const float* __restrict__ Wv, const float* __restrict__ Wo,
              const float* __restrict__ bv, const float* __restrict__ bo,
              unsigned short* __restrict__ wo, unsigned short* __restrict__ wvT,
              unsigned short* __restrict__ wqT, unsigned short* __restrict__ wkT,
              float* __restrict__ G, float* __restrict__ zb, float* __restrict__ b2) {
    __shared__ float tsm[64][65];
    const int bx  = blockIdx.x;
    const int tid = threadIdx.x;

    if (bx < 768) {
        const float* src = (bx < 256) ? Wv : (bx < 512) ? Wq : Wk;
        unsigned short* dst = (bx < 256) ? wvT : (bx < 512) ? wqT : wkT;
        const int t  = bx & 255;
        const int b0 = (t & 15) * 64;       // src col tile
        const int by = (t >> 4) * 64;       // src row tile
        const int tx = tid & 63, ty = tid >> 6;
        for (int r = ty; r < 64; r += 4)
            tsm[r][tx] = src[(size_t)(by + r) * 1024 + b0 + tx];
        __syncthreads();
        for (int r = ty; r < 64; r += 4)
            dst[(size_t)(b0 + r) * 1024 + by + tx] = f2bf(tsm[tx][r]);
    } else if (bx < 1024) {
        const int base = (bx - 768) * 4096 + tid * 4;
#pragma unroll
        for (int r = 0; r < 4; ++r) {
            const int i = base + r * 1024;
            f32x4 v = *(const f32x4*)(Wo + i);
            s16x4 o;
#pragma unroll
            for (int j = 0; j < 4; ++j) o[j] = (short)f2bf(v[j]);
            *(s16x4*)(wo + i) = o;
        }
    } else if (bx < 1033) {
        const int base = (bx - 1024) * 4096;
#pragma unroll
        for (int r = 0; r < 16; ++r) {
            const int i = base + r * 256 + tid;
            if (i < 32800) G[i] = 0.0f;
        }
    } else if (bx == 1033) {
        *(f32x4*)(zb + tid * 4) = (f32x4){0.f, 0.f, 0.f, 0.f};
    } else {
        const int n = (bx - 1034) * 4 + (tid >> 6);
        const int lane = tid & 63;
        float s = 0.f;
        for (int k = lane; k < 1024; k += 64) s += Wo[(size_t)n * 1024 + k] * bv[k];
#pragma unroll
        for (int off = 32; off > 0; off >>= 1) s += __shfl_xor(s, off, 64);
        if (lane == 0) b2[n] = s + bo[n];
    }
}

// ---------------------------------------------------------------------------
// 8-point DFT (negative exponent), in place on xr/xi[8].
// ---------------------------------------------------------------------------
__device__ __forceinline__ void dft8(float* xr, float* xi) {
    const float c8 = 0.70710678118654752440f;
    float es0r = xr[0] + xr[4], es0i = xi[0] + xi[4];
    float es1r = xr[0] - xr[4], es1i = xi[0] - xi[4];
    float es2r = xr[2] + xr[6], es2i = xi[2] + xi[6];
    float es3r = xr[2] - xr[6], es3i = xi[2] - xi[6];
    float E0r = es0r + es2r, E0i = es0i + es2i;
    float E2r = es0r - es2r, E2i = es0i - es2i;
    float E1r = es1r + es3i, E1i = es1i - es3r;
    float E3r = es1r - es3i, E3i = es1i + es3r;
    float os0r = xr[1] + xr[5], os0i = xi[1] + xi[5];
    float os1r = xr[1] - xr[5], os1i = xi[1] - xi[5];
    float os2r = xr[3] + xr[7], os2i = xi[3] + xi[7];
    float os3r = xr[3] - xr[7], os3i = xi[3] - xi[7];
    float O0r = os0r + os2r, O0i = os0i + os2i;
    float O2r = os0r - os2r, O2i = os0i - os2i;
    float O1r = os1r + os3i, O1i = os1i - os3r;
    float O3r = os1r - os3i, O3i = os1i + os3r;
    float p1 = c8 * (O1r + O1i), q1 = c8 * (O1i - O1r);
    float p3 = c8 * (O3r + O3i), q3 = c8 * (O3i - O3r);
    xr[0] = E0r + O0r; xi[0] = E0i + O0i;
    xr[4] = E0r - O0r; xi[4] = E0i - O0i;
    xr[1] = E1r + p1;  xi[1] = E1i + q1;
    xr[5] = E1r - p1;  xi[5] = E1i - q1;
    xr[2] = E2r + O2i; xi[2] = E2i - O2r;
    xr[6] = E2r - O2i; xi[6] = E2i + O2r;
    xr[3] = E3r + q3;  xi[3] = E3i - p3;
    xr[7] = E3r - q3;  xi[7] = E3i + p3;
}

// XOR swizzle on element index (involution), round-9 verified.
__device__ __forceinline__ int ps(int p) { return p ^ (((p >> 5) & 7) << 2); }

#define TWIDDLE2(wr_, wi_)                                                    \
    {                                                                         \
        float cr_ = (wr_), ci_ = (wi_);                                       \
        _Pragma("unroll")                                                     \
        for (int k = 1; k < 8; ++k) {                                         \
            float t0 = ar[k] * cr_ - ai[k] * ci_;                             \
            float t1 = ar[k] * ci_ + ai[k] * cr_;                             \
            ar[k] = t0; ai[k] = t1;                                           \
            float t2 = br[k] * cr_ - bi[k] * ci_;                             \
            float t3 = br[k] * ci_ + bi[k] * cr_;                             \
            br[k] = t2; bi[k] = t3;                                           \
            if (k < 7) {                                                      \
                float nr = cr_ * (wr_) - ci_ * (wi_);                         \
                float ni = cr_ * (wi_) + ci_ * (wr_);                         \
                cr_ = nr; ci_ = ni;                                           \
            }                                                                 \
        }                                                                     \
    }

// ---------------------------------------------------------------------------
// fft_corr v6: q preloaded into registers up-front as 2 x f32x4 per t-position
// (32B/row loads, 4x wider than v4's 8B; sibling chunk on same XCD consumes
// the other half-line). Iterations consume register q via compile-time-safe
// selects. k~ read coalesced bf16. LDS structure identical to round 9.
// grid = 2048 (swizzled 16 b x 128 chunks), block = 256.
// ---------------------------------------------------------------------------
__global__ __launch_bounds__(256)
void fft_corr(const float* __restrict__ qf, const unsigned short* __restrict__ kt,
              float* __restrict__ G) {
    __shared__ float2 za[2048];
    __shared__ float2 zb[2048];
    const int tid = threadIdx.x;
    const int bid = blockIdx.x;
    const int swzb = (bid & 7) * 256 + (bid >> 3);   // sibling chunks -> same XCD
    const int b = swzb >> 7;
    const int chunk = swzb & 127;

    const float N2PI = -6.28318530717958647692f;
    float w1r, w1i, w2r, w2i, w3r, w3i;
    {
        float s, c;
        __sincosf(N2PI * (float)tid * (1.0f / 2048.0f), &s, &c); w1r = c; w1i = s;
        __sincosf(N2PI * (float)(tid & 31) * (1.0f / 256.0f), &s, &c); w2r = c; w2i = s;
        __sincosf(N2PI * (float)(tid & 3) * (1.0f / 32.0f),  &s, &c); w3r = c; w3i = s;
    }

    // ---- q preload: 8 t-positions x 8 columns (2 x f32x4 each) ----
    f32x4 qreg0[8], qreg1[8];
    {
        const float* qb0 = qf + (size_t)b * 2048 * 1024 + chunk * 8;
#pragma unroll
        for (int k = 0; k < 8; ++k) {
            const float* p = qb0 + (size_t)(tid + 256 * k) * 1024;
            qreg0[k] = *(const f32x4*)p;
            qreg1[k] = *(const f32x4*)(p + 4);
        }
    }

    float aR0 = 0.f, aI0 = 0.f, aR1 = 0.f, aI1 = 0.f;
    float aR2 = 0.f, aI2 = 0.f, aR3 = 0.f, aI3 = 0.f, aR4 = 0.f;

    const int beta = tid >> 5, s2 = tid & 31;
    const int gam  = tid >> 2, u3 = tid & 3;

    for (int it = 0; it < 4; ++it) {
        const int d0 = chunk * 8 + it * 2;
        const unsigned short* k0 = kt + ((size_t)b * 1024 + d0) * 2048;
        const unsigned short* k1 = k0 + 2048;

        float ar[8], ai[8], br[8], bi[8];
        // R1: q from registers (static component indices, runtime select of halves)
#pragma unroll
        for (int k = 0; k < 8; ++k) {
            const int t = tid + 256 * k;
            f32x4 v = (it & 2) ? qreg1[k] : qreg0[k];
            float qa = (it & 1) ? v[2] : v[0];
            float qb = (it & 1) ? v[3] : v[1];
            ar[k] = qa; br[k] = qb;
            ai[k] = bf2f(k0[t]); bi[k] = bf2f(k1[t]);
        }
        dft8(ar, ai); dft8(br, bi);
        TWIDDLE2(w1r, w1i)
#pragma unroll
        for (int k = 0; k < 8; ++k) {
            const int p = ps(256 * k + tid);
            za[p] = make_float2(ar[k], ai[k]);
            zb[p] = make_float2(br[k], bi[k]);
        }
        __syncthreads();

        // R2
#pragma unroll
        for (int k = 0; k < 8; ++k) {
            const int p = ps(256 * beta + 32 * k + s2);
            float2 va = za[p]; ar[k] = va.x; ai[k] = va.y;
            float2 vb = zb[p]; br[k] = vb.x; bi[k] = vb.y;
        }
        dft8(ar, ai); dft8(br, bi);
        TWIDDLE2(w2r, w2i)
#pragma unroll
        for (int k = 0; k < 8; ++k) {
            const int p = ps(256 * beta + 32 * k + s2);
            za[p] = make_float2(ar[k], ai[k]);
            zb[p] = make_float2(br[k], bi[k]);
        }
        __syncthreads();

        // R3
#pragma unroll
        for (int k = 0; k < 8; ++k) {
            const int p = ps(32 * gam + 4 * k + u3);
            float2 va = za[p]; ar[k] = va.x; ai[k] = va.y;
            float2 vb = zb[p]; br[k] = vb.x; bi[k] = vb.y;
        }
        dft8(ar, ai); dft8(br, bi);
        TWIDDLE2(w3r, w3i)
#pragma unroll
        for (int k = 0; k < 8; ++k) {
            const int p = ps(32 * gam + 4 * k + u3);
            za[p] = make_float2(ar[k], ai[k]);
            zb[p] = make_float2(br[k], bi[k]);
        }
        __syncthreads();

        // R4
#pragma unroll
        for (int k = 0; k < 8; ++k) {
            const int p = ps(8 * tid + k);
            float2 va = za[p]; ar[k] = va.x; ai[k] = va.y;
            float2 vb = zb[p]; br[k] = vb.x; bi[k] = vb.y;
        }
        __syncthreads();

#pragma unroll
        for (int blk = 0; blk < 2; ++blk) {
            const int o = 4 * blk;
            {
                float s0r = ar[o] + ar[o + 2], s0i = ai[o] + ai[o + 2];
                float s1r = ar[o] - ar[o + 2], s1i = ai[o] - ai[o + 2];
                float s2r = ar[o + 1] + ar[o + 3], s2i = ai[o + 1] + ai[o + 3];
                float s3r = ar[o + 1] - ar[o + 3], s3i = ai[o + 1] - ai[o + 3];
                ar[o + 0] = s0r + s2r; ai[o + 0] = s0i + s2i;
                ar[o + 2] = s0r - s2r; ai[o + 2] = s0i - s2i;
                ar[o + 1] = s1r + s3i; ai[o + 1] = s1i - s3r;
                ar[o + 3] = s1r - s3i; ai[o + 3] = s1i + s3r;
            }
            {
                float s0r = br[o] + br[o + 2], s0i = bi[o] + bi[o + 2];
                float s1r = br[o] - br[o + 2], s1i = bi[o] - bi[o + 2];
                float s2r = br[o + 1] + br[o + 3], s2i = bi[o + 1] + bi[o + 3];
                float s3r = br[o + 1] - br[o + 3], s3i = bi[o + 1] - bi[o + 3];
                br[o + 0] = s0r + s2r; bi[o + 0] = s0i + s2i;
                br[o + 2] = s0r - s2r; bi[o + 2] = s0i - s2i;
                br[o + 1] = s1r + s3i; bi[o + 1] = s1i - s3r;
                br[o + 3] = s1r - s3i; bi[o + 3] = s1i + s3r;
            }
        }
        {
            const int k1d = tid >> 5;
            const int k2d = (tid >> 2) & 7;
            const int fb = k1d + 8 * k2d;
#pragma unroll
            for (int blk = 0; blk < 2; ++blk) {
                const int k3d = (2 * (tid & 3) + blk) & 7;
#pragma unroll
                for (int k4 = 0; k4 < 4; ++k4) {
                    const int f = fb + 64 * k3d + 512 * k4;
                    const int pf = ps(f);
                    za[pf] = make_float2(ar[4 * blk + k4], ai[4 * blk + k4]);
                    zb[pf] = make_float2(br[4 * blk + k4], bi[4 * blk + k4]);
                }
            }
        }
        __syncthreads();

        // Hermitian split + accumulate (registers)
#pragma unroll
        for (int k = 0; k < 4; ++k) {
            const int f = tid + 256 * k;
            const int f2 = (2048 - f) & 2047;
            const int pf = ps(f), pf2 = ps(f2);
            float2 Za = za[pf], Ya = za[pf2];
            float Qr = 0.5f * (Za.x + Ya.x), Qi = 0.5f * (Za.y - Ya.y);
            float Kr = 0.5f * (Za.y + Ya.y), Ki = -0.5f * (Za.x - Ya.x);
            float dR = Qr * Kr + Qi * Ki;
            float dI = Qi * Kr - Qr * Ki;
            float2 Zb = zb[pf], Yb = zb[pf2];
            Qr = 0.5f * (Zb.x + Yb.x); Qi = 0.5f * (Zb.y - Yb.y);
            Kr = 0.5f * (Zb.y + Yb.y); Ki = -0.5f * (Zb.x - Yb.x);
            dR += Qr * Kr + Qi * Ki;
            dI += Qi * Kr - Qr * Ki;
            if      (k == 0) { aR0 += dR; aI0 += dI; }
            else if (k == 1) { aR1 += dR; aI1 += dI; }
            else if (k == 2) { aR2 += dR; aI2 += dI; }
            else             { aR3 += dR; aI3 += dI; }
        }
        if (tid == 0) {
            const int pf = ps(1024);
            aR4 += za[pf].x * za[pf].y + zb[pf].x * zb[pf].y;
        }
        __syncthreads();
    }

    atomicAdd(&G[((size_t)b * 1025 + tid +   0) * 2 + 0], aR0);
    atomicAdd(&G[((size_t)b * 1025 + tid +   0) * 2 + 1], aI0);
    atomicAdd(&G[((size_t)b * 1025 + tid + 256) * 2 + 0], aR1);
    atomicAdd(&G[((size_t)b * 1025 + tid + 256) * 2 + 1], aI1);
    atomicAdd(&G[((size_t)b * 1025 + tid + 512) * 2 + 0], aR2);
    atomicAdd(&G[((size_t)b * 1025 + tid + 512) * 2 + 1], aI2);
    atomicAdd(&G[((size_t)b * 1025 + tid + 768) * 2 + 0], aR3);
    atomicAdd(&G[((size_t)b * 1025 + tid + 768) * 2 + 1], aI3);
    if (tid == 0)
        atomicAdd(&G[((size_t)b * 1025 + 1024) * 2 + 0], aR4);
}

// ---------------------------------------------------------------------------
// In-LDS radix-2 DIT FFT, N=2048 (only used by irfft_mean: 16 blocks, cheap).
// ---------------------------------------------------------------------------
__device__ __forceinline__ void fft2048(float* zr, float* zi,
                                        const float* twr, const float* twi, int tid) {
    for (int t = tid; t < 2048; t += 256) {
        int j = __brev((unsigned)t) >> 21;
        if (j > t) {
            float a = zr[t]; zr[t] = zr[j]; zr[j] = a;
            float c = zi[t]; zi[t] = zi[j]; zi[j] = c;
        }
    }
    __syncthreads();
    for (int s = 0; s < 11; ++s) {
        const int m = 1 << s;
        for (int i = tid; i < 1024; i += 256) {
            const int pos = i & (m - 1);
            const int i1  = ((i >> s) << (s + 1)) + pos;
            const int i2  = i1 + m;
            const int tw  = pos << (10 - s);
            float wr = twr[tw], wi = twi[tw];
            float xr = zr[i2], xi = zi[i2];
            float tr = wr * xr - wi * xi;
            float ti = wr * xi + wi * xr;
            float ur = zr[i1], ui = zi[i1];
            zr[i2] = ur - tr; zi[i2] = ui - ti;
            zr[i1] = ur + tr; zi[i1] = ui + ti;
        }
        __syncthreads();
    }
}

__device__ __forceinline__ void init_twiddle(float* twr, float* twi, int tid) {
    for (int j = tid; j < 1024; j += 256) {
        float ang = -6.28318530717958647692f * (float)j * (1.0f / 2048.0f);
        twr[j] = cosf(ang);
        twi[j] = sinf(ang);
    }
}

// ---------------------------------------------------------------------------
// Per-batch irfft of G -> mean_value[b][t], scale 1/(2048*1024). grid = 16.
// ---------------------------------------------------------------------------
__global__ __launch_bounds__(256)
void irfft_mean(const float* __restrict__ G, float* __restrict__ mv) {
    __shared__ float zr[2048], zi[2048];
    __shared__ float twr[1024], twi[1024];
    const int tid = threadIdx.x;
    const int b = blockIdx.x;
    init_twiddle(twr, twi, tid);
    for (int f = tid; f < 2048; f += 256) {
        int g = (f <= 1024) ? f : 2048 - f;
        float gr = G[((size_t)b * 1025 + g) * 2 + 0];
        float gi = G[((size_t)b * 1025 + g) * 2 + 1];
        zr[f] = gr;
        zi[f] = (f <= 1024) ? -gi : gi;
    }
    __syncthreads();
    fft2048(zr, zi, twr, twi, tid);
    const float sc = 1.0f / (2048.0f * 1024.0f);
    for (int t = tid; t < 2048; t += 256) mv[b * 2048 + t] = zr[t] * sc;
}

// ---------------------------------------------------------------------------
// Top-7 over batch-mean + per-batch softmax (parallel argmax).
// ---------------------------------------------------------------------------
__global__ __launch_bounds__(256)
void topk_softmax(const float* __restrict__ mv, int* __restrict__ idx_out,
                  float* __restrict__ w_out) {
    __shared__ float cm[2048];
    __shared__ float wv4[4];
    __shared__ int   wi4[4];
    __shared__ int   sel[7];
    const int tid  = threadIdx.x;
    const int lane = tid & 63;
    const int wvid = tid >> 6;

    for (int t = tid; t < 2048; t += 256) {
        float s = 0.f;
        for (int b = 0; b < 16; ++b) s += mv[b * 2048 + t];
        cm[t] = s * (1.0f / 16.0f);
    }
    __syncthreads();

    for (int it = 0; it < 7; ++it) {
        float best = -3.4e38f; int bi = 1 << 30;
#pragma unroll
        for (int q = 0; q < 8; ++q) {
            const int t = tid + q * 256;
            float v = cm[t];
            if (v > best || (v == best && t < bi)) { best = v; bi = t; }
        }
#pragma unroll
        for (int off = 32; off > 0; off >>= 1) {
            float ov = __shfl_xor(best, off, 64);
            int   oi = __shfl_xor(bi,   off, 64);
            if (ov > best || (ov == best && oi < bi)) { best = ov; bi = oi; }
        }
        if (lane == 0) { wv4[wvid] = best; wi4[wvid] = bi; }
        __syncthreads();
        if (tid == 0) {
            float bb = wv4[0]; int bj = wi4[0];
#pragma unroll
            for (int u = 1; u < 4; ++u)
                if (wv4[u] > bb || (wv4[u] == bb && wi4[u] < bj)) { bb = wv4[u]; bj = wi4[u]; }
            sel[it] = bj;
            idx_out[it] = bj;
            cm[bj] = -3.4e38f;
        }
        __syncthreads();
    }

    if (tid < 16) {
        const int b = tid;
        float wv[7]; float mx = -3.4e38f;
#pragma unroll
        for (int i = 0; i < 7; ++i) { wv[i] = mv[b * 2048 + sel[i]]; mx = fmaxf(mx, wv[i]); }
        float s = 0.f;
#pragma unroll
        for (int i = 0; i < 7; ++i) { wv[i] = expf(wv[i] - mx); s += wv[i]; }
        float inv = 1.0f / s;
#pragma unroll
        for (int i = 0; i < 7; ++i) w_out[b * 7 + i] = wv[i] * inv;
    }
}

// ---------------------------------------------------------------------------
// agg[b,t,d] = bf16( sum_i w[b,i] * values[b,(t+idx[i])%2048,d] )  (fp32 in)
// ---------------------------------------------------------------------------
__global__ __launch_bounds__(256)
void agg_kernel(const float* __restrict__ vsrc, const int* __restrict__ idx,
                const float* __restrict__ w, unsigned short* __restrict__ agg) {
    const int b  = blockIdx.y;
    const int t  = blockIdx.x * 2 + (threadIdx.x >> 7);
    const int d8 = (threadIdx.x & 127) * 8;
    float av[8] = {0.f, 0.f, 0.f, 0.f, 0.f, 0.f, 0.f, 0.f};
#pragma unroll
    for (int i = 0; i < 7; ++i) {
        const int srow = (t + idx[i]) & 2047;
        const float wi = w[b * 7 + i];
        const float* src = vsrc + ((size_t)b * 2048 + srow) * 1024 + d8;
        f32x4 v0 = *(const f32x4*)src;
        f32x4 v1 = *(const f32x4*)(src + 4);
#pragma unroll
        for (int j = 0; j < 4; ++j) av[j] += wi * v0[j];
#pragma unroll
        for (int j = 0; j < 4; ++j) av[4 + j] += wi * v1[j];
    }
    bf16x8 o;
#pragma unroll
    for (int j = 0; j < 8; ++j) o[j] = (short)f2bf(av[j]);
    *(bf16x8*)&agg[((size_t)b * 2048 + t) * 1024 + d8] = o;
}

// ---------------------------------------------------------------------------
extern "C" void kernel_launch(void* const* d_in, const int* in_sizes, int n_in,
                              void* d_out, int out_size, void* d_ws, size_t ws_size,
                              hipStream_t stream) {
    const float* queries = (const float*)d_in[0];
    const float* keys    = (const float*)d_in[1];
    const float* values  = (const float*)d_in[2];
    const float* Wq = (const float*)d_in[3];
    const float* Wk = (const float*)d_in[5];
    const float* Wv = (const float*)d_in[7];  const float* bv = (const float*)d_in[8];
    const float* Wo = (const float*)d_in[9];  const float* bo = (const float*)d_in[10];
    float* out = (float*)d_out;

    char* ws = (char*)d_ws;
    constexpr size_t SZP = (size_t)32768 * 1024 * 2;           // 64 MB (bf16 B*L*D)
    unsigned short* agg = (unsigned short*)(ws);               // agg output [b][t][d]
    unsigned short* kt  = (unsigned short*)(ws + SZP);         // k~^T [b][d][t]
    unsigned short* ab  = (unsigned short*)(ws + 3 * SZP);     // staging (64MB)
    unsigned short* wo  = ab;                                  // bf16 Wo
    unsigned short* wvT = ab + 1048576;                        // bf16 Wv^T
    unsigned short* wqT = ab + 2097152;                        // bf16 Wq^T
    unsigned short* wkT = ab + 3145728;                        // bf16 Wk^T
    unsigned short* W2  = (unsigned short*)(ws + 4 * SZP);     // bf16 Wo@Wv   [N][K]
    unsigned short* M   = W2 + 1048576;                        // bf16 Wq^T@Wk [N][K]
    char* tail = ws + 4 * SZP + 4194304;
    float* zb1024 = (float*)(tail);                            // 4KB zero bias
    float* b2     = (float*)(tail + 4096);
    float* G      = (float*)(tail + 8192);                     // 16*1025*2 f32
    float* mv     = (float*)(tail + 8192 + 131328);
    int*   idx    = (int*)  (tail + 8192 + 131328 + 131072);
    float* wsm    = (float*)(tail + 8192 + 131328 + 131072 + 64);

    // 1) all weight prep in one launch
    prep_all<<<1290, 256, 0, stream>>>(Wq, Wk, Wv, Wo, bv, bo,
                                       wo, wvT, wqT, wkT, G, zb1024, b2);
    // 2) W2 = Wo@Wv and M = Wq^T@Wk in one launch
    gemm_pair<<<32, 512, 0, stream>>>(wo, wvT, zb1024, W2,
                                      wqT, wkT, zb1024, M);
    // 3) k~ = k @ M^T (transposed out)
    cast_f2b<<<16384, 256, 0, stream>>>(keys, ab);
    gemm256<2><<<512, 512, 0, stream>>>(ab, M, zb1024, kt);

    // 4) correlation -> top-k -> aggregation -> fused output GEMM
    fft_corr<<<2048, 256, 0, stream>>>(queries, kt, G);
    irfft_mean<<<16, 256, 0, stream>>>(G, mv);
    topk_softmax<<<1, 256, 0, stream>>>(mv, idx, wsm);
    agg_kernel<<<dim3(1024, 16), 256, 0, stream>>>(values, idx, wsm, agg);
    gemm256<1><<<512, 512, 0, stream>>>(agg, W2, b2, out);
}

// Round 11
// 509.440 us; speedup vs baseline: 2.0033x; 1.0538x over previous
//
#include <hip/hip_runtime.h>

typedef __attribute__((ext_vector_type(8))) short bf16x8;
typedef __attribute__((ext_vector_type(4))) short s16x4;
typedef __attribute__((ext_vector_type(4))) float f32x4;

__device__ __forceinline__ float bf2f(unsigned short u) {
    union { unsigned int u; float f; } x; x.u = ((unsigned int)u) << 16; return x.f;
}
__device__ __forceinline__ unsigned short f2bf(float f) {
    union { float f; unsigned int u; } x; x.f = f;
    unsigned int u = x.u;
    unsigned int r = (u + 0x7fffu + ((u >> 16) & 1u)) >> 16;
    return (unsigned short)r;
}

#define GLDS16(gp, lp)                                                        \
    __builtin_amdgcn_global_load_lds(                                         \
        (const __attribute__((address_space(1))) void*)(gp),                  \
        (__attribute__((address_space(3))) void*)(lp), 16, 0, 0)

// ---------------------------------------------------------------------------
// GEMM body: C[M, N=1024] = A[M,K=1024] @ W^T + bias. A,W bf16 (W=[N,K]).
// 256x256 tile, BK=64, 8 waves, 128KB LDS dbuf, depth-2 prefetch, counted
// vmcnt(8), raw s_barrier, setprio, XOR-swizzled staging (verified conflicts=0).
// OUT_MODE: 0 = bf16 [row][col], 1 = f32 [row][col], 2 = bf16 transposed
//           [b][col][t] (row = b*2048+t).
// ---------------------------------------------------------------------------
template<int OUT_MODE>
__device__ __forceinline__
void gemm_body(const unsigned short* __restrict__ A, const unsigned short* __restrict__ Bw,
               const float* __restrict__ bias, void* __restrict__ out_,
               int bid, int nb, unsigned short* sAp, unsigned short* sBp) {
    const int tid  = threadIdx.x;
    const int lane = tid & 63;
    const int w    = tid >> 6;
    const int wr   = w >> 2, wc = w & 3;
    const int fr   = lane & 15, g4 = lane >> 4;

    const int qq  = nb >> 3;
    const int swz = qq ? (bid & 7) * qq + (bid >> 3) : bid;
    const int  col0 = (swz & 3) * 256;
    const long row0 = (long)(swz >> 2) * 256;

    const int srow = tid >> 3;
    const int sj   = (tid & 7) ^ (srow & 7);
    const unsigned short* gA = A  + (size_t)(row0 + srow) * 1024 + sj * 8;
    const unsigned short* gB = Bw + (size_t)(col0 + srow) * 1024 + sj * 8;
    const int ldst = w * 1024;

    auto stage = [&](int buf, int t) {
        const unsigned short* a = gA + t * 64;
        const unsigned short* b = gB + t * 64;
        char* dA = (char*)(sAp + buf * 16384);
        char* dB = (char*)(sBp + buf * 16384);
#pragma unroll
        for (int r = 0; r < 4; ++r)
            GLDS16(a + r * 65536, (__attribute__((address_space(3))) char*)(dA + r * 8192 + ldst));
#pragma unroll
        for (int r = 0; r < 4; ++r)
            GLDS16(b + r * 65536, (__attribute__((address_space(3))) char*)(dB + r * 8192 + ldst));
    };

    f32x4 acc[8][4];
#pragma unroll
    for (int m = 0; m < 8; ++m)
#pragma unroll
        for (int n = 0; n < 4; ++n) acc[m][n] = (f32x4){0.f, 0.f, 0.f, 0.f};

    stage(0, 0);
    stage(1, 1);

    const int mskK = (fr & 7) << 4;

    for (int t = 0; t < 16; ++t) {
        if (t < 15) asm volatile("s_waitcnt vmcnt(8)" ::: "memory");
        else        asm volatile("s_waitcnt vmcnt(0)" ::: "memory");
        asm volatile("s_barrier" ::: "memory");
        __builtin_amdgcn_sched_barrier(0);

        const char* la = (const char*)(sAp + (t & 1) * 16384);
        const char* lb = (const char*)(sBp + (t & 1) * 16384);

        bf16x8 bF[2][4];
#pragma unroll
        for (int c = 0; c < 2; ++c)
#pragma unroll
            for (int n = 0; n < 4; ++n) {
                const int row = wc * 64 + n * 16 + fr;
                bF[c][n] = *(const bf16x8*)(lb + row * 128 + ((c * 64 + g4 * 16) ^ mskK));
            }
#pragma unroll
        for (int mh = 0; mh < 2; ++mh) {
            bf16x8 aF[2][4];
#pragma unroll
            for (int c = 0; c < 2; ++c)
#pragma unroll
                for (int m = 0; m < 4; ++m) {
                    const int row = wr * 128 + mh * 64 + m * 16 + fr;
                    aF[c][m] = *(const bf16x8*)(la + row * 128 + ((c * 64 + g4 * 16) ^ mskK));
                }
            __builtin_amdgcn_s_setprio(1);
#pragma unroll
            for (int c = 0; c < 2; ++c)
#pragma unroll
                for (int n = 0; n < 4; ++n)
#pragma unroll
                    for (int m = 0; m < 4; ++m)
                        acc[mh * 4 + m][n] =
                            __builtin_amdgcn_mfma_f32_16x16x32_bf16(aF[c][m], bF[c][n], acc[mh * 4 + m][n], 0, 0, 0);
            __builtin_amdgcn_s_setprio(0);
        }

        __builtin_amdgcn_sched_barrier(0);
        asm volatile("s_barrier" ::: "memory");
        if (t + 2 < 16) stage(t & 1, t + 2);
    }

    const int cr = g4 * 4;
    const int cc = fr;
    if constexpr (OUT_MODE == 2) {
        const int b  = (int)(row0 >> 11);
        const int tb = ((int)row0 & 2047) + wr * 128 + cr;
#pragma unroll
        for (int m = 0; m < 8; ++m) {
#pragma unroll
            for (int n = 0; n < 4; ++n) {
                int col = col0 + wc * 64 + n * 16 + cc;
                float bv = bias[col];
                s16x4 o;
#pragma unroll
                for (int j = 0; j < 4; ++j) o[j] = (short)f2bf(acc[m][n][j] + bv);
                *(s16x4*)&((unsigned short*)out_)[((size_t)b * 1024 + col) * 2048 + tb + m * 16] = o;
            }
        }
    } else {
#pragma unroll
        for (int m = 0; m < 8; ++m) {
            long row = row0 + wr * 128 + m * 16 + cr;
#pragma unroll
            for (int n = 0; n < 4; ++n) {
                int col = col0 + wc * 64 + n * 16 + cc;
                float bv = bias[col];
#pragma unroll
                for (int j = 0; j < 4; ++j) {
                    float v = acc[m][n][j] + bv;
                    if constexpr (OUT_MODE == 1) ((float*)out_)[(row + j) * 1024 + col] = v;
                    else ((unsigned short*)out_)[(row + j) * 1024 + col] = f2bf(v);
                }
            }
        }
    }
}

template<int OUT_MODE>
__global__ __launch_bounds__(512, 2)
void gemm256(const unsigned short* __restrict__ A, const unsigned short* __restrict__ Bw,
             const float* __restrict__ bias, void* __restrict__ out_) {
    __shared__ __align__(16) unsigned short sA[2][16384];
    __shared__ __align__(16) unsigned short sB[2][16384];
    gemm_body<OUT_MODE>(A, Bw, bias, out_, blockIdx.x, gridDim.x, &sA[0][0], &sB[0][0]);
}

// two independent 1024x1024 GEMMs in one launch (grid = 32)
__global__ __launch_bounds__(512, 2)
void gemm_pair(const unsigned short* __restrict__ A0, const unsigned short* __restrict__ B0,
               const float* __restrict__ bias0, void* __restrict__ o0,
               const unsigned short* __restrict__ A1, const unsigned short* __restrict__ B1,
               const float* __restrict__ bias1, void* __restrict__ o1) {
    __shared__ __align__(16) unsigned short sA[2][16384];
    __shared__ __align__(16) unsigned short sB[2][16384];
    if (blockIdx.x < 16)
        gemm_body<0>(A0, B0, bias0, o0, blockIdx.x, 16, &sA[0][0], &sB[0][0]);
    else
        gemm_body<0>(A1, B1, bias1, o1, blockIdx.x - 16, 16, &sA[0][0], &sB[0][0]);
}

// ---------------------------------------------------------------------------
// prep_inputs: one launch producing both fft/gemm inputs.
//  blocks [0, 8192)      : qt[b][d][t] = bf16(queries[b][t][d])  (transpose-cast)
//  blocks [8192, 24576)  : ab = bf16(keys)                        (straight cast)
// block = 256.
// ---------------------------------------------------------------------------
__global__ __launch_bounds__(256)
void prep_inputs(const float* __restrict__ queries, const float* __restrict__ keys,
                 unsigned short* __restrict__ qt, unsigned short* __restrict__ ab) {
    __shared__ float tsm[64][65];
    const int bx  = blockIdx.x;
    const int tid = threadIdx.x;
    if (bx < 8192) {
        const int b   = bx >> 9;
        const int rem = bx & 511;
        const int t0  = (rem & 31) * 64;
        const int d0  = (rem >> 5) * 64;
        const int tx = tid & 63, ty = tid >> 6;
        const float* s = queries + ((size_t)b * 2048 + t0) * 1024 + d0;
        for (int r = ty; r < 64; r += 4)
            tsm[r][tx] = s[(size_t)r * 1024 + tx];
        __syncthreads();
        unsigned short* d = qt + ((size_t)b * 1024 + d0) * 2048 + t0;
        for (int r = ty; r < 64; r += 4)
            d[(size_t)r * 2048 + tx] = f2bf(tsm[tx][r]);
    } else {
        const size_t i = ((size_t)(bx - 8192) * 256 + tid) * 8;
        f32x4 v0 = *(const f32x4*)(keys + i);
        f32x4 v1 = *(const f32x4*)(keys + i + 4);
        bf16x8 o;
#pragma unroll
        for (int j = 0; j < 4; ++j) o[j] = (short)f2bf(v0[j]);
#pragma unroll
        for (int j = 0; j < 4; ++j) o[4 + j] = (short)f2bf(v1[j]);
        *(bf16x8*)(ab + i) = o;
    }
}

// ---------------------------------------------------------------------------
// prep_all: ALL weight preprocessing in one launch. grid = 1290, block 256.
// ---------------------------------------------------------------------------
__global__ __launch_bounds__(256)
void prep_all(const float* __restrict__ Wq, const float* __restrict__ Wk,
              const float* __restrict__ Wv, const float* __restrict__ Wo,
              const float* __restrict__ bv, const float* __restrict__ bo,
              unsigned short* __restrict__ wo, unsigned short* __restrict__ wvT,
              unsigned short* __restrict__ wqT, unsigned short* __restrict__ wkT,
              float* __restrict__ G, float* __restrict__ zb, float* __restrict__ b2) {
    __shared__ float tsm[64][65];
    const int bx  = blockIdx.x;
    const int tid = threadIdx.x;

    if (bx < 768) {
        const float* src = (bx < 256) ? Wv : (bx < 512) ? Wq : Wk;
        unsigned short* dst = (bx < 256) ? wvT : (bx < 512) ? wqT : wkT;
        const int t  = bx & 255;
        const int b0 = (t & 15) * 64;
        const int by = (t >> 4) * 64;
        const int tx = tid & 63, ty = tid >> 6;
        for (int r = ty; r < 64; r += 4)
            tsm[r][tx] = src[(size_t)(by + r) * 1024 + b0 + tx];
        __syncthreads();
        for (int r = ty; r < 64; r += 4)
            dst[(size_t)(b0 + r) * 1024 + by + tx] = f2bf(tsm[tx][r]);
    } else if (bx < 1024) {
        const int base = (bx - 768) * 4096 + tid * 4;
#pragma unroll
        for (int r = 0; r < 4; ++r) {
            const int i = base + r * 1024;
            f32x4 v = *(const f32x4*)(Wo + i);
            s16x4 o;
#pragma unroll
            for (int j = 0; j < 4; ++j) o[j] = (short)f2bf(v[j]);
            *(s16x4*)(wo + i) = o;
        }
    } else if (bx < 1033) {
        const int base = (bx - 1024) * 4096;
#pragma unroll
        for (int r = 0; r < 16; ++r) {
            const int i = base + r * 256 + tid;
            if (i < 32800) G[i] = 0.0f;
        }
    } else if (bx == 1033) {
        *(f32x4*)(zb + tid * 4) = (f32x4){0.f, 0.f, 0.f, 0.f};
    } else {
        const int n = (bx - 1034) * 4 + (tid >> 6);
        const int lane = tid & 63;
        float s = 0.f;
        for (int k = lane; k < 1024; k += 64) s += Wo[(size_t)n * 1024 + k] * bv[k];
#pragma unroll
        for (int off = 32; off > 0; off >>= 1) s += __shfl_xor(s, off, 64);
        if (lane == 0) b2[n] = s + bo[n];
    }
}

// ---------------------------------------------------------------------------
// 8-point DFT (negative exponent), in place on xr/xi[8].
// ---------------------------------------------------------------------------
__device__ __forceinline__ void dft8(float* xr, float* xi) {
    const float c8 = 0.70710678118654752440f;
    float es0r = xr[0] + xr[4], es0i = xi[0] + xi[4];
    float es1r = xr[0] - xr[4], es1i = xi[0] - xi[4];
    float es2r = xr[2] + xr[6], es2i = xi[2] + xi[6];
    float es3r = xr[2] - xr[6], es3i = xi[2] - xi[6];
    float E0r = es0r + es2r, E0i = es0i + es2i;
    float E2r = es0r - es2r, E2i = es0i - es2i;
    float E1r = es1r + es3i, E1i = es1i - es3r;
    float E3r = es1r - es3i, E3i = es1i + es3r;
    float os0r = xr[1] + xr[5], os0i = xi[1] + xi[5];
    float os1r = xr[1] - xr[5], os1i = xi[1] - xi[5];
    float os2r = xr[3] + xr[7], os2i = xi[3] + xi[7];
    float os3r = xr[3] - xr[7], os3i = xi[3] - xi[7];
    float O0r = os0r + os2r, O0i = os0i + os2i;
    float O2r = os0r - os2r, O2i = os0i - os2i;
    float O1r = os1r + os3i, O1i = os1i - os3r;
    float O3r = os1r - os3i, O3i = os1i + os3r;
    float p1 = c8 * (O1r + O1i), q1 = c8 * (O1i - O1r);
    float p3 = c8 * (O3r + O3i), q3 = c8 * (O3i - O3r);
    xr[0] = E0r + O0r; xi[0] = E0i + O0i;
    xr[4] = E0r - O0r; xi[4] = E0i - O0i;
    xr[1] = E1r + p1;  xi[1] = E1i + q1;
    xr[5] = E1r - p1;  xi[5] = E1i - q1;
    xr[2] = E2r + O2i; xi[2] = E2i - O2r;
    xr[6] = E2r - O2i; xi[6] = E2i + O2r;
    xr[3] = E3r + q3;  xi[3] = E3i - p3;
    xr[7] = E3r - q3;  xi[7] = E3i + p3;
}

__device__ __forceinline__ int padc(int p) { return p + (p >> 5); }

// apply W^{k} chain (base wr_,wi_) to both streams a and b
#define TWIDDLE2(wr_, wi_)                                                    \
    {                                                                         \
        float cr_ = (wr_), ci_ = (wi_);                                       \
        _Pragma("unroll")                                                     \
        for (int k = 1; k < 8; ++k) {                                         \
            float t0 = ar[k] * cr_ - ai[k] * ci_;                             \
            float t1 = ar[k] * ci_ + ai[k] * cr_;                             \
            ar[k] = t0; ai[k] = t1;                                           \
            float t2 = br[k] * cr_ - bi[k] * ci_;                             \
            float t3 = br[k] * ci_ + bi[k] * cr_;                             \
            br[k] = t2; bi[k] = t3;                                           \
            if (k < 7) {                                                      \
                float nr = cr_ * (wr_) - ci_ * (wi_);                         \
                float ni = cr_ * (wi_) + ci_ * (wr_);                         \
                cr_ = nr; ci_ = ni;                                           \
            }                                                                 \
        }                                                                     \
    }

// ---------------------------------------------------------------------------
// fft_corr (round-7 measured-best: 117us): dual-column batching (2 d-cols per
// FFT round-trip, shared twiddle chain), register accumulators, float2 planes
// with padc. grid = 2048 (16 b x 128 chunks), block = 256.
// ---------------------------------------------------------------------------
__global__ __launch_bounds__(256)
void fft_corr(const unsigned short* __restrict__ qt, const unsigned short* __restrict__ kt,
              float* __restrict__ G) {
    __shared__ float2 za[2112];
    __shared__ float2 zb[2112];
    float* zfr0 = (float*)za; float* zfi0 = zfr0 + 2112;
    float* zfr1 = (float*)zb; float* zfi1 = zfr1 + 2112;
    const int tid = threadIdx.x;
    const int b = blockIdx.x >> 7;
    const int chunk = blockIdx.x & 127;

    const float N2PI = -6.28318530717958647692f;
    float w1r, w1i, w2r, w2i, w3r, w3i;
    {
        float s, c;
        __sincosf(N2PI * (float)tid * (1.0f / 2048.0f), &s, &c); w1r = c; w1i = s;
        __sincosf(N2PI * (float)(tid & 31) * (1.0f / 256.0f), &s, &c); w2r = c; w2i = s;
        __sincosf(N2PI * (float)(tid & 3) * (1.0f / 32.0f),  &s, &c); w3r = c; w3i = s;
    }

    float aR0 = 0.f, aI0 = 0.f, aR1 = 0.f, aI1 = 0.f;
    float aR2 = 0.f, aI2 = 0.f, aR3 = 0.f, aI3 = 0.f, aR4 = 0.f;

    const int beta = tid >> 5, s2 = tid & 31;
    const int gam  = tid >> 2, u3 = tid & 3;

    for (int it = 0; it < 4; ++it) {
        const int d0 = chunk * 8 + it * 2;
        const unsigned short* q0 = qt + ((size_t)b * 1024 + d0) * 2048;
        const unsigned short* k0 = kt + ((size_t)b * 1024 + d0) * 2048;
        const unsigned short* q1 = q0 + 2048;
        const unsigned short* k1 = k0 + 2048;

        float ar[8], ai[8], br[8], bi[8];
#pragma unroll
        for (int k = 0; k < 8; ++k) {
            ar[k] = bf2f(q0[tid + 256 * k]); ai[k] = bf2f(k0[tid + 256 * k]);
            br[k] = bf2f(q1[tid + 256 * k]); bi[k] = bf2f(k1[tid + 256 * k]);
        }
        dft8(ar, ai); dft8(br, bi);
        TWIDDLE2(w1r, w1i)
#pragma unroll
        for (int k = 0; k < 8; ++k) {
            const int p = padc(256 * k + tid);
            za[p] = make_float2(ar[k], ai[k]);
            zb[p] = make_float2(br[k], bi[k]);
        }
        __syncthreads();

#pragma unroll
        for (int k = 0; k < 8; ++k) {
            const int p = padc(256 * beta + 32 * k + s2);
            float2 va = za[p]; ar[k] = va.x; ai[k] = va.y;
            float2 vb = zb[p]; br[k] = vb.x; bi[k] = vb.y;
        }
        dft8(ar, ai); dft8(br, bi);
        TWIDDLE2(w2r, w2i)
#pragma unroll
        for (int k = 0; k < 8; ++k) {
            const int p = padc(256 * beta + 32 * k + s2);
            za[p] = make_float2(ar[k], ai[k]);
            zb[p] = make_float2(br[k], bi[k]);
        }
        __syncthreads();

#pragma unroll
        for (int k = 0; k < 8; ++k) {
            const int p = padc(32 * gam + 4 * k + u3);
            float2 va = za[p]; ar[k] = va.x; ai[k] = va.y;
            float2 vb = zb[p]; br[k] = vb.x; bi[k] = vb.y;
        }
        dft8(ar, ai); dft8(br, bi);
        TWIDDLE2(w3r, w3i)
#pragma unroll
        for (int k = 0; k < 8; ++k) {
            const int p = padc(32 * gam + 4 * k + u3);
            za[p] = make_float2(ar[k], ai[k]);
            zb[p] = make_float2(br[k], bi[k]);
        }
        __syncthreads();

#pragma unroll
        for (int k = 0; k < 8; ++k) {
            const int p = padc(8 * tid + k);
            float2 va = za[p]; ar[k] = va.x; ai[k] = va.y;
            float2 vb = zb[p]; br[k] = vb.x; bi[k] = vb.y;
        }
        __syncthreads();   // reads complete before scatter overwrites aliased planes

#pragma unroll
        for (int blk = 0; blk < 2; ++blk) {
            const int o = 4 * blk;
            {
                float s0r = ar[o] + ar[o + 2], s0i = ai[o] + ai[o + 2];
                float s1r = ar[o] - ar[o + 2], s1i = ai[o] - ai[o + 2];
                float s2r = ar[o + 1] + ar[o + 3], s2i = ai[o + 1] + ai[o + 3];
                float s3r = ar[o + 1] - ar[o + 3], s3i = ai[o + 1] - ai[o + 3];
                ar[o + 0] = s0r + s2r; ai[o + 0] = s0i + s2i;
                ar[o + 2] = s0r - s2r; ai[o + 2] = s0i - s2i;
                ar[o + 1] = s1r + s3i; ai[o + 1] = s1i - s3r;
                ar[o + 3] = s1r - s3i; ai[o + 3] = s1i + s3r;
            }
            {
                float s0r = br[o] + br[o + 2], s0i = bi[o] + bi[o + 2];
                float s1r = br[o] - br[o + 2], s1i = bi[o] - bi[o + 2];
                float s2r = br[o + 1] + br[o + 3], s2i = bi[o + 1] + bi[o + 3];
                float s3r = br[o + 1] - br[o + 3], s3i = bi[o + 1] - bi[o + 3];
                br[o + 0] = s0r + s2r; bi[o + 0] = s0i + s2i;
                br[o + 2] = s0r - s2r; bi[o + 2] = s0i - s2i;
                br[o + 1] = s1r + s3i; bi[o + 1] = s1i - s3r;
                br[o + 3] = s1r - s3i; bi[o + 3] = s1i + s3r;
            }
        }
        {
            const int k1d = tid >> 5;
            const int k2d = (tid >> 2) & 7;
            const int fb = k1d + 8 * k2d;
#pragma unroll
            for (int blk = 0; blk < 2; ++blk) {
                const int k3d = (2 * (tid & 3) + blk) & 7;
#pragma unroll
                for (int k4 = 0; k4 < 4; ++k4) {
                    const int f = fb + 64 * k3d + 512 * k4;
                    const int pf = padc(f);
                    zfr0[pf] = ar[4 * blk + k4]; zfi0[pf] = ai[4 * blk + k4];
                    zfr1[pf] = br[4 * blk + k4]; zfi1[pf] = bi[4 * blk + k4];
                }
            }
        }
        __syncthreads();

        // Hermitian split + accumulate (registers)
#pragma unroll
        for (int k = 0; k < 4; ++k) {
            const int f = tid + 256 * k;
            const int f2 = (2048 - f) & 2047;
            const int pf = padc(f), pf2 = padc(f2);
            float Zr = zfr0[pf],  Zi = zfi0[pf];
            float Yr = zfr0[pf2], Yi = -zfi0[pf2];
            float Qr = 0.5f * (Zr + Yr), Qi = 0.5f * (Zi + Yi);
            float Kr = 0.5f * (Zi - Yi), Ki = -0.5f * (Zr - Yr);
            float dR = Qr * Kr + Qi * Ki;
            float dI = Qi * Kr - Qr * Ki;
            Zr = zfr1[pf];  Zi = zfi1[pf];
            Yr = zfr1[pf2]; Yi = -zfi1[pf2];
            Qr = 0.5f * (Zr + Yr); Qi = 0.5f * (Zi + Yi);
            Kr = 0.5f * (Zi - Yi); Ki = -0.5f * (Zr - Yr);
            dR += Qr * Kr + Qi * Ki;
            dI += Qi * Kr - Qr * Ki;
            if      (k == 0) { aR0 += dR; aI0 += dI; }
            else if (k == 1) { aR1 += dR; aI1 += dI; }
            else if (k == 2) { aR2 += dR; aI2 += dI; }
            else             { aR3 += dR; aI3 += dI; }
        }
        if (tid == 0) {   // f = 1024: Q = Re(Z), K = Im(Z), P imag = 0
            const int pf = padc(1024);
            aR4 += zfr0[pf] * zfi0[pf] + zfr1[pf] * zfi1[pf];
        }
        __syncthreads();   // plane reads done before next iteration's R1 writes
    }

    atomicAdd(&G[((size_t)b * 1025 + tid +   0) * 2 + 0], aR0);
    atomicAdd(&G[((size_t)b * 1025 + tid +   0) * 2 + 1], aI0);
    atomicAdd(&G[((size_t)b * 1025 + tid + 256) * 2 + 0], aR1);
    atomicAdd(&G[((size_t)b * 1025 + tid + 256) * 2 + 1], aI1);
    atomicAdd(&G[((size_t)b * 1025 + tid + 512) * 2 + 0], aR2);
    atomicAdd(&G[((size_t)b * 1025 + tid + 512) * 2 + 1], aI2);
    atomicAdd(&G[((size_t)b * 1025 + tid + 768) * 2 + 0], aR3);
    atomicAdd(&G[((size_t)b * 1025 + tid + 768) * 2 + 1], aI3);
    if (tid == 0)
        atomicAdd(&G[((size_t)b * 1025 + 1024) * 2 + 0], aR4);
}

// ---------------------------------------------------------------------------
// In-LDS radix-2 DIT FFT, N=2048 (only used by irfft_mean: 16 blocks, cheap).
// ---------------------------------------------------------------------------
__device__ __forceinline__ void fft2048(float* zr, float* zi,
                                        const float* twr, const float* twi, int tid) {
    for (int t = tid; t < 2048; t += 256) {
        int j = __brev((unsigned)t) >> 21;
        if (j > t) {
            float a = zr[t]; zr[t] = zr[j]; zr[j] = a;
            float c = zi[t]; zi[t] = zi[j]; zi[j] = c;
        }
    }
    __syncthreads();
    for (int s = 0; s < 11; ++s) {
        const int m = 1 << s;
        for (int i = tid; i < 1024; i += 256) {
            const int pos = i & (m - 1);
            const int i1  = ((i >> s) << (s + 1)) + pos;
            const int i2  = i1 + m;
            const int tw  = pos << (10 - s);
            float wr = twr[tw], wi = twi[tw];
            float xr = zr[i2], xi = zi[i2];
            float tr = wr * xr - wi * xi;
            float ti = wr * xi + wi * xr;
            float ur = zr[i1], ui = zi[i1];
            zr[i2] = ur - tr; zi[i2] = ui - ti;
            zr[i1] = ur + tr; zi[i1] = ui + ti;
        }
        __syncthreads();
    }
}

__device__ __forceinline__ void init_twiddle(float* twr, float* twi, int tid) {
    for (int j = tid; j < 1024; j += 256) {
        float ang = -6.28318530717958647692f * (float)j * (1.0f / 2048.0f);
        twr[j] = cosf(ang);
        twi[j] = sinf(ang);
    }
}

// ---------------------------------------------------------------------------
// Per-batch irfft of G -> mean_value[b][t], scale 1/(2048*1024). grid = 16.
// ---------------------------------------------------------------------------
__global__ __launch_bounds__(256)
void irfft_mean(const float* __restrict__ G, float* __restrict__ mv) {
    __shared__ float zr[2048], zi[2048];
    __shared__ float twr[1024], twi[1024];
    const int tid = threadIdx.x;
    const int b = blockIdx.x;
    init_twiddle(twr, twi, tid);
    for (int f = tid; f < 2048; f += 256) {
        int g = (f <= 1024) ? f : 2048 - f;
        float gr = G[((size_t)b * 1025 + g) * 2 + 0];
        float gi = G[((size_t)b * 1025 + g) * 2 + 1];
        zr[f] = gr;
        zi[f] = (f <= 1024) ? -gi : gi;
    }
    __syncthreads();
    fft2048(zr, zi, twr, twi, tid);
    const float sc = 1.0f / (2048.0f * 1024.0f);
    for (int t = tid; t < 2048; t += 256) mv[b * 2048 + t] = zr[t] * sc;
}

// ---------------------------------------------------------------------------
// Top-7 over batch-mean + per-batch softmax (parallel argmax).
// ---------------------------------------------------------------------------
__global__ __launch_bounds__(256)
void topk_softmax(const float* __restrict__ mv, int* __restrict__ idx_out,
                  float* __restrict__ w_out) {
    __shared__ float cm[2048];
    __shared__ float wv4[4];
    __shared__ int   wi4[4];
    __shared__ int   sel[7];
    const int tid  = threadIdx.x;
    const int lane = tid & 63;
    const int wvid = tid >> 6;

    for (int t = tid; t < 2048; t += 256) {
        float s = 0.f;
        for (int b = 0; b < 16; ++b) s += mv[b * 2048 + t];
        cm[t] = s * (1.0f / 16.0f);
    }
    __syncthreads();

    for (int it = 0; it < 7; ++it) {
        float best = -3.4e38f; int bi = 1 << 30;
#pragma unroll
        for (int q = 0; q < 8; ++q) {
            const int t = tid + q * 256;
            float v = cm[t];
            if (v > best || (v == best && t < bi)) { best = v; bi = t; }
        }
#pragma unroll
        for (int off = 32; off > 0; off >>= 1) {
            float ov = __shfl_xor(best, off, 64);
            int   oi = __shfl_xor(bi,   off, 64);
            if (ov > best || (ov == best && oi < bi)) { best = ov; bi = oi; }
        }
        if (lane == 0) { wv4[wvid] = best; wi4[wvid] = bi; }
        __syncthreads();
        if (tid == 0) {
            float bb = wv4[0]; int bj = wi4[0];
#pragma unroll
            for (int u = 1; u < 4; ++u)
                if (wv4[u] > bb || (wv4[u] == bb && wi4[u] < bj)) { bb = wv4[u]; bj = wi4[u]; }
            sel[it] = bj;
            idx_out[it] = bj;
            cm[bj] = -3.4e38f;
        }
        __syncthreads();
    }

    if (tid < 16) {
        const int b = tid;
        float wv[7]; float mx = -3.4e38f;
#pragma unroll
        for (int i = 0; i < 7; ++i) { wv[i] = mv[b * 2048 + sel[i]]; mx = fmaxf(mx, wv[i]); }
        float s = 0.f;
#pragma unroll
        for (int i = 0; i < 7; ++i) { wv[i] = expf(wv[i] - mx); s += wv[i]; }
        float inv = 1.0f / s;
#pragma unroll
        for (int i = 0; i < 7; ++i) w_out[b * 7 + i] = wv[i] * inv;
    }
}

// ---------------------------------------------------------------------------
// agg[b,t,d] = bf16( sum_i w[b,i] * values[b,(t+idx[i])%2048,d] )  (fp32 in)
// ---------------------------------------------------------------------------
__global__ __launch_bounds__(256)
void agg_kernel(const float* __restrict__ vsrc, const int* __restrict__ idx,
                const float* __restrict__ w, unsigned short* __restrict__ agg) {
    const int b  = blockIdx.y;
    const int t  = blockIdx.x * 2 + (threadIdx.x >> 7);
    const int d8 = (threadIdx.x & 127) * 8;
    float av[8] = {0.f, 0.f, 0.f, 0.f, 0.f, 0.f, 0.f, 0.f};
#pragma unroll
    for (int i = 0; i < 7; ++i) {
        const int srow = (t + idx[i]) & 2047;
        const float wi = w[b * 7 + i];
        const float* src = vsrc + ((size_t)b * 2048 + srow) * 1024 + d8;
        f32x4 v0 = *(const f32x4*)src;
        f32x4 v1 = *(const f32x4*)(src + 4);
#pragma unroll
        for (int j = 0; j < 4; ++j) av[j] += wi * v0[j];
#pragma unroll
        for (int j = 0; j < 4; ++j) av[4 + j] += wi * v1[j];
    }
    bf16x8 o;
#pragma unroll
    for (int j = 0; j < 8; ++j) o[j] = (short)f2bf(av[j]);
    *(bf16x8*)&agg[((size_t)b * 2048 + t) * 1024 + d8] = o;
}

// ---------------------------------------------------------------------------
extern "C" void kernel_launch(void* const* d_in, const int* in_sizes, int n_in,
                              void* d_out, int out_size, void* d_ws, size_t ws_size,
                              hipStream_t stream) {
    const float* queries = (const float*)d_in[0];
    const float* keys    = (const float*)d_in[1];
    const float* values  = (const float*)d_in[2];
    const float* Wq = (const float*)d_in[3];
    const float* Wk = (const float*)d_in[5];
    const float* Wv = (const float*)d_in[7];  const float* bv = (const float*)d_in[8];
    const float* Wo = (const float*)d_in[9];  const float* bo = (const float*)d_in[10];
    float* out = (float*)d_out;

    char* ws = (char*)d_ws;
    constexpr size_t SZP = (size_t)32768 * 1024 * 2;           // 64 MB (bf16 B*L*D)
    unsigned short* agg = (unsigned short*)(ws);               // agg output [b][t][d]
    unsigned short* kt  = (unsigned short*)(ws + SZP);         // k~^T [b][d][t]
    unsigned short* qt  = (unsigned short*)(ws + 2 * SZP);     // q^T  [b][d][t]
    unsigned short* ab  = (unsigned short*)(ws + 3 * SZP);     // staging (64MB)
    unsigned short* wo  = ab;                                  // bf16 Wo
    unsigned short* wvT = ab + 1048576;                        // bf16 Wv^T
    unsigned short* wqT = ab + 2097152;                        // bf16 Wq^T
    unsigned short* wkT = ab + 3145728;                        // bf16 Wk^T
    unsigned short* W2  = (unsigned short*)(ws + 4 * SZP);     // bf16 Wo@Wv   [N][K]
    unsigned short* M   = W2 + 1048576;                        // bf16 Wq^T@Wk [N][K]
    char* tail = ws + 4 * SZP + 4194304;
    float* zb1024 = (float*)(tail);                            // 4KB zero bias
    float* b2     = (float*)(tail + 4096);
    float* G      = (float*)(tail + 8192);                     // 16*1025*2 f32
    float* mv     = (float*)(tail + 8192 + 131328);
    int*   idx    = (int*)  (tail + 8192 + 131328 + 131072);
    float* wsm    = (float*)(tail + 8192 + 131328 + 131072 + 64);

    // 1) all weight prep in one launch
    prep_all<<<1290, 256, 0, stream>>>(Wq, Wk, Wv, Wo, bv, bo,
                                       wo, wvT, wqT, wkT, G, zb1024, b2);
    // 2) W2 = Wo@Wv and M = Wq^T@Wk in one launch
    gemm_pair<<<32, 512, 0, stream>>>(wo, wvT, zb1024, W2,
                                      wqT, wkT, zb1024, M);
    // 3) qt = queries^T (bf16) and ab = bf16(keys) in one launch
    prep_inputs<<<24576, 256, 0, stream>>>(queries, keys, qt, ab);
    // 4) k~ = k @ M^T (transposed out)
    gemm256<2><<<512, 512, 0, stream>>>(ab, M, zb1024, kt);

    // 5) correlation -> top-k -> aggregation -> fused output GEMM
    fft_corr<<<2048, 256, 0, stream>>>(qt, kt, G);
    irfft_mean<<<16, 256, 0, stream>>>(G, mv);
    topk_softmax<<<1, 256, 0, stream>>>(mv, idx, wsm);
    agg_kernel<<<dim3(1024, 16), 256, 0, stream>>>(values, idx, wsm, agg);
    gemm256<1><<<512, 512, 0, stream>>>(agg, W2, b2, out);
}

// Round 12
// 495.122 us; speedup vs baseline: 2.0612x; 1.0289x over previous
//
#include <hip/hip_runtime.h>

typedef __attribute__((ext_vector_type(8))) short bf16x8;
typedef __attribute__((ext_vector_type(4))) short s16x4;
typedef __attribute__((ext_vector_type(4))) float f32x4;

__device__ __forceinline__ float bf2f(unsigned short u) {
    union { unsigned int u; float f; } x; x.u = ((unsigned int)u) << 16; return x.f;
}
__device__ __forceinline__ unsigned short f2bf(float f) {
    union { float f; unsigned int u; } x; x.f = f;
    unsigned int u = x.u;
    unsigned int r = (u + 0x7fffu + ((u >> 16) & 1u)) >> 16;
    return (unsigned short)r;
}

#define GLDS16(gp, lp)                                                        \
    __builtin_amdgcn_global_load_lds(                                         \
        (const __attribute__((address_space(1))) void*)(gp),                  \
        (__attribute__((address_space(3))) void*)(lp), 16, 0, 0)

// ---------------------------------------------------------------------------
// GEMM body: C[M, N=1024] = A[M,K=1024] @ W^T + bias. A,W bf16 (W=[N,K]).
// 256x256 tile, BK=64, 8 waves, 128KB LDS dbuf, depth-2 prefetch, counted
// vmcnt(8), raw s_barrier, setprio, XOR-swizzled staging (verified conflicts=0).
// OUT_MODE: 0 = bf16 [row][col], 1 = f32 [row][col], 2 = bf16 transposed
//           [b][col][t] (row = b*2048+t).
// ---------------------------------------------------------------------------
template<int OUT_MODE>
__device__ __forceinline__
void gemm_body(const unsigned short* __restrict__ A, const unsigned short* __restrict__ Bw,
               const float* __restrict__ bias, void* __restrict__ out_,
               int bid, int nb, unsigned short* sAp, unsigned short* sBp) {
    const int tid  = threadIdx.x;
    const int lane = tid & 63;
    const int w    = tid >> 6;
    const int wr   = w >> 2, wc = w & 3;
    const int fr   = lane & 15, g4 = lane >> 4;

    const int qq  = nb >> 3;
    const int swz = qq ? (bid & 7) * qq + (bid >> 3) : bid;
    const int  col0 = (swz & 3) * 256;
    const long row0 = (long)(swz >> 2) * 256;

    const int srow = tid >> 3;
    const int sj   = (tid & 7) ^ (srow & 7);
    const unsigned short* gA = A  + (size_t)(row0 + srow) * 1024 + sj * 8;
    const unsigned short* gB = Bw + (size_t)(col0 + srow) * 1024 + sj * 8;
    const int ldst = w * 1024;

    auto stage = [&](int buf, int t) {
        const unsigned short* a = gA + t * 64;
        const unsigned short* b = gB + t * 64;
        char* dA = (char*)(sAp + buf * 16384);
        char* dB = (char*)(sBp + buf * 16384);
#pragma unroll
        for (int r = 0; r < 4; ++r)
            GLDS16(a + r * 65536, (__attribute__((address_space(3))) char*)(dA + r * 8192 + ldst));
#pragma unroll
        for (int r = 0; r < 4; ++r)
            GLDS16(b + r * 65536, (__attribute__((address_space(3))) char*)(dB + r * 8192 + ldst));
    };

    f32x4 acc[8][4];
#pragma unroll
    for (int m = 0; m < 8; ++m)
#pragma unroll
        for (int n = 0; n < 4; ++n) acc[m][n] = (f32x4){0.f, 0.f, 0.f, 0.f};

    stage(0, 0);
    stage(1, 1);

    const int mskK = (fr & 7) << 4;

    for (int t = 0; t < 16; ++t) {
        if (t < 15) asm volatile("s_waitcnt vmcnt(8)" ::: "memory");
        else        asm volatile("s_waitcnt vmcnt(0)" ::: "memory");
        asm volatile("s_barrier" ::: "memory");
        __builtin_amdgcn_sched_barrier(0);

        const char* la = (const char*)(sAp + (t & 1) * 16384);
        const char* lb = (const char*)(sBp + (t & 1) * 16384);

        bf16x8 bF[2][4];
#pragma unroll
        for (int c = 0; c < 2; ++c)
#pragma unroll
            for (int n = 0; n < 4; ++n) {
                const int row = wc * 64 + n * 16 + fr;
                bF[c][n] = *(const bf16x8*)(lb + row * 128 + ((c * 64 + g4 * 16) ^ mskK));
            }
#pragma unroll
        for (int mh = 0; mh < 2; ++mh) {
            bf16x8 aF[2][4];
#pragma unroll
            for (int c = 0; c < 2; ++c)
#pragma unroll
                for (int m = 0; m < 4; ++m) {
                    const int row = wr * 128 + mh * 64 + m * 16 + fr;
                    aF[c][m] = *(const bf16x8*)(la + row * 128 + ((c * 64 + g4 * 16) ^ mskK));
                }
            __builtin_amdgcn_s_setprio(1);
#pragma unroll
            for (int c = 0; c < 2; ++c)
#pragma unroll
                for (int n = 0; n < 4; ++n)
#pragma unroll
                    for (int m = 0; m < 4; ++m)
                        acc[mh * 4 + m][n] =
                            __builtin_amdgcn_mfma_f32_16x16x32_bf16(aF[c][m], bF[c][n], acc[mh * 4 + m][n], 0, 0, 0);
            __builtin_amdgcn_s_setprio(0);
        }

        __builtin_amdgcn_sched_barrier(0);
        asm volatile("s_barrier" ::: "memory");
        if (t + 2 < 16) stage(t & 1, t + 2);
    }

    const int cr = g4 * 4;
    const int cc = fr;
    if constexpr (OUT_MODE == 2) {
        const int b  = (int)(row0 >> 11);
        const int tb = ((int)row0 & 2047) + wr * 128 + cr;
#pragma unroll
        for (int m = 0; m < 8; ++m) {
#pragma unroll
            for (int n = 0; n < 4; ++n) {
                int col = col0 + wc * 64 + n * 16 + cc;
                float bv = bias[col];
                s16x4 o;
#pragma unroll
                for (int j = 0; j < 4; ++j) o[j] = (short)f2bf(acc[m][n][j] + bv);
                *(s16x4*)&((unsigned short*)out_)[((size_t)b * 1024 + col) * 2048 + tb + m * 16] = o;
            }
        }
    } else {
#pragma unroll
        for (int m = 0; m < 8; ++m) {
            long row = row0 + wr * 128 + m * 16 + cr;
#pragma unroll
            for (int n = 0; n < 4; ++n) {
                int col = col0 + wc * 64 + n * 16 + cc;
                float bv = bias[col];
#pragma unroll
                for (int j = 0; j < 4; ++j) {
                    float v = acc[m][n][j] + bv;
                    if constexpr (OUT_MODE == 1) ((float*)out_)[(row + j) * 1024 + col] = v;
                    else ((unsigned short*)out_)[(row + j) * 1024 + col] = f2bf(v);
                }
            }
        }
    }
}

template<int OUT_MODE>
__global__ __launch_bounds__(512, 2)
void gemm256(const unsigned short* __restrict__ A, const unsigned short* __restrict__ Bw,
             const float* __restrict__ bias, void* __restrict__ out_) {
    __shared__ __align__(16) unsigned short sA[2][16384];
    __shared__ __align__(16) unsigned short sB[2][16384];
    gemm_body<OUT_MODE>(A, Bw, bias, out_, blockIdx.x, gridDim.x, &sA[0][0], &sB[0][0]);
}

// two independent 1024x1024 GEMMs in one launch (grid = 32)
__global__ __launch_bounds__(512, 2)
void gemm_pair(const unsigned short* __restrict__ A0, const unsigned short* __restrict__ B0,
               const float* __restrict__ bias0, void* __restrict__ o0,
               const unsigned short* __restrict__ A1, const unsigned short* __restrict__ B1,
               const float* __restrict__ bias1, void* __restrict__ o1) {
    __shared__ __align__(16) unsigned short sA[2][16384];
    __shared__ __align__(16) unsigned short sB[2][16384];
    if (blockIdx.x < 16)
        gemm_body<0>(A0, B0, bias0, o0, blockIdx.x, 16, &sA[0][0], &sB[0][0]);
    else
        gemm_body<0>(A1, B1, bias1, o1, blockIdx.x - 16, 16, &sA[0][0], &sB[0][0]);
}

// ---------------------------------------------------------------------------
// prep_everything: ALL preprocessing in ONE launch. grid = 25866, block 256.
//  [0, 8192)      : qt[b][d][t] = bf16(queries[b][t][d])  (transpose-cast)
//  [8192, 24576)  : ab = bf16(keys)                        (straight cast)
//  [24576, 25344) : Wv/Wq/Wk transpose-cast -> wvT/wqT/wkT (768 blocks)
//  [25344, 25600) : Wo cast -> wo                          (256 blocks)
//  [25600, 25609) : zero G (32800 f32)
//  25609          : zero zb1024
//  [25610, 25866) : b2[n] = Wo[n,:]·bv + bo[n]             (256 blocks)
// ---------------------------------------------------------------------------
__global__ __launch_bounds__(256)
void prep_everything(const float* __restrict__ queries, const float* __restrict__ keys,
                     const float* __restrict__ Wq, const float* __restrict__ Wk,
                     const float* __restrict__ Wv, const float* __restrict__ Wo,
                     const float* __restrict__ bv, const float* __restrict__ bo,
                     unsigned short* __restrict__ qt, unsigned short* __restrict__ ab,
                     unsigned short* __restrict__ wo, unsigned short* __restrict__ wvT,
                     unsigned short* __restrict__ wqT, unsigned short* __restrict__ wkT,
                     float* __restrict__ G, float* __restrict__ zb, float* __restrict__ b2) {
    __shared__ float tsm[64][65];
    const int bx  = blockIdx.x;
    const int tid = threadIdx.x;

    if (bx < 8192) {
        const int b   = bx >> 9;
        const int rem = bx & 511;
        const int t0  = (rem & 31) * 64;
        const int d0  = (rem >> 5) * 64;
        const int tx = tid & 63, ty = tid >> 6;
        const float* s = queries + ((size_t)b * 2048 + t0) * 1024 + d0;
        for (int r = ty; r < 64; r += 4)
            tsm[r][tx] = s[(size_t)r * 1024 + tx];
        __syncthreads();
        unsigned short* d = qt + ((size_t)b * 1024 + d0) * 2048 + t0;
        for (int r = ty; r < 64; r += 4)
            d[(size_t)r * 2048 + tx] = f2bf(tsm[tx][r]);
    } else if (bx < 24576) {
        const size_t i = ((size_t)(bx - 8192) * 256 + tid) * 8;
        f32x4 v0 = *(const f32x4*)(keys + i);
        f32x4 v1 = *(const f32x4*)(keys + i + 4);
        bf16x8 o;
#pragma unroll
        for (int j = 0; j < 4; ++j) o[j] = (short)f2bf(v0[j]);
#pragma unroll
        for (int j = 0; j < 4; ++j) o[4 + j] = (short)f2bf(v1[j]);
        *(bf16x8*)(ab + i) = o;
    } else if (bx < 25344) {
        const int wx = bx - 24576;
        const float* src = (wx < 256) ? Wv : (wx < 512) ? Wq : Wk;
        unsigned short* dst = (wx < 256) ? wvT : (wx < 512) ? wqT : wkT;
        const int t  = wx & 255;
        const int b0 = (t & 15) * 64;
        const int by = (t >> 4) * 64;
        const int tx = tid & 63, ty = tid >> 6;
        for (int r = ty; r < 64; r += 4)
            tsm[r][tx] = src[(size_t)(by + r) * 1024 + b0 + tx];
        __syncthreads();
        for (int r = ty; r < 64; r += 4)
            dst[(size_t)(b0 + r) * 1024 + by + tx] = f2bf(tsm[tx][r]);
    } else if (bx < 25600) {
        const int base = (bx - 25344) * 4096 + tid * 4;
#pragma unroll
        for (int r = 0; r < 4; ++r) {
            const int i = base + r * 1024;
            f32x4 v = *(const f32x4*)(Wo + i);
            s16x4 o;
#pragma unroll
            for (int j = 0; j < 4; ++j) o[j] = (short)f2bf(v[j]);
            *(s16x4*)(wo + i) = o;
        }
    } else if (bx < 25609) {
        const int base = (bx - 25600) * 4096;
#pragma unroll
        for (int r = 0; r < 16; ++r) {
            const int i = base + r * 256 + tid;
            if (i < 32800) G[i] = 0.0f;
        }
    } else if (bx == 25609) {
        *(f32x4*)(zb + tid * 4) = (f32x4){0.f, 0.f, 0.f, 0.f};
    } else {
        const int n = (bx - 25610) * 4 + (tid >> 6);
        const int lane = tid & 63;
        float s = 0.f;
        for (int k = lane; k < 1024; k += 64) s += Wo[(size_t)n * 1024 + k] * bv[k];
#pragma unroll
        for (int off = 32; off > 0; off >>= 1) s += __shfl_xor(s, off, 64);
        if (lane == 0) b2[n] = s + bo[n];
    }
}

// ---------------------------------------------------------------------------
// 8-point DFT (negative exponent), in place on xr/xi[8].
// ---------------------------------------------------------------------------
__device__ __forceinline__ void dft8(float* xr, float* xi) {
    const float c8 = 0.70710678118654752440f;
    float es0r = xr[0] + xr[4], es0i = xi[0] + xi[4];
    float es1r = xr[0] - xr[4], es1i = xi[0] - xi[4];
    float es2r = xr[2] + xr[6], es2i = xi[2] + xi[6];
    float es3r = xr[2] - xr[6], es3i = xi[2] - xi[6];
    float E0r = es0r + es2r, E0i = es0i + es2i;
    float E2r = es0r - es2r, E2i = es0i - es2i;
    float E1r = es1r + es3i, E1i = es1i - es3r;
    float E3r = es1r - es3i, E3i = es1i + es3r;
    float os0r = xr[1] + xr[5], os0i = xi[1] + xi[5];
    float os1r = xr[1] - xr[5], os1i = xi[1] - xi[5];
    float os2r = xr[3] + xr[7], os2i = xi[3] + xi[7];
    float os3r = xr[3] - xr[7], os3i = xi[3] - xi[7];
    float O0r = os0r + os2r, O0i = os0i + os2i;
    float O2r = os0r - os2r, O2i = os0i - os2i;
    float O1r = os1r + os3i, O1i = os1i - os3r;
    float O3r = os1r - os3i, O3i = os1i + os3r;
    float p1 = c8 * (O1r + O1i), q1 = c8 * (O1i - O1r);
    float p3 = c8 * (O3r + O3i), q3 = c8 * (O3i - O3r);
    xr[0] = E0r + O0r; xi[0] = E0i + O0i;
    xr[4] = E0r - O0r; xi[4] = E0i - O0i;
    xr[1] = E1r + p1;  xi[1] = E1i + q1;
    xr[5] = E1r - p1;  xi[5] = E1i - q1;
    xr[2] = E2r + O2i; xi[2] = E2i - O2r;
    xr[6] = E2r - O2i; xi[6] = E2i + O2r;
    xr[3] = E3r + q3;  xi[3] = E3i - p3;
    xr[7] = E3r - q3;  xi[7] = E3i + p3;
}

__device__ __forceinline__ int padc(int p) { return p + (p >> 5); }

// apply W^{k} chain (base wr_,wi_) to both streams a and b
#define TWIDDLE2(wr_, wi_)                                                    \
    {                                                                         \
        float cr_ = (wr_), ci_ = (wi_);                                       \
        _Pragma("unroll")                                                     \
        for (int k = 1; k < 8; ++k) {                                         \
            float t0 = ar[k] * cr_ - ai[k] * ci_;                             \
            float t1 = ar[k] * ci_ + ai[k] * cr_;                             \
            ar[k] = t0; ai[k] = t1;                                           \
            float t2 = br[k] * cr_ - bi[k] * ci_;                             \
            float t3 = br[k] * ci_ + bi[k] * cr_;                             \
            br[k] = t2; bi[k] = t3;                                           \
            if (k < 7) {                                                      \
                float nr = cr_ * (wr_) - ci_ * (wi_);                         \
                float ni = cr_ * (wi_) + ci_ * (wr_);                         \
                cr_ = nr; ci_ = ni;                                           \
            }                                                                 \
        }                                                                     \
    }

// ---------------------------------------------------------------------------
// fft_corr (round-11 verified data path, minus 2 provably-redundant barriers):
// R2->R3 and R3->R4 exchanges are intra-wave (ownership analysis: R3's reads
// come from its own 32-group's R2 writes; R4's reads from its own 4-group's
// R3 writes; per-round read-set == write-set per thread). Program order +
// compiler lgkmcnt gives correctness without s_barrier.
// grid = 2048 (16 b x 128 chunks), block = 256.
// ---------------------------------------------------------------------------
__global__ __launch_bounds__(256)
void fft_corr(const unsigned short* __restrict__ qt, const unsigned short* __restrict__ kt,
              float* __restrict__ G) {
    __shared__ float2 za[2112];
    __shared__ float2 zb[2112];
    float* zfr0 = (float*)za; float* zfi0 = zfr0 + 2112;
    float* zfr1 = (float*)zb; float* zfi1 = zfr1 + 2112;
    const int tid = threadIdx.x;
    const int b = blockIdx.x >> 7;
    const int chunk = blockIdx.x & 127;

    const float N2PI = -6.28318530717958647692f;
    float w1r, w1i, w2r, w2i, w3r, w3i;
    {
        float s, c;
        __sincosf(N2PI * (float)tid * (1.0f / 2048.0f), &s, &c); w1r = c; w1i = s;
        __sincosf(N2PI * (float)(tid & 31) * (1.0f / 256.0f), &s, &c); w2r = c; w2i = s;
        __sincosf(N2PI * (float)(tid & 3) * (1.0f / 32.0f),  &s, &c); w3r = c; w3i = s;
    }

    float aR0 = 0.f, aI0 = 0.f, aR1 = 0.f, aI1 = 0.f;
    float aR2 = 0.f, aI2 = 0.f, aR3 = 0.f, aI3 = 0.f, aR4 = 0.f;

    const int beta = tid >> 5, s2 = tid & 31;
    const int gam  = tid >> 2, u3 = tid & 3;

    for (int it = 0; it < 4; ++it) {
        const int d0 = chunk * 8 + it * 2;
        const unsigned short* q0 = qt + ((size_t)b * 1024 + d0) * 2048;
        const unsigned short* k0 = kt + ((size_t)b * 1024 + d0) * 2048;
        const unsigned short* q1 = q0 + 2048;
        const unsigned short* k1 = k0 + 2048;

        float ar[8], ai[8], br[8], bi[8];
#pragma unroll
        for (int k = 0; k < 8; ++k) {
            ar[k] = bf2f(q0[tid + 256 * k]); ai[k] = bf2f(k0[tid + 256 * k]);
            br[k] = bf2f(q1[tid + 256 * k]); bi[k] = bf2f(k1[tid + 256 * k]);
        }
        dft8(ar, ai); dft8(br, bi);
        TWIDDLE2(w1r, w1i)
#pragma unroll
        for (int k = 0; k < 8; ++k) {
            const int p = padc(256 * k + tid);
            za[p] = make_float2(ar[k], ai[k]);
            zb[p] = make_float2(br[k], bi[k]);
        }
        __syncthreads();   // R1 writers cross-wave: barrier REQUIRED

#pragma unroll
        for (int k = 0; k < 8; ++k) {
            const int p = padc(256 * beta + 32 * k + s2);
            float2 va = za[p]; ar[k] = va.x; ai[k] = va.y;
            float2 vb = zb[p]; br[k] = vb.x; bi[k] = vb.y;
        }
        dft8(ar, ai); dft8(br, bi);
        TWIDDLE2(w2r, w2i)
#pragma unroll
        for (int k = 0; k < 8; ++k) {
            const int p = padc(256 * beta + 32 * k + s2);
            za[p] = make_float2(ar[k], ai[k]);
            zb[p] = make_float2(br[k], bi[k]);
        }
        // NO barrier: R3's reads are satisfied by its own wave's R2 writes
        // (writer tid' = 32*(tid>>5)+4k+u3, same 64-lane wave as reader).

#pragma unroll
        for (int k = 0; k < 8; ++k) {
            const int p = padc(32 * gam + 4 * k + u3);
            float2 va = za[p]; ar[k] = va.x; ai[k] = va.y;
            float2 vb = zb[p]; br[k] = vb.x; bi[k] = vb.y;
        }
        dft8(ar, ai); dft8(br, bi);
        TWIDDLE2(w3r, w3i)
#pragma unroll
        for (int k = 0; k < 8; ++k) {
            const int p = padc(32 * gam + 4 * k + u3);
            za[p] = make_float2(ar[k], ai[k]);
            zb[p] = make_float2(br[k], bi[k]);
        }
        // NO barrier: R4 thread reads 8*tid..8*tid+7, written in R3 by its
        // own 4-lane group (writers (tid&~3)..(tid&~3)+3).

#pragma unroll
        for (int k = 0; k < 8; ++k) {
            const int p = padc(8 * tid + k);
            float2 va = za[p]; ar[k] = va.x; ai[k] = va.y;
            float2 vb = zb[p]; br[k] = vb.x; bi[k] = vb.y;
        }
        __syncthreads();   // anti-dep: scatter overwrites other waves' R4 reads

#pragma unroll
        for (int blk = 0; blk < 2; ++blk) {
            const int o = 4 * blk;
            {
                float s0r = ar[o] + ar[o + 2], s0i = ai[o] + ai[o + 2];
                float s1r = ar[o] - ar[o + 2], s1i = ai[o] - ai[o + 2];
                float s2r = ar[o + 1] + ar[o + 3], s2i = ai[o + 1] + ai[o + 3];
                float s3r = ar[o + 1] - ar[o + 3], s3i = ai[o + 1] - ai[o + 3];
                ar[o + 0] = s0r + s2r; ai[o + 0] = s0i + s2i;
                ar[o + 2] = s0r - s2r; ai[o + 2] = s0i - s2i;
                ar[o + 1] = s1r + s3i; ai[o + 1] = s1i - s3r;
                ar[o + 3] = s1r - s3i; ai[o + 3] = s1i + s3r;
            }
            {
                float s0r = br[o] + br[o + 2], s0i = bi[o] + bi[o + 2];
                float s1r = br[o] - br[o + 2], s1i = bi[o] - bi[o + 2];
                float s2r = br[o + 1] + br[o + 3], s2i = bi[o + 1] + bi[o + 3];
                float s3r = br[o + 1] - br[o + 3], s3i = bi[o + 1] - bi[o + 3];
                br[o + 0] = s0r + s2r; bi[o + 0] = s0i + s2i;
                br[o + 2] = s0r - s2r; bi[o + 2] = s0i - s2i;
                br[o + 1] = s1r + s3i; bi[o + 1] = s1i - s3r;
                br[o + 3] = s1r - s3i; bi[o + 3] = s1i + s3r;
            }
        }
        {
            const int k1d = tid >> 5;
            const int k2d = (tid >> 2) & 7;
            const int fb = k1d + 8 * k2d;
#pragma unroll
            for (int blk = 0; blk < 2; ++blk) {
                const int k3d = (2 * (tid & 3) + blk) & 7;
#pragma unroll
                for (int k4 = 0; k4 < 4; ++k4) {
                    const int f = fb + 64 * k3d + 512 * k4;
                    const int pf = padc(f);
                    zfr0[pf] = ar[4 * blk + k4]; zfi0[pf] = ai[4 * blk + k4];
                    zfr1[pf] = br[4 * blk + k4]; zfi1[pf] = bi[4 * blk + k4];
                }
            }
        }
        __syncthreads();   // scatter writers cross-wave before Hermitian reads

        // Hermitian split + accumulate (registers)
#pragma unroll
        for (int k = 0; k < 4; ++k) {
            const int f = tid + 256 * k;
            const int f2 = (2048 - f) & 2047;
            const int pf = padc(f), pf2 = padc(f2);
            float Zr = zfr0[pf],  Zi = zfi0[pf];
            float Yr = zfr0[pf2], Yi = -zfi0[pf2];
            float Qr = 0.5f * (Zr + Yr), Qi = 0.5f * (Zi + Yi);
            float Kr = 0.5f * (Zi - Yi), Ki = -0.5f * (Zr - Yr);
            float dR = Qr * Kr + Qi * Ki;
            float dI = Qi * Kr - Qr * Ki;
            Zr = zfr1[pf];  Zi = zfi1[pf];
            Yr = zfr1[pf2]; Yi = -zfi1[pf2];
            Qr = 0.5f * (Zr + Yr); Qi = 0.5f * (Zi + Yi);
            Kr = 0.5f * (Zi - Yi); Ki = -0.5f * (Zr - Yr);
            dR += Qr * Kr + Qi * Ki;
            dI += Qi * Kr - Qr * Ki;
            if      (k == 0) { aR0 += dR; aI0 += dI; }
            else if (k == 1) { aR1 += dR; aI1 += dI; }
            else if (k == 2) { aR2 += dR; aI2 += dI; }
            else             { aR3 += dR; aI3 += dI; }
        }
        if (tid == 0) {   // f = 1024: Q = Re(Z), K = Im(Z), P imag = 0
            const int pf = padc(1024);
            aR4 += zfr0[pf] * zfi0[pf] + zfr1[pf] * zfi1[pf];
        }
        __syncthreads();   // anti-dep: next iteration's R1 writes
    }

    atomicAdd(&G[((size_t)b * 1025 + tid +   0) * 2 + 0], aR0);
    atomicAdd(&G[((size_t)b * 1025 + tid +   0) * 2 + 1], aI0);
    atomicAdd(&G[((size_t)b * 1025 + tid + 256) * 2 + 0], aR1);
    atomicAdd(&G[((size_t)b * 1025 + tid + 256) * 2 + 1], aI1);
    atomicAdd(&G[((size_t)b * 1025 + tid + 512) * 2 + 0], aR2);
    atomicAdd(&G[((size_t)b * 1025 + tid + 512) * 2 + 1], aI2);
    atomicAdd(&G[((size_t)b * 1025 + tid + 768) * 2 + 0], aR3);
    atomicAdd(&G[((size_t)b * 1025 + tid + 768) * 2 + 1], aI3);
    if (tid == 0)
        atomicAdd(&G[((size_t)b * 1025 + 1024) * 2 + 0], aR4);
}

// ---------------------------------------------------------------------------
// In-LDS radix-2 DIT FFT, N=2048 (only used by irfft_mean: 16 blocks, cheap).
// ---------------------------------------------------------------------------
__device__ __forceinline__ void fft2048(float* zr, float* zi,
                                        const float* twr, const float* twi, int tid) {
    for (int t = tid; t < 2048; t += 256) {
        int j = __brev((unsigned)t) >> 21;
        if (j > t) {
            float a = zr[t]; zr[t] = zr[j]; zr[j] = a;
            float c = zi[t]; zi[t] = zi[j]; zi[j] = c;
        }
    }
    __syncthreads();
    for (int s = 0; s < 11; ++s) {
        const int m = 1 << s;
        for (int i = tid; i < 1024; i += 256) {
            const int pos = i & (m - 1);
            const int i1  = ((i >> s) << (s + 1)) + pos;
            const int i2  = i1 + m;
            const int tw  = pos << (10 - s);
            float wr = twr[tw], wi = twi[tw];
            float xr = zr[i2], xi = zi[i2];
            float tr = wr * xr - wi * xi;
            float ti = wr * xi + wi * xr;
            float ur = zr[i1], ui = zi[i1];
            zr[i2] = ur - tr; zi[i2] = ui - ti;
            zr[i1] = ur + tr; zi[i1] = ui + ti;
        }
        __syncthreads();
    }
}

__device__ __forceinline__ void init_twiddle(float* twr, float* twi, int tid) {
    for (int j = tid; j < 1024; j += 256) {
        float ang = -6.28318530717958647692f * (float)j * (1.0f / 2048.0f);
        twr[j] = cosf(ang);
        twi[j] = sinf(ang);
    }
}

// ---------------------------------------------------------------------------
// Per-batch irfft of G -> mean_value[b][t], scale 1/(2048*1024). grid = 16.
// ---------------------------------------------------------------------------
__global__ __launch_bounds__(256)
void irfft_mean(const float* __restrict__ G, float* __restrict__ mv) {
    __shared__ float zr[2048], zi[2048];
    __shared__ float twr[1024], twi[1024];
    const int tid = threadIdx.x;
    const int b = blockIdx.x;
    init_twiddle(twr, twi, tid);
    for (int f = tid; f < 2048; f += 256) {
        int g = (f <= 1024) ? f : 2048 - f;
        float gr = G[((size_t)b * 1025 + g) * 2 + 0];
        float gi = G[((size_t)b * 1025 + g) * 2 + 1];
        zr[f] = gr;
        zi[f] = (f <= 1024) ? -gi : gi;
    }
    __syncthreads();
    fft2048(zr, zi, twr, twi, tid);
    const float sc = 1.0f / (2048.0f * 1024.0f);
    for (int t = tid; t < 2048; t += 256) mv[b * 2048 + t] = zr[t] * sc;
}

// ---------------------------------------------------------------------------
// Top-7 over batch-mean + per-batch softmax (parallel argmax).
// ---------------------------------------------------------------------------
__global__ __launch_bounds__(256)
void topk_softmax(const float* __restrict__ mv, int* __restrict__ idx_out,
                  float* __restrict__ w_out) {
    __shared__ float cm[2048];
    __shared__ float wv4[4];
    __shared__ int   wi4[4];
    __shared__ int   sel[7];
    const int tid  = threadIdx.x;
    const int lane = tid & 63;
    const int wvid = tid >> 6;

    for (int t = tid; t < 2048; t += 256) {
        float s = 0.f;
        for (int b = 0; b < 16; ++b) s += mv[b * 2048 + t];
        cm[t] = s * (1.0f / 16.0f);
    }
    __syncthreads();

    for (int it = 0; it < 7; ++it) {
        float best = -3.4e38f; int bi = 1 << 30;
#pragma unroll
        for (int q = 0; q < 8; ++q) {
            const int t = tid + q * 256;
            float v = cm[t];
            if (v > best || (v == best && t < bi)) { best = v; bi = t; }
        }
#pragma unroll
        for (int off = 32; off > 0; off >>= 1) {
            float ov = __shfl_xor(best, off, 64);
            int   oi = __shfl_xor(bi,   off, 64);
            if (ov > best || (ov == best && oi < bi)) { best = ov; bi = oi; }
        }
        if (lane == 0) { wv4[wvid] = best; wi4[wvid] = bi; }
        __syncthreads();
        if (tid == 0) {
            float bb = wv4[0]; int bj = wi4[0];
#pragma unroll
            for (int u = 1; u < 4; ++u)
                if (wv4[u] > bb || (wv4[u] == bb && wi4[u] < bj)) { bb = wv4[u]; bj = wi4[u]; }
            sel[it] = bj;
            idx_out[it] = bj;
            cm[bj] = -3.4e38f;
        }
        __syncthreads();
    }

    if (tid < 16) {
        const int b = tid;
        float wv[7]; float mx = -3.4e38f;
#pragma unroll
        for (int i = 0; i < 7; ++i) { wv[i] = mv[b * 2048 + sel[i]]; mx = fmaxf(mx, wv[i]); }
        float s = 0.f;
#pragma unroll
        for (int i = 0; i < 7; ++i) { wv[i] = expf(wv[i] - mx); s += wv[i]; }
        float inv = 1.0f / s;
#pragma unroll
        for (int i = 0; i < 7; ++i) w_out[b * 7 + i] = wv[i] * inv;
    }
}

// ---------------------------------------------------------------------------
// agg[b,t,d] = bf16( sum_i w[b,i] * values[b,(t+idx[i])%2048,d] )  (fp32 in)
// ---------------------------------------------------------------------------
__global__ __launch_bounds__(256)
void agg_kernel(const float* __restrict__ vsrc, const int* __restrict__ idx,
                const float* __restrict__ w, unsigned short* __restrict__ agg) {
    const int b  = blockIdx.y;
    const int t  = blockIdx.x * 2 + (threadIdx.x >> 7);
    const int d8 = (threadIdx.x & 127) * 8;
    float av[8] = {0.f, 0.f, 0.f, 0.f, 0.f, 0.f, 0.f, 0.f};
#pragma unroll
    for (int i = 0; i < 7; ++i) {
        const int srow = (t + idx[i]) & 2047;
        const float wi = w[b * 7 + i];
        const float* src = vsrc + ((size_t)b * 2048 + srow) * 1024 + d8;
        f32x4 v0 = *(const f32x4*)src;
        f32x4 v1 = *(const f32x4*)(src + 4);
#pragma unroll
        for (int j = 0; j < 4; ++j) av[j] += wi * v0[j];
#pragma unroll
        for (int j = 0; j < 4; ++j) av[4 + j] += wi * v1[j];
    }
    bf16x8 o;
#pragma unroll
    for (int j = 0; j < 8; ++j) o[j] = (short)f2bf(av[j]);
    *(bf16x8*)&agg[((size_t)b * 2048 + t) * 1024 + d8] = o;
}

// ---------------------------------------------------------------------------
extern "C" void kernel_launch(void* const* d_in, const int* in_sizes, int n_in,
                              void* d_out, int out_size, void* d_ws, size_t ws_size,
                              hipStream_t stream) {
    const float* queries = (const float*)d_in[0];
    const float* keys    = (const float*)d_in[1];
    const float* values  = (const float*)d_in[2];
    const float* Wq = (const float*)d_in[3];
    const float* Wk = (const float*)d_in[5];
    const float* Wv = (const float*)d_in[7];  const float* bv = (const float*)d_in[8];
    const float* Wo = (const float*)d_in[9];  const float* bo = (const float*)d_in[10];
    float* out = (float*)d_out;

    char* ws = (char*)d_ws;
    constexpr size_t SZP = (size_t)32768 * 1024 * 2;           // 64 MB (bf16 B*L*D)
    unsigned short* agg = (unsigned short*)(ws);               // agg output [b][t][d]
    unsigned short* kt  = (unsigned short*)(ws + SZP);         // k~^T [b][d][t]
    unsigned short* qt  = (unsigned short*)(ws + 2 * SZP);     // q^T  [b][d][t]
    unsigned short* ab  = (unsigned short*)(ws + 3 * SZP);     // staging (64MB)
    unsigned short* wo  = ab;                                  // bf16 Wo
    unsigned short* wvT = ab + 1048576;                        // bf16 Wv^T
    unsigned short* wqT = ab + 2097152;                        // bf16 Wq^T
    unsigned short* wkT = ab + 3145728;                        // bf16 Wk^T
    unsigned short* W2  = (unsigned short*)(ws + 4 * SZP);     // bf16 Wo@Wv   [N][K]
    unsigned short* M   = W2 + 1048576;                        // bf16 Wq^T@Wk [N][K]
    char* tail = ws + 4 * SZP + 4194304;
    float* zb1024 = (float*)(tail);                            // 4KB zero bias
    float* b2     = (float*)(tail + 4096);
    float* G      = (float*)(tail + 8192);                     // 16*1025*2 f32
    float* mv     = (float*)(tail + 8192 + 131328);
    int*   idx    = (int*)  (tail + 8192 + 131328 + 131072);
    float* wsm    = (float*)(tail + 8192 + 131328 + 131072 + 64);

    // NOTE: weight temps (wo/wvT/wqT/wkT) live in ab[0..4M) while the key-cast
    // writes ab too -- but key-cast blocks write ab[i] for i >= 0. Conflict!
    // ab region is 32M elements; weight temps occupy first 4M elements. The
    // key-cast covers all of ab. To keep both in ONE launch, weight temps are
    // moved to a dedicated region after M (no overlap with ab).
    unsigned short* wtmp = M + 1048576;                        // 4 x 1M bf16
    wo  = wtmp;
    wvT = wtmp + 1048576;
    wqT = wtmp + 2097152;
    wkT = wtmp + 3145728;
    tail = ws + 4 * SZP + 4194304 + 8388608;
    zb1024 = (float*)(tail);
    b2     = (float*)(tail + 4096);
    G      = (float*)(tail + 8192);
    mv     = (float*)(tail + 8192 + 131328);
    idx    = (int*)  (tail + 8192 + 131328 + 131072);
    wsm    = (float*)(tail + 8192 + 131328 + 131072 + 64);

    // 1) ALL prep in one launch (inputs + weights + zeros + b2)
    prep_everything<<<25866, 256, 0, stream>>>(queries, keys, Wq, Wk, Wv, Wo, bv, bo,
                                               qt, ab, wo, wvT, wqT, wkT,
                                               G, zb1024, b2);
    // 2) W2 = Wo@Wv and M = Wq^T@Wk in one launch
    gemm_pair<<<32, 512, 0, stream>>>(wo, wvT, zb1024, W2,
                                      wqT, wkT, zb1024, M);
    // 3) k~ = k @ M^T (transposed out)
    gemm256<2><<<512, 512, 0, stream>>>(ab, M, zb1024, kt);

    // 4) correlation -> top-k -> aggregation -> fused output GEMM
    fft_corr<<<2048, 256, 0, stream>>>(qt, kt, G);
    irfft_mean<<<16, 256, 0, stream>>>(G, mv);
    topk_softmax<<<1, 256, 0, stream>>>(mv, idx, wsm);
    agg_kernel<<<dim3(1024, 16), 256, 0, stream>>>(values, idx, wsm, agg);
    gemm256<1><<<512, 512, 0, stream>>>(agg, W2, b2, out);
}

// Round 13
// 494.332 us; speedup vs baseline: 2.0645x; 1.0016x over previous
//
#include <hip/hip_runtime.h>

typedef __attribute__((ext_vector_type(8))) short bf16x8;
typedef __attribute__((ext_vector_type(4))) short s16x4;
typedef __attribute__((ext_vector_type(4))) float f32x4;

__device__ __forceinline__ float bf2f(unsigned short u) {
    union { unsigned int u; float f; } x; x.u = ((unsigned int)u) << 16; return x.f;
}
__device__ __forceinline__ unsigned short f2bf(float f) {
    union { float f; unsigned int u; } x; x.f = f;
    unsigned int u = x.u;
    unsigned int r = (u + 0x7fffu + ((u >> 16) & 1u)) >> 16;
    return (unsigned short)r;
}

#define GLDS16(gp, lp)                                                        \
    __builtin_amdgcn_global_load_lds(                                         \
        (const __attribute__((address_space(1))) void*)(gp),                  \
        (__attribute__((address_space(3))) void*)(lp), 16, 0, 0)

// ---------------------------------------------------------------------------
// GEMM body: C[M, N=1024] = A[M,K=1024] @ W^T + bias. A,W bf16 (W=[N,K]).
// 256x256 tile, BK=64, 8 waves, 128KB LDS dbuf, depth-2 prefetch, counted
// vmcnt(8), raw s_barrier, setprio, XOR-swizzled staging (verified conflicts=0).
// OUT_MODE: 0 = bf16 [row][col], 1 = f32 [row][col], 2 = bf16 transposed
//           [b][col][t] (row = b*2048+t).
// ---------------------------------------------------------------------------
template<int OUT_MODE>
__device__ __forceinline__
void gemm_body(const unsigned short* __restrict__ A, const unsigned short* __restrict__ Bw,
               const float* __restrict__ bias, void* __restrict__ out_,
               int bid, int nb, unsigned short* sAp, unsigned short* sBp) {
    const int tid  = threadIdx.x;
    const int lane = tid & 63;
    const int w    = tid >> 6;
    const int wr   = w >> 2, wc = w & 3;
    const int fr   = lane & 15, g4 = lane >> 4;

    const int qq  = nb >> 3;
    const int swz = qq ? (bid & 7) * qq + (bid >> 3) : bid;
    const int  col0 = (swz & 3) * 256;
    const long row0 = (long)(swz >> 2) * 256;

    const int srow = tid >> 3;
    const int sj   = (tid & 7) ^ (srow & 7);
    const unsigned short* gA = A  + (size_t)(row0 + srow) * 1024 + sj * 8;
    const unsigned short* gB = Bw + (size_t)(col0 + srow) * 1024 + sj * 8;
    const int ldst = w * 1024;

    auto stage = [&](int buf, int t) {
        const unsigned short* a = gA + t * 64;
        const unsigned short* b = gB + t * 64;
        char* dA = (char*)(sAp + buf * 16384);
        char* dB = (char*)(sBp + buf * 16384);
#pragma unroll
        for (int r = 0; r < 4; ++r)
            GLDS16(a + r * 65536, (__attribute__((address_space(3))) char*)(dA + r * 8192 + ldst));
#pragma unroll
        for (int r = 0; r < 4; ++r)
            GLDS16(b + r * 65536, (__attribute__((address_space(3))) char*)(dB + r * 8192 + ldst));
    };

    f32x4 acc[8][4];
#pragma unroll
    for (int m = 0; m < 8; ++m)
#pragma unroll
        for (int n = 0; n < 4; ++n) acc[m][n] = (f32x4){0.f, 0.f, 0.f, 0.f};

    stage(0, 0);
    stage(1, 1);

    const int mskK = (fr & 7) << 4;

    for (int t = 0; t < 16; ++t) {
        if (t < 15) asm volatile("s_waitcnt vmcnt(8)" ::: "memory");
        else        asm volatile("s_waitcnt vmcnt(0)" ::: "memory");
        asm volatile("s_barrier" ::: "memory");
        __builtin_amdgcn_sched_barrier(0);

        const char* la = (const char*)(sAp + (t & 1) * 16384);
        const char* lb = (const char*)(sBp + (t & 1) * 16384);

        bf16x8 bF[2][4];
#pragma unroll
        for (int c = 0; c < 2; ++c)
#pragma unroll
            for (int n = 0; n < 4; ++n) {
                const int row = wc * 64 + n * 16 + fr;
                bF[c][n] = *(const bf16x8*)(lb + row * 128 + ((c * 64 + g4 * 16) ^ mskK));
            }
#pragma unroll
        for (int mh = 0; mh < 2; ++mh) {
            bf16x8 aF[2][4];
#pragma unroll
            for (int c = 0; c < 2; ++c)
#pragma unroll
                for (int m = 0; m < 4; ++m) {
                    const int row = wr * 128 + mh * 64 + m * 16 + fr;
                    aF[c][m] = *(const bf16x8*)(la + row * 128 + ((c * 64 + g4 * 16) ^ mskK));
                }
            __builtin_amdgcn_s_setprio(1);
#pragma unroll
            for (int c = 0; c < 2; ++c)
#pragma unroll
                for (int n = 0; n < 4; ++n)
#pragma unroll
                    for (int m = 0; m < 4; ++m)
                        acc[mh * 4 + m][n] =
                            __builtin_amdgcn_mfma_f32_16x16x32_bf16(aF[c][m], bF[c][n], acc[mh * 4 + m][n], 0, 0, 0);
            __builtin_amdgcn_s_setprio(0);
        }

        __builtin_amdgcn_sched_barrier(0);
        asm volatile("s_barrier" ::: "memory");
        if (t + 2 < 16) stage(t & 1, t + 2);
    }

    const int cr = g4 * 4;
    const int cc = fr;
    if constexpr (OUT_MODE == 2) {
        const int b  = (int)(row0 >> 11);
        const int tb = ((int)row0 & 2047) + wr * 128 + cr;
#pragma unroll
        for (int m = 0; m < 8; ++m) {
#pragma unroll
            for (int n = 0; n < 4; ++n) {
                int col = col0 + wc * 64 + n * 16 + cc;
                float bv = bias[col];
                s16x4 o;
#pragma unroll
                for (int j = 0; j < 4; ++j) o[j] = (short)f2bf(acc[m][n][j] + bv);
                *(s16x4*)&((unsigned short*)out_)[((size_t)b * 1024 + col) * 2048 + tb + m * 16] = o;
            }
        }
    } else {
#pragma unroll
        for (int m = 0; m < 8; ++m) {
            long row = row0 + wr * 128 + m * 16 + cr;
#pragma unroll
            for (int n = 0; n < 4; ++n) {
                int col = col0 + wc * 64 + n * 16 + cc;
                float bv = bias[col];
#pragma unroll
                for (int j = 0; j < 4; ++j) {
                    float v = acc[m][n][j] + bv;
                    if constexpr (OUT_MODE == 1) ((float*)out_)[(row + j) * 1024 + col] = v;
                    else ((unsigned short*)out_)[(row + j) * 1024 + col] = f2bf(v);
                }
            }
        }
    }
}

template<int OUT_MODE>
__global__ __launch_bounds__(512, 2)
void gemm256(const unsigned short* __restrict__ A, const unsigned short* __restrict__ Bw,
             const float* __restrict__ bias, void* __restrict__ out_) {
    __shared__ __align__(16) unsigned short sA[2][16384];
    __shared__ __align__(16) unsigned short sB[2][16384];
    gemm_body<OUT_MODE>(A, Bw, bias, out_, blockIdx.x, gridDim.x, &sA[0][0], &sB[0][0]);
}

// two independent 1024x1024 GEMMs in one launch (grid = 32)
__global__ __launch_bounds__(512, 2)
void gemm_pair(const unsigned short* __restrict__ A0, const unsigned short* __restrict__ B0,
               const float* __restrict__ bias0, void* __restrict__ o0,
               const unsigned short* __restrict__ A1, const unsigned short* __restrict__ B1,
               const float* __restrict__ bias1, void* __restrict__ o1) {
    __shared__ __align__(16) unsigned short sA[2][16384];
    __shared__ __align__(16) unsigned short sB[2][16384];
    if (blockIdx.x < 16)
        gemm_body<0>(A0, B0, bias0, o0, blockIdx.x, 16, &sA[0][0], &sB[0][0]);
    else
        gemm_body<0>(A1, B1, bias1, o1, blockIdx.x - 16, 16, &sA[0][0], &sB[0][0]);
}

// ---------------------------------------------------------------------------
// prep_everything: ALL preprocessing in ONE launch. grid = 25866, block 256.
// Transpose writes are bf16x8 (16B/thread) -- 8x fewer store instructions
// than the scalar-ushort version (round-12 counter: 2.45 TB/s effective).
//  [0, 8192)      : qt[b][d][t] = bf16(queries[b][t][d])  (transpose-cast)
//  [8192, 24576)  : ab = bf16(keys)                        (straight cast)
//  [24576, 25344) : Wv/Wq/Wk transpose-cast -> wvT/wqT/wkT (768 blocks)
//  [25344, 25600) : Wo cast -> wo                          (256 blocks)
//  [25600, 25609) : zero G (32800 f32)
//  25609          : zero zb1024
//  [25610, 25866) : b2[n] = Wo[n,:]·bv + bo[n]             (256 blocks)
// ---------------------------------------------------------------------------
__global__ __launch_bounds__(256)
void prep_everything(const float* __restrict__ queries, const float* __restrict__ keys,
                     const float* __restrict__ Wq, const float* __restrict__ Wk,
                     const float* __restrict__ Wv, const float* __restrict__ Wo,
                     const float* __restrict__ bv, const float* __restrict__ bo,
                     unsigned short* __restrict__ qt, unsigned short* __restrict__ ab,
                     unsigned short* __restrict__ wo, unsigned short* __restrict__ wvT,
                     unsigned short* __restrict__ wqT, unsigned short* __restrict__ wkT,
                     float* __restrict__ G, float* __restrict__ zb, float* __restrict__ b2) {
    __shared__ float tsm[64][65];
    const int bx  = blockIdx.x;
    const int tid = threadIdx.x;

    if (bx < 8192) {
        // qt[b][d0+dl][t0+tl] = bf16(queries[b][t0+tl][d0+dl]); tsm[t][d]
        const int b   = bx >> 9;
        const int rem = bx & 511;
        const int t0  = (rem & 31) * 64;
        const int d0  = (rem >> 5) * 64;
        const int tx = tid & 63, ty = tid >> 6;
        const float* s = queries + ((size_t)b * 2048 + t0) * 1024 + d0;
        for (int r = ty; r < 64; r += 4)
            tsm[r][tx] = s[(size_t)r * 1024 + tx];
        __syncthreads();
        unsigned short* d = qt + ((size_t)b * 1024 + d0) * 2048 + t0;
        const int seg = tid & 7, rbase = tid >> 3;   // 8 t-segments x 32 d-rows
#pragma unroll
        for (int rr = 0; rr < 2; ++rr) {
            const int dl = rbase + rr * 32;
            bf16x8 o;
#pragma unroll
            for (int j = 0; j < 8; ++j) o[j] = (short)f2bf(tsm[seg * 8 + j][dl]);
            *(bf16x8*)(d + (size_t)dl * 2048 + seg * 8) = o;
        }
    } else if (bx < 24576) {
        const size_t i = ((size_t)(bx - 8192) * 256 + tid) * 8;
        f32x4 v0 = *(const f32x4*)(keys + i);
        f32x4 v1 = *(const f32x4*)(keys + i + 4);
        bf16x8 o;
#pragma unroll
        for (int j = 0; j < 4; ++j) o[j] = (short)f2bf(v0[j]);
#pragma unroll
        for (int j = 0; j < 4; ++j) o[4 + j] = (short)f2bf(v1[j]);
        *(bf16x8*)(ab + i) = o;
    } else if (bx < 25344) {
        // dst[b0+rl][by+cc] = bf16(src[by+cc][b0+rl]); tsm[srcrow][srccol]
        const int wx = bx - 24576;
        const float* src = (wx < 256) ? Wv : (wx < 512) ? Wq : Wk;
        unsigned short* dst = (wx < 256) ? wvT : (wx < 512) ? wqT : wkT;
        const int t  = wx & 255;
        const int b0 = (t & 15) * 64;
        const int by = (t >> 4) * 64;
        const int tx = tid & 63, ty = tid >> 6;
        for (int r = ty; r < 64; r += 4)
            tsm[r][tx] = src[(size_t)(by + r) * 1024 + b0 + tx];
        __syncthreads();
        const int seg = tid & 7, rbase = tid >> 3;
#pragma unroll
        for (int rr = 0; rr < 2; ++rr) {
            const int rl = rbase + rr * 32;
            bf16x8 o;
#pragma unroll
            for (int j = 0; j < 8; ++j) o[j] = (short)f2bf(tsm[seg * 8 + j][rl]);
            *(bf16x8*)(dst + (size_t)(b0 + rl) * 1024 + by + seg * 8) = o;
        }
    } else if (bx < 25600) {
        const int base = (bx - 25344) * 4096 + tid * 4;
#pragma unroll
        for (int r = 0; r < 4; ++r) {
            const int i = base + r * 1024;
            f32x4 v = *(const f32x4*)(Wo + i);
            s16x4 o;
#pragma unroll
            for (int j = 0; j < 4; ++j) o[j] = (short)f2bf(v[j]);
            *(s16x4*)(wo + i) = o;
        }
    } else if (bx < 25609) {
        const int base = (bx - 25600) * 4096;
#pragma unroll
        for (int r = 0; r < 16; ++r) {
            const int i = base + r * 256 + tid;
            if (i < 32800) G[i] = 0.0f;
        }
    } else if (bx == 25609) {
        *(f32x4*)(zb + tid * 4) = (f32x4){0.f, 0.f, 0.f, 0.f};
    } else {
        const int n = (bx - 25610) * 4 + (tid >> 6);
        const int lane = tid & 63;
        float s = 0.f;
        for (int k = lane; k < 1024; k += 64) s += Wo[(size_t)n * 1024 + k] * bv[k];
#pragma unroll
        for (int off = 32; off > 0; off >>= 1) s += __shfl_xor(s, off, 64);
        if (lane == 0) b2[n] = s + bo[n];
    }
}

// ---------------------------------------------------------------------------
// 8-point DFT (negative exponent), in place on xr/xi[8].
// ---------------------------------------------------------------------------
__device__ __forceinline__ void dft8(float* xr, float* xi) {
    const float c8 = 0.70710678118654752440f;
    float es0r = xr[0] + xr[4], es0i = xi[0] + xi[4];
    float es1r = xr[0] - xr[4], es1i = xi[0] - xi[4];
    float es2r = xr[2] + xr[6], es2i = xi[2] + xi[6];
    float es3r = xr[2] - xr[6], es3i = xi[2] - xi[6];
    float E0r = es0r + es2r, E0i = es0i + es2i;
    float E2r = es0r - es2r, E2i = es0i - es2i;
    float E1r = es1r + es3i, E1i = es1i - es3r;
    float E3r = es1r - es3i, E3i = es1i + es3r;
    float os0r = xr[1] + xr[5], os0i = xi[1] + xi[5];
    float os1r = xr[1] - xr[5], os1i = xi[1] - xi[5];
    float os2r = xr[3] + xr[7], os2i = xi[3] + xi[7];
    float os3r = xr[3] - xr[7], os3i = xi[3] - xi[7];
    float O0r = os0r + os2r, O0i = os0i + os2i;
    float O2r = os0r - os2r, O2i = os0i - os2i;
    float O1r = os1r + os3i, O1i = os1i - os3r;
    float O3r = os1r - os3i, O3i = os1i + os3r;
    float p1 = c8 * (O1r + O1i), q1 = c8 * (O1i - O1r);
    float p3 = c8 * (O3r + O3i), q3 = c8 * (O3i - O3r);
    xr[0] = E0r + O0r; xi[0] = E0i + O0i;
    xr[4] = E0r - O0r; xi[4] = E0i - O0i;
    xr[1] = E1r + p1;  xi[1] = E1i + q1;
    xr[5] = E1r - p1;  xi[5] = E1i - q1;
    xr[2] = E2r + O2i; xi[2] = E2i - O2r;
    xr[6] = E2r - O2i; xi[6] = E2i + O2r;
    xr[3] = E3r + q3;  xi[3] = E3i - p3;
    xr[7] = E3r - q3;  xi[7] = E3i + p3;
}

__device__ __forceinline__ int padc(int p) { return p + (p >> 5); }

// apply W^{k} chain (base wr_,wi_) to both streams a and b
#define TWIDDLE2(wr_, wi_)                                                    \
    {                                                                         \
        float cr_ = (wr_), ci_ = (wi_);                                       \
        _Pragma("unroll")                                                     \
        for (int k = 1; k < 8; ++k) {                                         \
            float t0 = ar[k] * cr_ - ai[k] * ci_;                             \
            float t1 = ar[k] * ci_ + ai[k] * cr_;                             \
            ar[k] = t0; ai[k] = t1;                                           \
            float t2 = br[k] * cr_ - bi[k] * ci_;                             \
            float t3 = br[k] * ci_ + bi[k] * cr_;                             \
            br[k] = t2; bi[k] = t3;                                           \
            if (k < 7) {                                                      \
                float nr = cr_ * (wr_) - ci_ * (wi_);                         \
                float ni = cr_ * (wi_) + ci_ * (wr_);                         \
                cr_ = nr; ci_ = ni;                                           \
            }                                                                 \
        }                                                                     \
    }

// ---------------------------------------------------------------------------
// fft_corr (round-12 verified: structural floor at ~116us for this
// decomposition). Dual-column batching, register accumulators, float2+padc,
// 4 barriers per iteration (R2->R3 and R3->R4 are intra-wave).
// grid = 2048 (16 b x 128 chunks), block = 256.
// ---------------------------------------------------------------------------
__global__ __launch_bounds__(256)
void fft_corr(const unsigned short* __restrict__ qt, const unsigned short* __restrict__ kt,
              float* __restrict__ G) {
    __shared__ float2 za[2112];
    __shared__ float2 zb[2112];
    float* zfr0 = (float*)za; float* zfi0 = zfr0 + 2112;
    float* zfr1 = (float*)zb; float* zfi1 = zfr1 + 2112;
    const int tid = threadIdx.x;
    const int b = blockIdx.x >> 7;
    const int chunk = blockIdx.x & 127;

    const float N2PI = -6.28318530717958647692f;
    float w1r, w1i, w2r, w2i, w3r, w3i;
    {
        float s, c;
        __sincosf(N2PI * (float)tid * (1.0f / 2048.0f), &s, &c); w1r = c; w1i = s;
        __sincosf(N2PI * (float)(tid & 31) * (1.0f / 256.0f), &s, &c); w2r = c; w2i = s;
        __sincosf(N2PI * (float)(tid & 3) * (1.0f / 32.0f),  &s, &c); w3r = c; w3i = s;
    }

    float aR0 = 0.f, aI0 = 0.f, aR1 = 0.f, aI1 = 0.f;
    float aR2 = 0.f, aI2 = 0.f, aR3 = 0.f, aI3 = 0.f, aR4 = 0.f;

    const int beta = tid >> 5, s2 = tid & 31;
    const int gam  = tid >> 2, u3 = tid & 3;

    for (int it = 0; it < 4; ++it) {
        const int d0 = chunk * 8 + it * 2;
        const unsigned short* q0 = qt + ((size_t)b * 1024 + d0) * 2048;
        const unsigned short* k0 = kt + ((size_t)b * 1024 + d0) * 2048;
        const unsigned short* q1 = q0 + 2048;
        const unsigned short* k1 = k0 + 2048;

        float ar[8], ai[8], br[8], bi[8];
#pragma unroll
        for (int k = 0; k < 8; ++k) {
            ar[k] = bf2f(q0[tid + 256 * k]); ai[k] = bf2f(k0[tid + 256 * k]);
            br[k] = bf2f(q1[tid + 256 * k]); bi[k] = bf2f(k1[tid + 256 * k]);
        }
        dft8(ar, ai); dft8(br, bi);
        TWIDDLE2(w1r, w1i)
#pragma unroll
        for (int k = 0; k < 8; ++k) {
            const int p = padc(256 * k + tid);
            za[p] = make_float2(ar[k], ai[k]);
            zb[p] = make_float2(br[k], bi[k]);
        }
        __syncthreads();   // R1 writers cross-wave: barrier REQUIRED

#pragma unroll
        for (int k = 0; k < 8; ++k) {
            const int p = padc(256 * beta + 32 * k + s2);
            float2 va = za[p]; ar[k] = va.x; ai[k] = va.y;
            float2 vb = zb[p]; br[k] = vb.x; bi[k] = vb.y;
        }
        dft8(ar, ai); dft8(br, bi);
        TWIDDLE2(w2r, w2i)
#pragma unroll
        for (int k = 0; k < 8; ++k) {
            const int p = padc(256 * beta + 32 * k + s2);
            za[p] = make_float2(ar[k], ai[k]);
            zb[p] = make_float2(br[k], bi[k]);
        }
        // NO barrier: R3's reads come from its own wave's R2 writes.

#pragma unroll
        for (int k = 0; k < 8; ++k) {
            const int p = padc(32 * gam + 4 * k + u3);
            float2 va = za[p]; ar[k] = va.x; ai[k] = va.y;
            float2 vb = zb[p]; br[k] = vb.x; bi[k] = vb.y;
        }
        dft8(ar, ai); dft8(br, bi);
        TWIDDLE2(w3r, w3i)
#pragma unroll
        for (int k = 0; k < 8; ++k) {
            const int p = padc(32 * gam + 4 * k + u3);
            za[p] = make_float2(ar[k], ai[k]);
            zb[p] = make_float2(br[k], bi[k]);
        }
        // NO barrier: R4 reads its own 4-lane group's R3 writes.

#pragma unroll
        for (int k = 0; k < 8; ++k) {
            const int p = padc(8 * tid + k);
            float2 va = za[p]; ar[k] = va.x; ai[k] = va.y;
            float2 vb = zb[p]; br[k] = vb.x; bi[k] = vb.y;
        }
        __syncthreads();   // anti-dep: scatter overwrites other waves' R4 reads

#pragma unroll
        for (int blk = 0; blk < 2; ++blk) {
            const int o = 4 * blk;
            {
                float s0r = ar[o] + ar[o + 2], s0i = ai[o] + ai[o + 2];
                float s1r = ar[o] - ar[o + 2], s1i = ai[o] - ai[o + 2];
                float s2r = ar[o + 1] + ar[o + 3], s2i = ai[o + 1] + ai[o + 3];
                float s3r = ar[o + 1] - ar[o + 3], s3i = ai[o + 1] - ai[o + 3];
                ar[o + 0] = s0r + s2r; ai[o + 0] = s0i + s2i;
                ar[o + 2] = s0r - s2r; ai[o + 2] = s0i - s2i;
                ar[o + 1] = s1r + s3i; ai[o + 1] = s1i - s3r;
                ar[o + 3] = s1r - s3i; ai[o + 3] = s1i + s3r;
            }
            {
                float s0r = br[o] + br[o + 2], s0i = bi[o] + bi[o + 2];
                float s1r = br[o] - br[o + 2], s1i = bi[o] - bi[o + 2];
                float s2r = br[o + 1] + br[o + 3], s2i = bi[o + 1] + bi[o + 3];
                float s3r = br[o + 1] - br[o + 3], s3i = bi[o + 1] - bi[o + 3];
                br[o + 0] = s0r + s2r; bi[o + 0] = s0i + s2i;
                br[o + 2] = s0r - s2r; bi[o + 2] = s0i - s2i;
                br[o + 1] = s1r + s3i; bi[o + 1] = s1i - s3r;
                br[o + 3] = s1r - s3i; bi[o + 3] = s1i + s3r;
            }
        }
        {
            const int k1d = tid >> 5;
            const int k2d = (tid >> 2) & 7;
            const int fb = k1d + 8 * k2d;
#pragma unroll
            for (int blk = 0; blk < 2; ++blk) {
                const int k3d = (2 * (tid & 3) + blk) & 7;
#pragma unroll
                for (int k4 = 0; k4 < 4; ++k4) {
                    const int f = fb + 64 * k3d + 512 * k4;
                    const int pf = padc(f);
                    zfr0[pf] = ar[4 * blk + k4]; zfi0[pf] = ai[4 * blk + k4];
                    zfr1[pf] = br[4 * blk + k4]; zfi1[pf] = bi[4 * blk + k4];
                }
            }
        }
        __syncthreads();   // scatter writers cross-wave before Hermitian reads

        // Hermitian split + accumulate (registers)
#pragma unroll
        for (int k = 0; k < 4; ++k) {
            const int f = tid + 256 * k;
            const int f2 = (2048 - f) & 2047;
            const int pf = padc(f), pf2 = padc(f2);
            float Zr = zfr0[pf],  Zi = zfi0[pf];
            float Yr = zfr0[pf2], Yi = -zfi0[pf2];
            float Qr = 0.5f * (Zr + Yr), Qi = 0.5f * (Zi + Yi);
            float Kr = 0.5f * (Zi - Yi), Ki = -0.5f * (Zr - Yr);
            float dR = Qr * Kr + Qi * Ki;
            float dI = Qi * Kr - Qr * Ki;
            Zr = zfr1[pf];  Zi = zfi1[pf];
            Yr = zfr1[pf2]; Yi = -zfi1[pf2];
            Qr = 0.5f * (Zr + Yr); Qi = 0.5f * (Zi + Yi);
            Kr = 0.5f * (Zi - Yi); Ki = -0.5f * (Zr - Yr);
            dR += Qr * Kr + Qi * Ki;
            dI += Qi * Kr - Qr * Ki;
            if      (k == 0) { aR0 += dR; aI0 += dI; }
            else if (k == 1) { aR1 += dR; aI1 += dI; }
            else if (k == 2) { aR2 += dR; aI2 += dI; }
            else             { aR3 += dR; aI3 += dI; }
        }
        if (tid == 0) {   // f = 1024: Q = Re(Z), K = Im(Z), P imag = 0
            const int pf = padc(1024);
            aR4 += zfr0[pf] * zfi0[pf] + zfr1[pf] * zfi1[pf];
        }
        __syncthreads();   // anti-dep: next iteration's R1 writes
    }

    atomicAdd(&G[((size_t)b * 1025 + tid +   0) * 2 + 0], aR0);
    atomicAdd(&G[((size_t)b * 1025 + tid +   0) * 2 + 1], aI0);
    atomicAdd(&G[((size_t)b * 1025 + tid + 256) * 2 + 0], aR1);
    atomicAdd(&G[((size_t)b * 1025 + tid + 256) * 2 + 1], aI1);
    atomicAdd(&G[((size_t)b * 1025 + tid + 512) * 2 + 0], aR2);
    atomicAdd(&G[((size_t)b * 1025 + tid + 512) * 2 + 1], aI2);
    atomicAdd(&G[((size_t)b * 1025 + tid + 768) * 2 + 0], aR3);
    atomicAdd(&G[((size_t)b * 1025 + tid + 768) * 2 + 1], aI3);
    if (tid == 0)
        atomicAdd(&G[((size_t)b * 1025 + 1024) * 2 + 0], aR4);
}

// ---------------------------------------------------------------------------
// In-LDS radix-2 DIT FFT, N=2048 (only used by irfft_mean: 16 blocks, cheap).
// ---------------------------------------------------------------------------
__device__ __forceinline__ void fft2048(float* zr, float* zi,
                                        const float* twr, const float* twi, int tid) {
    for (int t = tid; t < 2048; t += 256) {
        int j = __brev((unsigned)t) >> 21;
        if (j > t) {
            float a = zr[t]; zr[t] = zr[j]; zr[j] = a;
            float c = zi[t]; zi[t] = zi[j]; zi[j] = c;
        }
    }
    __syncthreads();
    for (int s = 0; s < 11; ++s) {
        const int m = 1 << s;
        for (int i = tid; i < 1024; i += 256) {
            const int pos = i & (m - 1);
            const int i1  = ((i >> s) << (s + 1)) + pos;
            const int i2  = i1 + m;
            const int tw  = pos << (10 - s);
            float wr = twr[tw], wi = twi[tw];
            float xr = zr[i2], xi = zi[i2];
            float tr = wr * xr - wi * xi;
            float ti = wr * xi + wi * xr;
            float ur = zr[i1], ui = zi[i1];
            zr[i2] = ur - tr; zi[i2] = ui - ti;
            zr[i1] = ur + tr; zi[i1] = ui + ti;
        }
        __syncthreads();
    }
}

__device__ __forceinline__ void init_twiddle(float* twr, float* twi, int tid) {
    for (int j = tid; j < 1024; j += 256) {
        float ang = -6.28318530717958647692f * (float)j * (1.0f / 2048.0f);
        twr[j] = cosf(ang);
        twi[j] = sinf(ang);
    }
}

// ---------------------------------------------------------------------------
// Per-batch irfft of G -> mean_value[b][t], scale 1/(2048*1024). grid = 16.
// ---------------------------------------------------------------------------
__global__ __launch_bounds__(256)
void irfft_mean(const float* __restrict__ G, float* __restrict__ mv) {
    __shared__ float zr[2048], zi[2048];
    __shared__ float twr[1024], twi[1024];
    const int tid = threadIdx.x;
    const int b = blockIdx.x;
    init_twiddle(twr, twi, tid);
    for (int f = tid; f < 2048; f += 256) {
        int g = (f <= 1024) ? f : 2048 - f;
        float gr = G[((size_t)b * 1025 + g) * 2 + 0];
        float gi = G[((size_t)b * 1025 + g) * 2 + 1];
        zr[f] = gr;
        zi[f] = (f <= 1024) ? -gi : gi;
    }
    __syncthreads();
    fft2048(zr, zi, twr, twi, tid);
    const float sc = 1.0f / (2048.0f * 1024.0f);
    for (int t = tid; t < 2048; t += 256) mv[b * 2048 + t] = zr[t] * sc;
}

// ---------------------------------------------------------------------------
// Top-7 over batch-mean + per-batch softmax (parallel argmax).
// ---------------------------------------------------------------------------
__global__ __launch_bounds__(256)
void topk_softmax(const float* __restrict__ mv, int* __restrict__ idx_out,
                  float* __restrict__ w_out) {
    __shared__ float cm[2048];
    __shared__ float wv4[4];
    __shared__ int   wi4[4];
    __shared__ int   sel[7];
    const int tid  = threadIdx.x;
    const int lane = tid & 63;
    const int wvid = tid >> 6;

    for (int t = tid; t < 2048; t += 256) {
        float s = 0.f;
        for (int b = 0; b < 16; ++b) s += mv[b * 2048 + t];
        cm[t] = s * (1.0f / 16.0f);
    }
    __syncthreads();

    for (int it = 0; it < 7; ++it) {
        float best = -3.4e38f; int bi = 1 << 30;
#pragma unroll
        for (int q = 0; q < 8; ++q) {
            const int t = tid + q * 256;
            float v = cm[t];
            if (v > best || (v == best && t < bi)) { best = v; bi = t; }
        }
#pragma unroll
        for (int off = 32; off > 0; off >>= 1) {
            float ov = __shfl_xor(best, off, 64);
            int   oi = __shfl_xor(bi,   off, 64);
            if (ov > best || (ov == best && oi < bi)) { best = ov; bi = oi; }
        }
        if (lane == 0) { wv4[wvid] = best; wi4[wvid] = bi; }
        __syncthreads();
        if (tid == 0) {
            float bb = wv4[0]; int bj = wi4[0];
#pragma unroll
            for (int u = 1; u < 4; ++u)
                if (wv4[u] > bb || (wv4[u] == bb && wi4[u] < bj)) { bb = wv4[u]; bj = wi4[u]; }
            sel[it] = bj;
            idx_out[it] = bj;
            cm[bj] = -3.4e38f;
        }
        __syncthreads();
    }

    if (tid < 16) {
        const int b = tid;
        float wv[7]; float mx = -3.4e38f;
#pragma unroll
        for (int i = 0; i < 7; ++i) { wv[i] = mv[b * 2048 + sel[i]]; mx = fmaxf(mx, wv[i]); }
        float s = 0.f;
#pragma unroll
        for (int i = 0; i < 7; ++i) { wv[i] = expf(wv[i] - mx); s += wv[i]; }
        float inv = 1.0f / s;
#pragma unroll
        for (int i = 0; i < 7; ++i) w_out[b * 7 + i] = wv[i] * inv;
    }
}

// ---------------------------------------------------------------------------
// agg[b,t,d] = bf16( sum_i w[b,i] * values[b,(t+idx[i])%2048,d] )  (fp32 in)
// ---------------------------------------------------------------------------
__global__ __launch_bounds__(256)
void agg_kernel(const float* __restrict__ vsrc, const int* __restrict__ idx,
                const float* __restrict__ w, unsigned short* __restrict__ agg) {
    const int b  = blockIdx.y;
    const int t  = blockIdx.x * 2 + (threadIdx.x >> 7);
    const int d8 = (threadIdx.x & 127) * 8;
    float av[8] = {0.f, 0.f, 0.f, 0.f, 0.f, 0.f, 0.f, 0.f};
#pragma unroll
    for (int i = 0; i < 7; ++i) {
        const int srow = (t + idx[i]) & 2047;
        const float wi = w[b * 7 + i];
        const float* src = vsrc + ((size_t)b * 2048 + srow) * 1024 + d8;
        f32x4 v0 = *(const f32x4*)src;
        f32x4 v1 = *(const f32x4*)(src + 4);
#pragma unroll
        for (int j = 0; j < 4; ++j) av[j] += wi * v0[j];
#pragma unroll
        for (int j = 0; j < 4; ++j) av[4 + j] += wi * v1[j];
    }
    bf16x8 o;
#pragma unroll
    for (int j = 0; j < 8; ++j) o[j] = (short)f2bf(av[j]);
    *(bf16x8*)&agg[((size_t)b * 2048 + t) * 1024 + d8] = o;
}

// ---------------------------------------------------------------------------
extern "C" void kernel_launch(void* const* d_in, const int* in_sizes, int n_in,
                              void* d_out, int out_size, void* d_ws, size_t ws_size,
                              hipStream_t stream) {
    const float* queries = (const float*)d_in[0];
    const float* keys    = (const float*)d_in[1];
    const float* values  = (const float*)d_in[2];
    const float* Wq = (const float*)d_in[3];
    const float* Wk = (const float*)d_in[5];
    const float* Wv = (const float*)d_in[7];  const float* bv = (const float*)d_in[8];
    const float* Wo = (const float*)d_in[9];  const float* bo = (const float*)d_in[10];
    float* out = (float*)d_out;

    char* ws = (char*)d_ws;
    constexpr size_t SZP = (size_t)32768 * 1024 * 2;           // 64 MB (bf16 B*L*D)
    unsigned short* agg = (unsigned short*)(ws);               // agg output [b][t][d]
    unsigned short* kt  = (unsigned short*)(ws + SZP);         // k~^T [b][d][t]
    unsigned short* qt  = (unsigned short*)(ws + 2 * SZP);     // q^T  [b][d][t]
    unsigned short* ab  = (unsigned short*)(ws + 3 * SZP);     // staging (64MB)
    unsigned short* W2  = (unsigned short*)(ws + 4 * SZP);     // bf16 Wo@Wv   [N][K]
    unsigned short* M   = W2 + 1048576;                        // bf16 Wq^T@Wk [N][K]
    unsigned short* wtmp = M + 1048576;                        // 4 x 1M bf16 weight temps
    unsigned short* wo  = wtmp;
    unsigned short* wvT = wtmp + 1048576;
    unsigned short* wqT = wtmp + 2097152;
    unsigned short* wkT = wtmp + 3145728;
    char* tail = ws + 4 * SZP + 4194304 + 8388608;
    float* zb1024 = (float*)(tail);                            // 4KB zero bias
    float* b2     = (float*)(tail + 4096);
    float* G      = (float*)(tail + 8192);                     // 16*1025*2 f32
    float* mv     = (float*)(tail + 8192 + 131328);
    int*   idx    = (int*)  (tail + 8192 + 131328 + 131072);
    float* wsm    = (float*)(tail + 8192 + 131328 + 131072 + 64);

    // 1) ALL prep in one launch (inputs + weights + zeros + b2)
    prep_everything<<<25866, 256, 0, stream>>>(queries, keys, Wq, Wk, Wv, Wo, bv, bo,
                                               qt, ab, wo, wvT, wqT, wkT,
                                               G, zb1024, b2);
    // 2) W2 = Wo@Wv and M = Wq^T@Wk in one launch
    gemm_pair<<<32, 512, 0, stream>>>(wo, wvT, zb1024, W2,
                                      wqT, wkT, zb1024, M);
    // 3) k~ = k @ M^T (transposed out)
    gemm256<2><<<512, 512, 0, stream>>>(ab, M, zb1024, kt);

    // 4) correlation -> top-k -> aggregation -> fused output GEMM
    fft_corr<<<2048, 256, 0, stream>>>(qt, kt, G);
    irfft_mean<<<16, 256, 0, stream>>>(G, mv);
    topk_softmax<<<1, 256, 0, stream>>>(mv, idx, wsm);
    agg_kernel<<<dim3(1024, 16), 256, 0, stream>>>(values, idx, wsm, agg);
    gemm256<1><<<512, 512, 0, stream>>>(agg, W2, b2, out);
}

// Round 14
// 492.396 us; speedup vs baseline: 2.0726x; 1.0039x over previous
//
#include <hip/hip_runtime.h>

typedef __attribute__((ext_vector_type(8))) short bf16x8;
typedef __attribute__((ext_vector_type(4))) short s16x4;
typedef __attribute__((ext_vector_type(4))) float f32x4;

__device__ __forceinline__ float bf2f(unsigned short u) {
    union { unsigned int u; float f; } x; x.u = ((unsigned int)u) << 16; return x.f;
}
__device__ __forceinline__ unsigned short f2bf(float f) {
    union { float f; unsigned int u; } x; x.f = f;
    unsigned int u = x.u;
    unsigned int r = (u + 0x7fffu + ((u >> 16) & 1u)) >> 16;
    return (unsigned short)r;
}

#define GLDS16(gp, lp)                                                        \
    __builtin_amdgcn_global_load_lds(                                         \
        (const __attribute__((address_space(1))) void*)(gp),                  \
        (__attribute__((address_space(3))) void*)(lp), 16, 0, 0)

// ---------------------------------------------------------------------------
// GEMM body: C[M, N=1024] = A[M,K=1024] @ W^T + bias. A,W bf16 (W=[N,K]).
// 256x256 tile, BK=64, 8 waves, 128KB LDS dbuf, depth-2 prefetch, counted
// vmcnt(8), raw s_barrier, setprio, XOR-swizzled staging (verified conflicts=0).
// OUT_MODE: 0 = bf16 [row][col], 1 = f32 [row][col], 2 = bf16 transposed
//           [b][col][t] (row = b*2048+t).
// ---------------------------------------------------------------------------
template<int OUT_MODE>
__device__ __forceinline__
void gemm_body(const unsigned short* __restrict__ A, const unsigned short* __restrict__ Bw,
               const float* __restrict__ bias, void* __restrict__ out_,
               int bid, int nb, unsigned short* sAp, unsigned short* sBp) {
    const int tid  = threadIdx.x;
    const int lane = tid & 63;
    const int w    = tid >> 6;
    const int wr   = w >> 2, wc = w & 3;
    const int fr   = lane & 15, g4 = lane >> 4;

    const int qq  = nb >> 3;
    const int swz = qq ? (bid & 7) * qq + (bid >> 3) : bid;
    const int  col0 = (swz & 3) * 256;
    const long row0 = (long)(swz >> 2) * 256;

    const int srow = tid >> 3;
    const int sj   = (tid & 7) ^ (srow & 7);
    const unsigned short* gA = A  + (size_t)(row0 + srow) * 1024 + sj * 8;
    const unsigned short* gB = Bw + (size_t)(col0 + srow) * 1024 + sj * 8;
    const int ldst = w * 1024;

    auto stage = [&](int buf, int t) {
        const unsigned short* a = gA + t * 64;
        const unsigned short* b = gB + t * 64;
        char* dA = (char*)(sAp + buf * 16384);
        char* dB = (char*)(sBp + buf * 16384);
#pragma unroll
        for (int r = 0; r < 4; ++r)
            GLDS16(a + r * 65536, (__attribute__((address_space(3))) char*)(dA + r * 8192 + ldst));
#pragma unroll
        for (int r = 0; r < 4; ++r)
            GLDS16(b + r * 65536, (__attribute__((address_space(3))) char*)(dB + r * 8192 + ldst));
    };

    f32x4 acc[8][4];
#pragma unroll
    for (int m = 0; m < 8; ++m)
#pragma unroll
        for (int n = 0; n < 4; ++n) acc[m][n] = (f32x4){0.f, 0.f, 0.f, 0.f};

    stage(0, 0);
    stage(1, 1);

    const int mskK = (fr & 7) << 4;

    for (int t = 0; t < 16; ++t) {
        if (t < 15) asm volatile("s_waitcnt vmcnt(8)" ::: "memory");
        else        asm volatile("s_waitcnt vmcnt(0)" ::: "memory");
        asm volatile("s_barrier" ::: "memory");
        __builtin_amdgcn_sched_barrier(0);

        const char* la = (const char*)(sAp + (t & 1) * 16384);
        const char* lb = (const char*)(sBp + (t & 1) * 16384);

        bf16x8 bF[2][4];
#pragma unroll
        for (int c = 0; c < 2; ++c)
#pragma unroll
            for (int n = 0; n < 4; ++n) {
                const int row = wc * 64 + n * 16 + fr;
                bF[c][n] = *(const bf16x8*)(lb + row * 128 + ((c * 64 + g4 * 16) ^ mskK));
            }
#pragma unroll
        for (int mh = 0; mh < 2; ++mh) {
            bf16x8 aF[2][4];
#pragma unroll
            for (int c = 0; c < 2; ++c)
#pragma unroll
                for (int m = 0; m < 4; ++m) {
                    const int row = wr * 128 + mh * 64 + m * 16 + fr;
                    aF[c][m] = *(const bf16x8*)(la + row * 128 + ((c * 64 + g4 * 16) ^ mskK));
                }
            __builtin_amdgcn_s_setprio(1);
#pragma unroll
            for (int c = 0; c < 2; ++c)
#pragma unroll
                for (int n = 0; n < 4; ++n)
#pragma unroll
                    for (int m = 0; m < 4; ++m)
                        acc[mh * 4 + m][n] =
                            __builtin_amdgcn_mfma_f32_16x16x32_bf16(aF[c][m], bF[c][n], acc[mh * 4 + m][n], 0, 0, 0);
            __builtin_amdgcn_s_setprio(0);
        }

        __builtin_amdgcn_sched_barrier(0);
        asm volatile("s_barrier" ::: "memory");
        if (t + 2 < 16) stage(t & 1, t + 2);
    }

    const int cr = g4 * 4;
    const int cc = fr;
    if constexpr (OUT_MODE == 2) {
        const int b  = (int)(row0 >> 11);
        const int tb = ((int)row0 & 2047) + wr * 128 + cr;
#pragma unroll
        for (int m = 0; m < 8; ++m) {
#pragma unroll
            for (int n = 0; n < 4; ++n) {
                int col = col0 + wc * 64 + n * 16 + cc;
                float bv = bias[col];
                s16x4 o;
#pragma unroll
                for (int j = 0; j < 4; ++j) o[j] = (short)f2bf(acc[m][n][j] + bv);
                *(s16x4*)&((unsigned short*)out_)[((size_t)b * 1024 + col) * 2048 + tb + m * 16] = o;
            }
        }
    } else {
#pragma unroll
        for (int m = 0; m < 8; ++m) {
            long row = row0 + wr * 128 + m * 16 + cr;
#pragma unroll
            for (int n = 0; n < 4; ++n) {
                int col = col0 + wc * 64 + n * 16 + cc;
                float bv = bias[col];
#pragma unroll
                for (int j = 0; j < 4; ++j) {
                    float v = acc[m][n][j] + bv;
                    if constexpr (OUT_MODE == 1) ((float*)out_)[(row + j) * 1024 + col] = v;
                    else ((unsigned short*)out_)[(row + j) * 1024 + col] = f2bf(v);
                }
            }
        }
    }
}

template<int OUT_MODE>
__global__ __launch_bounds__(512, 2)
void gemm256(const unsigned short* __restrict__ A, const unsigned short* __restrict__ Bw,
             const float* __restrict__ bias, void* __restrict__ out_) {
    __shared__ __align__(16) unsigned short sA[2][16384];
    __shared__ __align__(16) unsigned short sB[2][16384];
    gemm_body<OUT_MODE>(A, Bw, bias, out_, blockIdx.x, gridDim.x, &sA[0][0], &sB[0][0]);
}

// two independent 1024x1024 GEMMs in one launch (grid = 32)
__global__ __launch_bounds__(512, 2)
void gemm_pair(const unsigned short* __restrict__ A0, const unsigned short* __restrict__ B0,
               const float* __restrict__ bias0, void* __restrict__ o0,
               const unsigned short* __restrict__ A1, const unsigned short* __restrict__ B1,
               const float* __restrict__ bias1, void* __restrict__ o1) {
    __shared__ __align__(16) unsigned short sA[2][16384];
    __shared__ __align__(16) unsigned short sB[2][16384];
    if (blockIdx.x < 16)
        gemm_body<0>(A0, B0, bias0, o0, blockIdx.x, 16, &sA[0][0], &sB[0][0]);
    else
        gemm_body<0>(A1, B1, bias1, o1, blockIdx.x - 16, 16, &sA[0][0], &sB[0][0]);
}

// ---------------------------------------------------------------------------
// prep_everything: ALL preprocessing in ONE launch. grid = 21770, block 256.
// q-transpose tile is 128t x 64d: each qt d-row written as 256B contiguous
// (round-13 counter: write-side limited at 1.2 TB/s with 128B chunks).
//  [0, 4096)      : qt[b][d][t] = bf16(queries[b][t][d])  (128x64 tiles)
//  [4096, 20480)  : ab = bf16(keys)                        (straight cast)
//  [20480, 21248) : Wv/Wq/Wk transpose-cast -> wvT/wqT/wkT (768 blocks)
//  [21248, 21504) : Wo cast -> wo                          (256 blocks)
//  [21504, 21513) : zero G (32800 f32)
//  21513          : zero zb1024
//  [21514, 21770) : b2[n] = Wo[n,:]·bv + bo[n]             (256 blocks)
// ---------------------------------------------------------------------------
__global__ __launch_bounds__(256)
void prep_everything(const float* __restrict__ queries, const float* __restrict__ keys,
                     const float* __restrict__ Wq, const float* __restrict__ Wk,
                     const float* __restrict__ Wv, const float* __restrict__ Wo,
                     const float* __restrict__ bv, const float* __restrict__ bo,
                     unsigned short* __restrict__ qt, unsigned short* __restrict__ ab,
                     unsigned short* __restrict__ wo, unsigned short* __restrict__ wvT,
                     unsigned short* __restrict__ wqT, unsigned short* __restrict__ wkT,
                     float* __restrict__ G, float* __restrict__ zb, float* __restrict__ b2) {
    __shared__ float tsm[128][65];
    const int bx  = blockIdx.x;
    const int tid = threadIdx.x;

    if (bx < 4096) {
        // qt[b][d0+dl][t0+tl] = bf16(queries[b][t0+tl][d0+dl]); tsm[t][d]
        const int b   = bx >> 8;            // 256 blocks/batch
        const int rem = bx & 255;
        const int t0  = (rem & 15) * 128;   // 16 t-tiles
        const int d0  = (rem >> 4) * 64;    // 16 d-tiles
        const int tx = tid & 63, ty = tid >> 6;
        const float* s = queries + ((size_t)b * 2048 + t0) * 1024 + d0;
        for (int r = ty; r < 128; r += 4)
            tsm[r][tx] = s[(size_t)r * 1024 + tx];
        __syncthreads();
        unsigned short* d = qt + ((size_t)b * 1024 + d0) * 2048 + t0;
        const int seg = tid & 15, rbase = tid >> 4;   // 16 t-segs x 16 d-rows
#pragma unroll
        for (int rr = 0; rr < 4; ++rr) {
            const int dl = rbase + rr * 16;
            bf16x8 o;
#pragma unroll
            for (int j = 0; j < 8; ++j) o[j] = (short)f2bf(tsm[seg * 8 + j][dl]);
            *(bf16x8*)(d + (size_t)dl * 2048 + seg * 8) = o;
        }
    } else if (bx < 20480) {
        const size_t i = ((size_t)(bx - 4096) * 256 + tid) * 8;
        f32x4 v0 = *(const f32x4*)(keys + i);
        f32x4 v1 = *(const f32x4*)(keys + i + 4);
        bf16x8 o;
#pragma unroll
        for (int j = 0; j < 4; ++j) o[j] = (short)f2bf(v0[j]);
#pragma unroll
        for (int j = 0; j < 4; ++j) o[4 + j] = (short)f2bf(v1[j]);
        *(bf16x8*)(ab + i) = o;
    } else if (bx < 21248) {
        // dst[b0+rl][by+cc] = bf16(src[by+cc][b0+rl]); tsm[srcrow][srccol]
        const int wx = bx - 20480;
        const float* src = (wx < 256) ? Wv : (wx < 512) ? Wq : Wk;
        unsigned short* dst = (wx < 256) ? wvT : (wx < 512) ? wqT : wkT;
        const int t  = wx & 255;
        const int b0 = (t & 15) * 64;
        const int by = (t >> 4) * 64;
        const int tx = tid & 63, ty = tid >> 6;
        for (int r = ty; r < 64; r += 4)
            tsm[r][tx] = src[(size_t)(by + r) * 1024 + b0 + tx];
        __syncthreads();
        const int seg = tid & 7, rbase = tid >> 3;
#pragma unroll
        for (int rr = 0; rr < 2; ++rr) {
            const int rl = rbase + rr * 32;
            bf16x8 o;
#pragma unroll
            for (int j = 0; j < 8; ++j) o[j] = (short)f2bf(tsm[seg * 8 + j][rl]);
            *(bf16x8*)(dst + (size_t)(b0 + rl) * 1024 + by + seg * 8) = o;
        }
    } else if (bx < 21504) {
        const int base = (bx - 21248) * 4096 + tid * 4;
#pragma unroll
        for (int r = 0; r < 4; ++r) {
            const int i = base + r * 1024;
            f32x4 v = *(const f32x4*)(Wo + i);
            s16x4 o;
#pragma unroll
            for (int j = 0; j < 4; ++j) o[j] = (short)f2bf(v[j]);
            *(s16x4*)(wo + i) = o;
        }
    } else if (bx < 21513) {
        const int base = (bx - 21504) * 4096;
#pragma unroll
        for (int r = 0; r < 16; ++r) {
            const int i = base + r * 256 + tid;
            if (i < 32800) G[i] = 0.0f;
        }
    } else if (bx == 21513) {
        *(f32x4*)(zb + tid * 4) = (f32x4){0.f, 0.f, 0.f, 0.f};
    } else {
        const int n = (bx - 21514) * 4 + (tid >> 6);
        const int lane = tid & 63;
        float s = 0.f;
        for (int k = lane; k < 1024; k += 64) s += Wo[(size_t)n * 1024 + k] * bv[k];
#pragma unroll
        for (int off = 32; off > 0; off >>= 1) s += __shfl_xor(s, off, 64);
        if (lane == 0) b2[n] = s + bo[n];
    }
}

// ---------------------------------------------------------------------------
// 8-point DFT (negative exponent), in place on xr/xi[8].
// ---------------------------------------------------------------------------
__device__ __forceinline__ void dft8(float* xr, float* xi) {
    const float c8 = 0.70710678118654752440f;
    float es0r = xr[0] + xr[4], es0i = xi[0] + xi[4];
    float es1r = xr[0] - xr[4], es1i = xi[0] - xi[4];
    float es2r = xr[2] + xr[6], es2i = xi[2] + xi[6];
    float es3r = xr[2] - xr[6], es3i = xi[2] - xi[6];
    float E0r = es0r + es2r, E0i = es0i + es2i;
    float E2r = es0r - es2r, E2i = es0i - es2i;
    float E1r = es1r + es3i, E1i = es1i - es3r;
    float E3r = es1r - es3i, E3i = es1i + es3r;
    float os0r = xr[1] + xr[5], os0i = xi[1] + xi[5];
    float os1r = xr[1] - xr[5], os1i = xi[1] - xi[5];
    float os2r = xr[3] + xr[7], os2i = xi[3] + xi[7];
    float os3r = xr[3] - xr[7], os3i = xi[3] - xi[7];
    float O0r = os0r + os2r, O0i = os0i + os2i;
    float O2r = os0r - os2r, O2i = os0i - os2i;
    float O1r = os1r + os3i, O1i = os1i - os3r;
    float O3r = os1r - os3i, O3i = os1i + os3r;
    float p1 = c8 * (O1r + O1i), q1 = c8 * (O1i - O1r);
    float p3 = c8 * (O3r + O3i), q3 = c8 * (O3i - O3r);
    xr[0] = E0r + O0r; xi[0] = E0i + O0i;
    xr[4] = E0r - O0r; xi[4] = E0i - O0i;
    xr[1] = E1r + p1;  xi[1] = E1i + q1;
    xr[5] = E1r - p1;  xi[5] = E1i - q1;
    xr[2] = E2r + O2i; xi[2] = E2i - O2r;
    xr[6] = E2r - O2i; xi[6] = E2i + O2r;
    xr[3] = E3r + q3;  xi[3] = E3i - p3;
    xr[7] = E3r - q3;  xi[7] = E3i + p3;
}

__device__ __forceinline__ int padc(int p) { return p + (p >> 5); }

// apply W^{k} chain (base wr_,wi_) to both streams a and b
#define TWIDDLE2(wr_, wi_)                                                    \
    {                                                                         \
        float cr_ = (wr_), ci_ = (wi_);                                       \
        _Pragma("unroll")                                                     \
        for (int k = 1; k < 8; ++k) {                                         \
            float t0 = ar[k] * cr_ - ai[k] * ci_;                             \
            float t1 = ar[k] * ci_ + ai[k] * cr_;                             \
            ar[k] = t0; ai[k] = t1;                                           \
            float t2 = br[k] * cr_ - bi[k] * ci_;                             \
            float t3 = br[k] * ci_ + bi[k] * cr_;                             \
            br[k] = t2; bi[k] = t3;                                           \
            if (k < 7) {                                                      \
                float nr = cr_ * (wr_) - ci_ * (wi_);                         \
                float ni = cr_ * (wi_) + ci_ * (wr_);                         \
                cr_ = nr; ci_ = ni;                                           \
            }                                                                 \
        }                                                                     \
    }

// ---------------------------------------------------------------------------
// fft_corr (round-12 verified: structural floor at ~116us for this
// decomposition). Dual-column batching, register accumulators, float2+padc,
// 4 barriers per iteration (R2->R3 and R3->R4 are intra-wave).
// grid = 2048 (16 b x 128 chunks), block = 256.
// ---------------------------------------------------------------------------
__global__ __launch_bounds__(256)
void fft_corr(const unsigned short* __restrict__ qt, const unsigned short* __restrict__ kt,
              float* __restrict__ G) {
    __shared__ float2 za[2112];
    __shared__ float2 zb[2112];
    float* zfr0 = (float*)za; float* zfi0 = zfr0 + 2112;
    float* zfr1 = (float*)zb; float* zfi1 = zfr1 + 2112;
    const int tid = threadIdx.x;
    const int b = blockIdx.x >> 7;
    const int chunk = blockIdx.x & 127;

    const float N2PI = -6.28318530717958647692f;
    float w1r, w1i, w2r, w2i, w3r, w3i;
    {
        float s, c;
        __sincosf(N2PI * (float)tid * (1.0f / 2048.0f), &s, &c); w1r = c; w1i = s;
        __sincosf(N2PI * (float)(tid & 31) * (1.0f / 256.0f), &s, &c); w2r = c; w2i = s;
        __sincosf(N2PI * (float)(tid & 3) * (1.0f / 32.0f),  &s, &c); w3r = c; w3i = s;
    }

    float aR0 = 0.f, aI0 = 0.f, aR1 = 0.f, aI1 = 0.f;
    float aR2 = 0.f, aI2 = 0.f, aR3 = 0.f, aI3 = 0.f, aR4 = 0.f;

    const int beta = tid >> 5, s2 = tid & 31;
    const int gam  = tid >> 2, u3 = tid & 3;

    for (int it = 0; it < 4; ++it) {
        const int d0 = chunk * 8 + it * 2;
        const unsigned short* q0 = qt + ((size_t)b * 1024 + d0) * 2048;
        const unsigned short* k0 = kt + ((size_t)b * 1024 + d0) * 2048;
        const unsigned short* q1 = q0 + 2048;
        const unsigned short* k1 = k0 + 2048;

        float ar[8], ai[8], br[8], bi[8];
#pragma unroll
        for (int k = 0; k < 8; ++k) {
            ar[k] = bf2f(q0[tid + 256 * k]); ai[k] = bf2f(k0[tid + 256 * k]);
            br[k] = bf2f(q1[tid + 256 * k]); bi[k] = bf2f(k1[tid + 256 * k]);
        }
        dft8(ar, ai); dft8(br, bi);
        TWIDDLE2(w1r, w1i)
#pragma unroll
        for (int k = 0; k < 8; ++k) {
            const int p = padc(256 * k + tid);
            za[p] = make_float2(ar[k], ai[k]);
            zb[p] = make_float2(br[k], bi[k]);
        }
        __syncthreads();   // R1 writers cross-wave: barrier REQUIRED

#pragma unroll
        for (int k = 0; k < 8; ++k) {
            const int p = padc(256 * beta + 32 * k + s2);
            float2 va = za[p]; ar[k] = va.x; ai[k] = va.y;
            float2 vb = zb[p]; br[k] = vb.x; bi[k] = vb.y;
        }
        dft8(ar, ai); dft8(br, bi);
        TWIDDLE2(w2r, w2i)
#pragma unroll
        for (int k = 0; k < 8; ++k) {
            const int p = padc(256 * beta + 32 * k + s2);
            za[p] = make_float2(ar[k], ai[k]);
            zb[p] = make_float2(br[k], bi[k]);
        }
        // NO barrier: R3's reads come from its own wave's R2 writes.

#pragma unroll
        for (int k = 0; k < 8; ++k) {
            const int p = padc(32 * gam + 4 * k + u3);
            float2 va = za[p]; ar[k] = va.x; ai[k] = va.y;
            float2 vb = zb[p]; br[k] = vb.x; bi[k] = vb.y;
        }
        dft8(ar, ai); dft8(br, bi);
        TWIDDLE2(w3r, w3i)
#pragma unroll
        for (int k = 0; k < 8; ++k) {
            const int p = padc(32 * gam + 4 * k + u3);
            za[p] = make_float2(ar[k], ai[k]);
            zb[p] = make_float2(br[k], bi[k]);
        }
        // NO barrier: R4 reads its own 4-lane group's R3 writes.

#pragma unroll
        for (int k = 0; k < 8; ++k) {
            const int p = padc(8 * tid + k);
            float2 va = za[p]; ar[k] = va.x; ai[k] = va.y;
            float2 vb = zb[p]; br[k] = vb.x; bi[k] = vb.y;
        }
        __syncthreads();   // anti-dep: scatter overwrites other waves' R4 reads

#pragma unroll
        for (int blk = 0; blk < 2; ++blk) {
            const int o = 4 * blk;
            {
                float s0r = ar[o] + ar[o + 2], s0i = ai[o] + ai[o + 2];
                float s1r = ar[o] - ar[o + 2], s1i = ai[o] - ai[o + 2];
                float s2r = ar[o + 1] + ar[o + 3], s2i = ai[o + 1] + ai[o + 3];
                float s3r = ar[o + 1] - ar[o + 3], s3i = ai[o + 1] - ai[o + 3];
                ar[o + 0] = s0r + s2r; ai[o + 0] = s0i + s2i;
                ar[o + 2] = s0r - s2r; ai[o + 2] = s0i - s2i;
                ar[o + 1] = s1r + s3i; ai[o + 1] = s1i - s3r;
                ar[o + 3] = s1r - s3i; ai[o + 3] = s1i + s3r;
            }
            {
                float s0r = br[o] + br[o + 2], s0i = bi[o] + bi[o + 2];
                float s1r = br[o] - br[o + 2], s1i = bi[o] - bi[o + 2];
                float s2r = br[o + 1] + br[o + 3], s2i = bi[o + 1] + bi[o + 3];
                float s3r = br[o + 1] - br[o + 3], s3i = bi[o + 1] - bi[o + 3];
                br[o + 0] = s0r + s2r; bi[o + 0] = s0i + s2i;
                br[o + 2] = s0r - s2r; bi[o + 2] = s0i - s2i;
                br[o + 1] = s1r + s3i; bi[o + 1] = s1i - s3r;
                br[o + 3] = s1r - s3i; bi[o + 3] = s1i + s3r;
            }
        }
        {
            const int k1d = tid >> 5;
            const int k2d = (tid >> 2) & 7;
            const int fb = k1d + 8 * k2d;
#pragma unroll
            for (int blk = 0; blk < 2; ++blk) {
                const int k3d = (2 * (tid & 3) + blk) & 7;
#pragma unroll
                for (int k4 = 0; k4 < 4; ++k4) {
                    const int f = fb + 64 * k3d + 512 * k4;
                    const int pf = padc(f);
                    zfr0[pf] = ar[4 * blk + k4]; zfi0[pf] = ai[4 * blk + k4];
                    zfr1[pf] = br[4 * blk + k4]; zfi1[pf] = bi[4 * blk + k4];
                }
            }
        }
        __syncthreads();   // scatter writers cross-wave before Hermitian reads

        // Hermitian split + accumulate (registers)
#pragma unroll
        for (int k = 0; k < 4; ++k) {
            const int f = tid + 256 * k;
            const int f2 = (2048 - f) & 2047;
            const int pf = padc(f), pf2 = padc(f2);
            float Zr = zfr0[pf],  Zi = zfi0[pf];
            float Yr = zfr0[pf2], Yi = -zfi0[pf2];
            float Qr = 0.5f * (Zr + Yr), Qi = 0.5f * (Zi + Yi);
            float Kr = 0.5f * (Zi - Yi), Ki = -0.5f * (Zr - Yr);
            float dR = Qr * Kr + Qi * Ki;
            float dI = Qi * Kr - Qr * Ki;
            Zr = zfr1[pf];  Zi = zfi1[pf];
            Yr = zfr1[pf2]; Yi = -zfi1[pf2];
            Qr = 0.5f * (Zr + Yr); Qi = 0.5f * (Zi + Yi);
            Kr = 0.5f * (Zi - Yi); Ki = -0.5f * (Zr - Yr);
            dR += Qr * Kr + Qi * Ki;
            dI += Qi * Kr - Qr * Ki;
            if      (k == 0) { aR0 += dR; aI0 += dI; }
            else if (k == 1) { aR1 += dR; aI1 += dI; }
            else if (k == 2) { aR2 += dR; aI2 += dI; }
            else             { aR3 += dR; aI3 += dI; }
        }
        if (tid == 0) {   // f = 1024: Q = Re(Z), K = Im(Z), P imag = 0
            const int pf = padc(1024);
            aR4 += zfr0[pf] * zfi0[pf] + zfr1[pf] * zfi1[pf];
        }
        __syncthreads();   // anti-dep: next iteration's R1 writes
    }

    atomicAdd(&G[((size_t)b * 1025 + tid +   0) * 2 + 0], aR0);
    atomicAdd(&G[((size_t)b * 1025 + tid +   0) * 2 + 1], aI0);
    atomicAdd(&G[((size_t)b * 1025 + tid + 256) * 2 + 0], aR1);
    atomicAdd(&G[((size_t)b * 1025 + tid + 256) * 2 + 1], aI1);
    atomicAdd(&G[((size_t)b * 1025 + tid + 512) * 2 + 0], aR2);
    atomicAdd(&G[((size_t)b * 1025 + tid + 512) * 2 + 1], aI2);
    atomicAdd(&G[((size_t)b * 1025 + tid + 768) * 2 + 0], aR3);
    atomicAdd(&G[((size_t)b * 1025 + tid + 768) * 2 + 1], aI3);
    if (tid == 0)
        atomicAdd(&G[((size_t)b * 1025 + 1024) * 2 + 0], aR4);
}

// ---------------------------------------------------------------------------
// In-LDS radix-2 DIT FFT, N=2048 (only used by irfft_mean: 16 blocks, cheap).
// ---------------------------------------------------------------------------
__device__ __forceinline__ void fft2048(float* zr, float* zi,
                                        const float* twr, const float* twi, int tid) {
    for (int t = tid; t < 2048; t += 256) {
        int j = __brev((unsigned)t) >> 21;
        if (j > t) {
            float a = zr[t]; zr[t] = zr[j]; zr[j] = a;
            float c = zi[t]; zi[t] = zi[j]; zi[j] = c;
        }
    }
    __syncthreads();
    for (int s = 0; s < 11; ++s) {
        const int m = 1 << s;
        for (int i = tid; i < 1024; i += 256) {
            const int pos = i & (m - 1);
            const int i1  = ((i >> s) << (s + 1)) + pos;
            const int i2  = i1 + m;
            const int tw  = pos << (10 - s);
            float wr = twr[tw], wi = twi[tw];
            float xr = zr[i2], xi = zi[i2];
            float tr = wr * xr - wi * xi;
            float ti = wr * xi + wi * xr;
            float ur = zr[i1], ui = zi[i1];
            zr[i2] = ur - tr; zi[i2] = ui - ti;
            zr[i1] = ur + tr; zi[i1] = ui + ti;
        }
        __syncthreads();
    }
}

__device__ __forceinline__ void init_twiddle(float* twr, float* twi, int tid) {
    for (int j = tid; j < 1024; j += 256) {
        float ang = -6.28318530717958647692f * (float)j * (1.0f / 2048.0f);
        twr[j] = cosf(ang);
        twi[j] = sinf(ang);
    }
}

// ---------------------------------------------------------------------------
// Per-batch irfft of G -> mean_value[b][t], scale 1/(2048*1024). grid = 16.
// ---------------------------------------------------------------------------
__global__ __launch_bounds__(256)
void irfft_mean(const float* __restrict__ G, float* __restrict__ mv) {
    __shared__ float zr[2048], zi[2048];
    __shared__ float twr[1024], twi[1024];
    const int tid = threadIdx.x;
    const int b = blockIdx.x;
    init_twiddle(twr, twi, tid);
    for (int f = tid; f < 2048; f += 256) {
        int g = (f <= 1024) ? f : 2048 - f;
        float gr = G[((size_t)b * 1025 + g) * 2 + 0];
        float gi = G[((size_t)b * 1025 + g) * 2 + 1];
        zr[f] = gr;
        zi[f] = (f <= 1024) ? -gi : gi;
    }
    __syncthreads();
    fft2048(zr, zi, twr, twi, tid);
    const float sc = 1.0f / (2048.0f * 1024.0f);
    for (int t = tid; t < 2048; t += 256) mv[b * 2048 + t] = zr[t] * sc;
}

// ---------------------------------------------------------------------------
// Top-7 over batch-mean + per-batch softmax (parallel argmax).
// ---------------------------------------------------------------------------
__global__ __launch_bounds__(256)
void topk_softmax(const float* __restrict__ mv, int* __restrict__ idx_out,
                  float* __restrict__ w_out) {
    __shared__ float cm[2048];
    __shared__ float wv4[4];
    __shared__ int   wi4[4];
    __shared__ int   sel[7];
    const int tid  = threadIdx.x;
    const int lane = tid & 63;
    const int wvid = tid >> 6;

    for (int t = tid; t < 2048; t += 256) {
        float s = 0.f;
        for (int b = 0; b < 16; ++b) s += mv[b * 2048 + t];
        cm[t] = s * (1.0f / 16.0f);
    }
    __syncthreads();

    for (int it = 0; it < 7; ++it) {
        float best = -3.4e38f; int bi = 1 << 30;
#pragma unroll
        for (int q = 0; q < 8; ++q) {
            const int t = tid + q * 256;
            float v = cm[t];
            if (v > best || (v == best && t < bi)) { best = v; bi = t; }
        }
#pragma unroll
        for (int off = 32; off > 0; off >>= 1) {
            float ov = __shfl_xor(best, off, 64);
            int   oi = __shfl_xor(bi,   off, 64);
            if (ov > best || (ov == best && oi < bi)) { best = ov; bi = oi; }
        }
        if (lane == 0) { wv4[wvid] = best; wi4[wvid] = bi; }
        __syncthreads();
        if (tid == 0) {
            float bb = wv4[0]; int bj = wi4[0];
#pragma unroll
            for (int u = 1; u < 4; ++u)
                if (wv4[u] > bb || (wv4[u] == bb && wi4[u] < bj)) { bb = wv4[u]; bj = wi4[u]; }
            sel[it] = bj;
            idx_out[it] = bj;
            cm[bj] = -3.4e38f;
        }
        __syncthreads();
    }

    if (tid < 16) {
        const int b = tid;
        float wv[7]; float mx = -3.4e38f;
#pragma unroll
        for (int i = 0; i < 7; ++i) { wv[i] = mv[b * 2048 + sel[i]]; mx = fmaxf(mx, wv[i]); }
        float s = 0.f;
#pragma unroll
        for (int i = 0; i < 7; ++i) { wv[i] = expf(wv[i] - mx); s += wv[i]; }
        float inv = 1.0f / s;
#pragma unroll
        for (int i = 0; i < 7; ++i) w_out[b * 7 + i] = wv[i] * inv;
    }
}

// ---------------------------------------------------------------------------
// agg[b,t,d] = bf16( sum_i w[b,i] * values[b,(t+idx[i])%2048,d] )  (fp32 in)
// ---------------------------------------------------------------------------
__global__ __launch_bounds__(256)
void agg_kernel(const float* __restrict__ vsrc, const int* __restrict__ idx,
                const float* __restrict__ w, unsigned short* __restrict__ agg) {
    const int b  = blockIdx.y;
    const int t  = blockIdx.x * 2 + (threadIdx.x >> 7);
    const int d8 = (threadIdx.x & 127) * 8;
    float av[8] = {0.f, 0.f, 0.f, 0.f, 0.f, 0.f, 0.f, 0.f};
#pragma unroll
    for (int i = 0; i < 7; ++i) {
        const int srow = (t + idx[i]) & 2047;
        const float wi = w[b * 7 + i];
        const float* src = vsrc + ((size_t)b * 2048 + srow) * 1024 + d8;
        f32x4 v0 = *(const f32x4*)src;
        f32x4 v1 = *(const f32x4*)(src + 4);
#pragma unroll
        for (int j = 0; j < 4; ++j) av[j] += wi * v0[j];
#pragma unroll
        for (int j = 0; j < 4; ++j) av[4 + j] += wi * v1[j];
    }
    bf16x8 o;
#pragma unroll
    for (int j = 0; j < 8; ++j) o[j] = (short)f2bf(av[j]);
    *(bf16x8*)&agg[((size_t)b * 2048 + t) * 1024 + d8] = o;
}

// ---------------------------------------------------------------------------
extern "C" void kernel_launch(void* const* d_in, const int* in_sizes, int n_in,
                              void* d_out, int out_size, void* d_ws, size_t ws_size,
                              hipStream_t stream) {
    const float* queries = (const float*)d_in[0];
    const float* keys    = (const float*)d_in[1];
    const float* values  = (const float*)d_in[2];
    const float* Wq = (const float*)d_in[3];
    const float* Wk = (const float*)d_in[5];
    const float* Wv = (const float*)d_in[7];  const float* bv = (const float*)d_in[8];
    const float* Wo = (const float*)d_in[9];  const float* bo = (const float*)d_in[10];
    float* out = (float*)d_out;

    char* ws = (char*)d_ws;
    constexpr size_t SZP = (size_t)32768 * 1024 * 2;           // 64 MB (bf16 B*L*D)
    unsigned short* agg = (unsigned short*)(ws);               // agg output [b][t][d]
    unsigned short* kt  = (unsigned short*)(ws + SZP);         // k~^T [b][d][t]
    unsigned short* qt  = (unsigned short*)(ws + 2 * SZP);     // q^T  [b][d][t]
    unsigned short* ab  = (unsigned short*)(ws + 3 * SZP);     // staging (64MB)
    unsigned short* W2  = (unsigned short*)(ws + 4 * SZP);     // bf16 Wo@Wv   [N][K]
    unsigned short* M   = W2 + 1048576;                        // bf16 Wq^T@Wk [N][K]
    unsigned short* wtmp = M + 1048576;                        // 4 x 1M bf16 weight temps
    unsigned short* wo  = wtmp;
    unsigned short* wvT = wtmp + 1048576;
    unsigned short* wqT = wtmp + 2097152;
    unsigned short* wkT = wtmp + 3145728;
    char* tail = ws + 4 * SZP + 4194304 + 8388608;
    float* zb1024 = (float*)(tail);                            // 4KB zero bias
    float* b2     = (float*)(tail + 4096);
    float* G      = (float*)(tail + 8192);                     // 16*1025*2 f32
    float* mv     = (float*)(tail + 8192 + 131328);
    int*   idx    = (int*)  (tail + 8192 + 131328 + 131072);
    float* wsm    = (float*)(tail + 8192 + 131328 + 131072 + 64);

    // 1) ALL prep in one launch (inputs + weights + zeros + b2)
    prep_everything<<<21770, 256, 0, stream>>>(queries, keys, Wq, Wk, Wv, Wo, bv, bo,
                                               qt, ab, wo, wvT, wqT, wkT,
                                               G, zb1024, b2);
    // 2) W2 = Wo@Wv and M = Wq^T@Wk in one launch
    gemm_pair<<<32, 512, 0, stream>>>(wo, wvT, zb1024, W2,
                                      wqT, wkT, zb1024, M);
    // 3) k~ = k @ M^T (transposed out)
    gemm256<2><<<512, 512, 0, stream>>>(ab, M, zb1024, kt);

    // 4) correlation -> top-k -> aggregation -> fused output GEMM
    fft_corr<<<2048, 256, 0, stream>>>(qt, kt, G);
    irfft_mean<<<16, 256, 0, stream>>>(G, mv);
    topk_softmax<<<1, 256, 0, stream>>>(mv, idx, wsm);
    agg_kernel<<<dim3(1024, 16), 256, 0, stream>>>(values, idx, wsm, agg);
    gemm256<1><<<512, 512, 0, stream>>>(agg, W2, b2, out);
}